// Round 8
// baseline (247.377 us; speedup 1.0000x reference)
//
#include <hip/hip_runtime.h>
#include <hip/hip_bf16.h>
#include <float.h>

#define T_LEN 2048
#define DM    1024
#define NB    128
#define NEGC  (-1e9f)

typedef __attribute__((ext_vector_type(8))) short short8;
typedef __attribute__((ext_vector_type(4))) float floatx4;
typedef _Float16 h2 __attribute__((ext_vector_type(2)));
typedef _Float16 h8 __attribute__((ext_vector_type(8)));

// ---------------- helpers ----------------
__device__ __forceinline__ float wred_max(float v) {
#pragma unroll
  for (int o = 32; o > 0; o >>= 1) v = fmaxf(v, __shfl_xor(v, o, 64));
  return v;
}
__device__ __forceinline__ float wred_sum(float v) {
#pragma unroll
  for (int o = 32; o > 0; o >>= 1) v += __shfl_xor(v, o, 64);
  return v;
}
__device__ __forceinline__ unsigned short f32_to_bf16(float f) {
  unsigned int b = __float_as_uint(f);
  return (unsigned short)((b + 0x7fffu + ((b >> 16) & 1u)) >> 16);
}
__device__ __forceinline__ float bf16_to_f32(unsigned short u) {
  return __uint_as_float(((unsigned int)u) << 16);
}
__device__ __forceinline__ unsigned int pack_h2(float a, float b) {
  h2 r; r[0] = (_Float16)a; r[1] = (_Float16)b;
  return __builtin_bit_cast(unsigned int, r);
}
__device__ __forceinline__ unsigned short f32_to_f16u(float f) {
  h2 r; r[0] = (_Float16)f; r[1] = (_Float16)0.f;
  return (unsigned short)(__builtin_bit_cast(unsigned int, r) & 0xffffu);
}
__device__ __forceinline__ float fdot2u(unsigned int a, unsigned int b, float c) {
#if __has_builtin(__builtin_amdgcn_fdot2)
  return __builtin_amdgcn_fdot2(__builtin_bit_cast(h2, a), __builtin_bit_cast(h2, b), c, false);
#else
  const h2 av = __builtin_bit_cast(h2, a), bv = __builtin_bit_cast(h2, b);
  return c + (float)av[0] * (float)bv[0] + (float)av[1] * (float)bv[1];
#endif
}
__device__ __forceinline__ void lds_async16(unsigned short* l, const unsigned short* g) {
  __builtin_amdgcn_global_load_lds(
      (const __attribute__((address_space(1))) unsigned int*)g,
      (__attribute__((address_space(3))) unsigned int*)l, 16, 0, 0);
}

// ====== qkv GEMM: 128x192 tile, BK=32, 2-phase counted-vmcnt ======
// r7 model: GEMM time = staged-bytes / (~11 B/cy/CU) regardless of barrier
// or prefetch structure (BK=64 halved steps but doubled step time). Lever:
// flops per staged byte. 64x128 tile = 43.7 fl/B; 128x192 = 76.8 (1.76x).
// N=3072/192=16 -> grid (16,16) = 256 blocks = EXACTLY 1/CU, no straggle.
// 4 waves (2x2), each owns 64x96 out = 4x6 accs. Per step/wave: 2 A-group +
// 3 B-group lds_async16 (5 loads) -> stage t+1 then vmcnt(5) = tile t landed.
// LDS layout per 16-row group (512 shorts): chunk(k/8)*128 + mrow*8 -> dest
// is lane-contiguous (global_load_lds req) and fragment ds_read_b128 hits
// bank mrow*4 mod 32 (2-way alias = free).
__global__ __launch_bounds__(256) void qkv_gemm(const unsigned short* __restrict__ Axf,
                                                const unsigned short* __restrict__ Bqkv,
                                                float* __restrict__ C) {
  __shared__ __align__(16) unsigned short As[2 * 4096];   // 2 x 128x32 f16
  __shared__ __align__(16) unsigned short Bs[2 * 6144];   // 2 x 192x32 f16
  const int tid = threadIdx.x;
  const int w = tid >> 6, lane = tid & 63;
  const int wr = w >> 1, wc = w & 1;
  const int mrow = lane & 15, kgrp = lane >> 4;
  const int row0 = blockIdx.y * 128;
  const int col0 = blockIdx.x * 192;

  floatx4 zero = {0.f, 0.f, 0.f, 0.f};
  floatx4 acc[4][6];
#pragma unroll
  for (int i = 0; i < 4; i++)
#pragma unroll
    for (int j = 0; j < 6; j++) acc[i][j] = zero;

  // per-lane global sources (k-offset added per step)
  const unsigned short* ApA[2];
#pragma unroll
  for (int j = 0; j < 2; j++)
    ApA[j] = Axf + (size_t)(row0 + (w * 2 + j) * 16 + mrow) * 1024 + kgrp * 8;
  const unsigned short* BpB[3];
#pragma unroll
  for (int j = 0; j < 3; j++)
    BpB[j] = Bqkv + (size_t)(col0 + (w * 3 + j) * 16 + mrow) * 1024 + kgrp * 8;

  auto stage = [&](int t, int b) {
    const int ko = t * 32;
#pragma unroll
    for (int j = 0; j < 2; j++)
      lds_async16(&As[b * 4096 + (w * 2 + j) * 512], ApA[j] + ko);
#pragma unroll
    for (int j = 0; j < 3; j++)
      lds_async16(&Bs[b * 6144 + (w * 3 + j) * 512], BpB[j] + ko);
  };

  stage(0, 0);
  int cur = 0;
  for (int t = 0; t < 32; t++) {
    if (t + 1 < 32) {
      stage(t + 1, cur ^ 1);                              // outstanding: 10
      asm volatile("s_waitcnt vmcnt(5)" ::: "memory");    // tile t landed; t+1 in flight
    } else {
      asm volatile("s_waitcnt vmcnt(0)" ::: "memory");
    }
    __builtin_amdgcn_s_barrier();
    const unsigned short* as = As + cur * 4096;
    const unsigned short* bs = Bs + cur * 6144;
    short8 af[4], bf6[6];
#pragma unroll
    for (int mi = 0; mi < 4; mi++)
      af[mi] = *(const short8*)&as[(wr * 4 + mi) * 512 + kgrp * 128 + mrow * 8];
#pragma unroll
    for (int ni = 0; ni < 6; ni++)
      bf6[ni] = *(const short8*)&bs[(wc * 6 + ni) * 512 + kgrp * 128 + mrow * 8];
#pragma unroll
    for (int mi = 0; mi < 4; mi++)
#pragma unroll
      for (int ni = 0; ni < 6; ni++)
        acc[mi][ni] = __builtin_amdgcn_mfma_f32_16x16x32_f16(
            __builtin_bit_cast(h8, af[mi]), __builtin_bit_cast(h8, bf6[ni]),
            acc[mi][ni], 0, 0, 0);
    asm volatile("" ::: "memory");
    __builtin_amdgcn_s_barrier();       // buf[cur] reads done before overwrite
    cur ^= 1;
  }
#pragma unroll
  for (int mi = 0; mi < 4; mi++)
#pragma unroll
    for (int ni = 0; ni < 6; ni++) {
      float* Cp = C + (size_t)(row0 + wr * 64 + mi * 16 + kgrp * 4) * 3072
                    + col0 + wc * 96 + ni * 16 + mrow;
      Cp[0] = acc[mi][ni][0];
      Cp[3072] = acc[mi][ni][1];
      Cp[2 * 3072] = acc[mi][ni][2];
      Cp[3 * 3072] = acc[mi][ni][3];
    }
}

// ====== 64x128-tile core (bt64 only) — BK=64, 2-phase counted-vmcnt ======
__device__ __forceinline__ void gemm64_core(
    const unsigned short* __restrict__ A, const unsigned short* __restrict__ Bt,
    float* __restrict__ C, int K, int lda, int row0, int bcol0, int ccol0, int ldc,
    unsigned short* As, unsigned short* Bs) {
  const int tid = threadIdx.x;
  const int w = tid >> 6, lane = tid & 63;
  const int wr = w >> 1, wc = w & 1;
  const int mrow = lane & 15, kgrp = lane >> 4;

  const int sr = (w << 4) + mrow;
  const int sc = kgrp;

  floatx4 zero = {0.f, 0.f, 0.f, 0.f};
  floatx4 acc[2][4];
#pragma unroll
  for (int i = 0; i < 2; i++)
#pragma unroll
    for (int j = 0; j < 4; j++) acc[i][j] = zero;

  const int nt = K >> 6;
  const unsigned short* Ap  = A  + (size_t)(row0 + sr) * lda + sc * 8;
  const unsigned short* Bp0 = Bt + (size_t)(bcol0 + sr) * K + sc * 8;
  const unsigned short* Bp1 = Bt + (size_t)(bcol0 + 64 + sr) * K + sc * 8;

  auto stage = [&](int t, int b) {
    const int ko = t << 6;
#pragma unroll
    for (int j = 0; j < 2; j++) {
      lds_async16(&As[b * 4096 + w * 1024 + j * 512], Ap + ko + j * 32);
      lds_async16(&Bs[b * 8192 + w * 1024 + j * 512], Bp0 + ko + j * 32);
      lds_async16(&Bs[b * 8192 + 4096 + w * 1024 + j * 512], Bp1 + ko + j * 32);
    }
  };

  stage(0, 0);
  int cur = 0;
  for (int t = 0; t < nt; t++) {
    if (t + 1 < nt) {
      stage(t + 1, cur ^ 1);
      asm volatile("s_waitcnt vmcnt(6)" ::: "memory");
    } else {
      asm volatile("s_waitcnt vmcnt(0)" ::: "memory");
    }
    __builtin_amdgcn_s_barrier();
    const unsigned short* as = As + cur * 4096;
    const unsigned short* bs = Bs + cur * 8192;
#pragma unroll
    for (int ks = 0; ks < 2; ks++) {
      short8 af[2], bf4[4];
#pragma unroll
      for (int mi = 0; mi < 2; mi++)
        af[mi] = *(const short8*)&as[(wr * 2 + mi) * 1024 + (ks * 4 + kgrp) * 128 + mrow * 8];
#pragma unroll
      for (int ni = 0; ni < 4; ni++)
        bf4[ni] = *(const short8*)&bs[(wc * 4 + ni) * 1024 + (ks * 4 + kgrp) * 128 + mrow * 8];
#pragma unroll
      for (int mi = 0; mi < 2; mi++)
#pragma unroll
        for (int ni = 0; ni < 4; ni++)
          acc[mi][ni] = __builtin_amdgcn_mfma_f32_16x16x32_bf16(af[mi], bf4[ni],
                                                                acc[mi][ni], 0, 0, 0);
    }
    asm volatile("" ::: "memory");
    __builtin_amdgcn_s_barrier();
    cur ^= 1;
  }
#pragma unroll
  for (int mi = 0; mi < 2; mi++)
#pragma unroll
    for (int ni = 0; ni < 4; ni++) {
      float* Cp = C + (size_t)(row0 + wr * 32 + mi * 16 + kgrp * 4) * ldc
                    + ccol0 + wc * 64 + ni * 16 + mrow;
      Cp[0] = acc[mi][ni][0];
      Cp[(size_t)ldc] = acc[mi][ni][1];
      Cp[(size_t)2 * ldc] = acc[mi][ni][2];
      Cp[(size_t)3 * ldc] = acc[mi][ni][3];
    }
}

// final output projection (bf16 inputs)
__global__ __launch_bounds__(256) void gemm_bt64(const unsigned short* __restrict__ A,
                                                 const unsigned short* __restrict__ Bt,
                                                 float* __restrict__ C,
                                                 int K, int lda, int ldc) {
  __shared__ __align__(16) unsigned short As[2 * 64 * 64];
  __shared__ __align__(16) unsigned short Bs[2 * 128 * 64];
  gemm64_core(A, Bt, C, K, lda, blockIdx.y * 64,
              blockIdx.x * 128, blockIdx.x * 128, ldc, As, Bs);
}

// ---------------- cast x -> f16 (2048 x 1024) ----------------
__global__ __launch_bounds__(256) void cast_x_k(const float* __restrict__ x,
                                                unsigned short* __restrict__ Axf) {
  const int gid = blockIdx.x * 256 + threadIdx.x;
  float4 xv = ((const float4*)x)[gid];
  const unsigned int p0 = pack_h2(xv.x, xv.y);
  const unsigned int p1 = pack_h2(xv.z, xv.w);
  *(uint2*)&Axf[(size_t)gid * 4] = make_uint2(p0, p1);
}

// ---- transpose-cast Wq/Wk/Wv (by blockIdx.z) into Bqkv f16 (3072n x 1024k) ----
__global__ void cast_wqkv(const float* __restrict__ Wq, const float* __restrict__ Wk,
                          const float* __restrict__ Wv, unsigned short* __restrict__ Bt) {
  __shared__ float tile[32][33];
  const float* W = (blockIdx.z == 0) ? Wq : (blockIdx.z == 1) ? Wk : Wv;
  const int n0 = blockIdx.z * 1024;
  const int kt0 = blockIdx.y * 32, nt0 = blockIdx.x * 32;
  const int tx = threadIdx.x, ty = threadIdx.y;
#pragma unroll
  for (int i = 0; i < 32; i += 8)
    tile[ty + i][tx] = W[(size_t)(kt0 + ty + i) * 1024 + nt0 + tx];
  __syncthreads();
#pragma unroll
  for (int i = 0; i < 32; i += 8) {
    const int n = nt0 + ty + i, kk = kt0 + tx;
    Bt[(size_t)(n0 + n) * 1024 + kk] = f32_to_f16u(tile[tx][ty + i]);
  }
}

// ---- transpose-cast 1024x1024 W -> Bt (1024n x 1024k) bf16 ----
__global__ void cast_wt1(const float* __restrict__ W, unsigned short* __restrict__ Bt) {
  __shared__ float tile[32][33];
  const int kt0 = blockIdx.y * 32, nt0 = blockIdx.x * 32;
  const int tx = threadIdx.x, ty = threadIdx.y;
#pragma unroll
  for (int i = 0; i < 32; i += 8)
    tile[ty + i][tx] = W[(size_t)(kt0 + ty + i) * 1024 + nt0 + tx];
  __syncthreads();
#pragma unroll
  for (int i = 0; i < 32; i += 8) {
    const int n = nt0 + ty + i, kk = kt0 + tx;
    Bt[(size_t)n * 1024 + kk] = f32_to_bf16(tile[tx][ty + i]);
  }
}

// ---- transpose-cast Wck/Wcv (1024x64) -> (64,1024) hi/lo bf16 ----
__global__ void cast_wct(const float* __restrict__ Wck, const float* __restrict__ Wcv,
                         unsigned short* __restrict__ KT_hi, unsigned short* __restrict__ KT_lo,
                         unsigned short* __restrict__ VT_hi, unsigned short* __restrict__ VT_lo) {
  __shared__ float tile[32][33];
  const float* W = blockIdx.z ? Wcv : Wck;
  unsigned short* Bh = blockIdx.z ? VT_hi : KT_hi;
  unsigned short* Bl = blockIdx.z ? VT_lo : KT_lo;
  const int kt0 = blockIdx.y * 32, nt0 = blockIdx.x * 32;
  const int tx = threadIdx.x, ty = threadIdx.y;
#pragma unroll
  for (int i = 0; i < 32; i += 8)
    tile[ty + i][tx] = W[(size_t)(kt0 + ty + i) * 64 + nt0 + tx];
  __syncthreads();
#pragma unroll
  for (int i = 0; i < 32; i += 8) {
    const int n = nt0 + ty + i, kk = kt0 + tx;
    const float f = tile[tx][ty + i];
    const unsigned short hb = f32_to_bf16(f);
    Bh[(size_t)n * 1024 + kk] = hb;
    Bl[(size_t)n * 1024 + kk] = f32_to_bf16(f - bf16_to_f32(hb));
  }
}

// ---------------- reorg: C(t,3072) -> qh f32, qhf f16 (T,1024),
//                  khfT f16 (H, 8, T, 8), vhf f16 (H, T, 64) ----------------
__global__ __launch_bounds__(256) void reorg_qkv(const float* __restrict__ C,
                                                 float* __restrict__ qh,
                                                 unsigned short* __restrict__ qhf,
                                                 unsigned short* __restrict__ khfT,
                                                 unsigned short* __restrict__ vhf) {
  const int gid = blockIdx.x * 256 + threadIdx.x;
  const int t = gid / 768;
  const int c = (gid - t * 768) * 4;
  float4 val = *(const float4*)&C[(size_t)t * 3072 + c];
  const unsigned int p0 = pack_h2(val.x, val.y);
  const unsigned int p1 = pack_h2(val.z, val.w);
  if (c < 1024) {
    *(float4*)&qh[(size_t)t * 1024 + c] = val;
    *(uint2*)&qhf[(size_t)t * 1024 + c] = make_uint2(p0, p1);
  } else if (c < 2048) {
    const int h = (c >> 6) & 15, d = c & 63;
    const int dc = d >> 3, j = d & 7;
    *(uint2*)&khfT[((size_t)(h * 8 + dc) * 2048 + t) * 8 + j] = make_uint2(p0, p1);
  } else {
    const int h = (c >> 6) & 15, d = c & 63;
    *(uint2*)&vhf[((size_t)h * 2048 + t) * 64 + d] = make_uint2(p0, p1);
  }
}

// ---- transpose vhf [h][t][64] -> vhfT [h][d][2048] f16 (for window PV MFMA) ----
__global__ void transp_v(const unsigned short* __restrict__ vhf,
                         unsigned short* __restrict__ vhfT) {
  __shared__ unsigned short tile[32][34];
  const int h = blockIdx.z;
  const int t0 = blockIdx.x * 32, d0 = blockIdx.y * 32;
  const int tx = threadIdx.x, ty = threadIdx.y;
#pragma unroll
  for (int i = 0; i < 32; i += 8)
    tile[ty + i][tx] = vhf[((size_t)h * 2048 + t0 + ty + i) * 64 + d0 + tx];
  __syncthreads();
#pragma unroll
  for (int i = 0; i < 32; i += 8)
    vhfT[((size_t)h * 64 + d0 + ty + i) * 2048 + t0 + tx] = tile[tx][ty + i];
}

// ---------------- compress via MFMA (reads k/v straight from C) ----------------
__global__ __launch_bounds__(512) void compress_mfma(
    const float* __restrict__ C,
    const unsigned short* __restrict__ KT_hi, const unsigned short* __restrict__ KT_lo,
    const unsigned short* __restrict__ VT_hi, const unsigned short* __restrict__ VT_lo,
    unsigned short* __restrict__ kc_hi, unsigned short* __restrict__ kc_lo,
    unsigned short* __restrict__ vcT) {
  __shared__ float red[8][64][17];
  const int isv = blockIdx.y;
  const unsigned short* Bh = isv ? VT_hi : KT_hi;
  const unsigned short* Bl = isv ? VT_lo : KT_lo;
  const int tid = threadIdx.x, w = tid >> 6, lane = tid & 63;
  const int mrow = lane & 15, kgrp = lane >> 4;
  const int m0 = blockIdx.x * 16;
  const int m = m0 + mrow;
  const int hh = m >> 7, nb = m & 127;
  const int cbase = 1024 + isv * 1024 + hh * 64;

  floatx4 zero = {0.f, 0.f, 0.f, 0.f};
  floatx4 acc[4] = {zero, zero, zero, zero};

  const int kbeg = w << 7;
  for (int k0 = kbeg; k0 < kbeg + 128; k0 += 32) {
    const int c = k0 + kgrp * 8;
    const float* ap = &C[(size_t)(nb * 16 + (c >> 6)) * 3072 + cbase + (c & 63)];
    float4 q0 = *(const float4*)ap;
    float4 q1 = *(const float4*)(ap + 4);
    float qq[8] = {q0.x, q0.y, q0.z, q0.w, q1.x, q1.y, q1.z, q1.w};
    short8 a_hi, a_lo;
#pragma unroll
    for (int j = 0; j < 8; j++) {
      unsigned short hb = f32_to_bf16(qq[j]);
      a_hi[j] = (short)hb;
      a_lo[j] = (short)f32_to_bf16(qq[j] - bf16_to_f32(hb));
    }
#pragma unroll
    for (int ni = 0; ni < 4; ni++) {
      const size_t boff = (size_t)(ni * 16 + mrow) * 1024 + k0 + kgrp * 8;
      short8 b_hi = *(const short8*)&Bh[boff];
      short8 b_lo = *(const short8*)&Bl[boff];
      acc[ni] = __builtin_amdgcn_mfma_f32_16x16x32_bf16(a_hi, b_hi, acc[ni], 0, 0, 0);
      acc[ni] = __builtin_amdgcn_mfma_f32_16x16x32_bf16(a_lo, b_hi, acc[ni], 0, 0, 0);
      acc[ni] = __builtin_amdgcn_mfma_f32_16x16x32_bf16(a_hi, b_lo, acc[ni], 0, 0, 0);
    }
  }

#pragma unroll
  for (int ni = 0; ni < 4; ni++)
#pragma unroll
    for (int r = 0; r < 4; r++) red[w][lane][ni * 4 + r] = acc[ni][r];
  __syncthreads();

  if (w < 4) {
#pragma unroll
    for (int r = 0; r < 4; r++) {
      const int j = w * 4 + r;
      float val = 0.f;
#pragma unroll
      for (int ww = 0; ww < 8; ww++) val += red[ww][lane][j];
      const int mo = m0 + kgrp * 4 + r;
      const int d = w * 16 + mrow;
      if (!isv) {
        const unsigned short hb = f32_to_bf16(val);
        kc_hi[(size_t)mo * 64 + d] = hb;
        kc_lo[(size_t)mo * 64 + d] = f32_to_bf16(val - bf16_to_f32(hb));
      } else {
        vcT[(size_t)(mo >> 7) * 8192 + (size_t)d * 128 + (mo & 127)] = f32_to_bf16(val);
      }
    }
  }
}

// ---------------- gates ----------------
__global__ __launch_bounds__(256) void gates_k(const float* __restrict__ C,
                                               const float* __restrict__ Wg,
                                               const float* __restrict__ bg,
                                               float* __restrict__ gates) {
  const int w = threadIdx.x >> 6, lane = threadIdx.x & 63;
  const int t = blockIdx.x * 4 + w;
  float m = 0.f;
#pragma unroll
  for (int h = 0; h < 16; h++) m += C[(size_t)t * 3072 + h * 64 + lane];
  m *= (1.f / 16.f);
  float g0 = wred_sum(m * Wg[lane * 3 + 0]);
  float g1 = wred_sum(m * Wg[lane * 3 + 1]);
  float g2 = wred_sum(m * Wg[lane * 3 + 2]);
  if (lane == 0) {
    g0 += bg[0]; g1 += bg[1]; g2 += bg[2];
    float mx = fmaxf(g0, fmaxf(g1, g2));
    float e0 = __expf(g0 - mx), e1 = __expf(g1 - mx), e2 = __expf(g2 - mx);
    float inv = 1.f / (e0 + e1 + e2);
    gates[t * 3 + 0] = e0 * inv;
    gates[t * 3 + 1] = e1 * inv;
    gates[t * 3 + 2] = e2 * inv;
  }
}

// ------- cscore: MFMA scores + softmax + top-4 + fused PV (r7 fast argmax) -------
__global__ __launch_bounds__(256) void cscore_k(
    const float* __restrict__ qh, const unsigned short* __restrict__ kc_hi,
    const unsigned short* __restrict__ kc_lo, const unsigned short* __restrict__ vcT,
    float* __restrict__ oc, int4* __restrict__ sel) {
  __shared__ float S_s[16][132];
  const int h = blockIdx.x >> 7, t0 = (blockIdx.x & 127) * 16;
  const int tid = threadIdx.x, w = tid >> 6, lane = tid & 63;
  const int mrow = lane & 15, kgrp = lane >> 4;

  short8 a_hi[2], a_lo[2];
#pragma unroll
  for (int ks = 0; ks < 2; ks++) {
    const float* qp = &qh[(size_t)(t0 + mrow) * 1024 + h * 64 + ks * 32 + kgrp * 8];
    float4 q0 = *(const float4*)qp;
    float4 q1 = *(const float4*)(qp + 4);
    float qq[8] = {q0.x, q0.y, q0.z, q0.w, q1.x, q1.y, q1.z, q1.w};
#pragma unroll
    for (int j = 0; j < 8; j++) {
      unsigned short hb = f32_to_bf16(qq[j]);
      a_hi[ks][j] = (short)hb;
      a_lo[ks][j] = (short)f32_to_bf16(qq[j] - bf16_to_f32(hb));
    }
  }
  floatx4 zero = {0.f, 0.f, 0.f, 0.f};
  floatx4 acc[2] = {zero, zero};
#pragma unroll
  for (int ni = 0; ni < 2; ni++) {
    const int nb = w * 32 + ni * 16 + mrow;
#pragma unroll
    for (int ks = 0; ks < 2; ks++) {
      const size_t off = ((size_t)h * 128 + nb) * 64 + ks * 32 + kgrp * 8;
      short8 b_hi = *(const short8*)&kc_hi[off];
      short8 b_lo = *(const short8*)&kc_lo[off];
      acc[ni] = __builtin_amdgcn_mfma_f32_16x16x32_bf16(a_hi[ks], b_hi, acc[ni], 0, 0, 0);
      acc[ni] = __builtin_amdgcn_mfma_f32_16x16x32_bf16(a_lo[ks], b_hi, acc[ni], 0, 0, 0);
      acc[ni] = __builtin_amdgcn_mfma_f32_16x16x32_bf16(a_hi[ks], b_lo, acc[ni], 0, 0, 0);
    }
  }
#pragma unroll
  for (int ni = 0; ni < 2; ni++) {
    const int n = w * 32 + ni * 16 + mrow;
#pragma unroll
    for (int r = 0; r < 4; r++) {
      const int row = kgrp * 4 + r;
      const int count = (t0 + row) >> 4;
      S_s[row][n] = (n < count) ? acc[ni][r] * 0.125f : NEGC;
    }
  }
  __syncthreads();

#pragma unroll
  for (int qq = 0; qq < 4; qq++) {
    const int row = w * 4 + qq, t = t0 + row, count = t >> 4;
    const float2 sv = *(const float2*)&S_s[row][2 * lane];
    const float s0 = sv.x, s1 = sv.y;
    const float M = wred_max(fmaxf(s0, s1));
    const float e0 = __expf(s0 - M), e1 = __expf(s1 - M);
    const float inv = 1.f / wred_sum(e0 + e1);
    S_s[row][2 * lane]     = (count == 0) ? 0.f : e0 * inv;
    S_s[row][2 * lane + 1] = (count == 0) ? 0.f : e1 * inv;

    float c0 = s0, c1 = s1;
    float curM = M;
    int se0 = 0, se1 = 0, se2 = 0, se3 = 0;
#pragma unroll
    for (int j = 0; j < 4; j++) {
      if (j) curM = wred_max(fmaxf(c0, c1));
      const unsigned long long b = __ballot((c0 == curM) || (c1 == curM));
      const int lidx = (int)__builtin_ctzll(b);
      const float c0l = __shfl(c0, lidx, 64);
      const int isc0 = (c0l == curM);
      const int idx = 2 * lidx + (isc0 ? 0 : 1);
      if (j == 0) se0 = idx; else if (j == 1) se1 = idx;
      else if (j == 2) se2 = idx; else se3 = idx;
      if (lane == lidx) { if (isc0) c0 = -FLT_MAX; else c1 = -FLT_MAX; }
    }
    if (lane == 0) sel[((size_t)h << 11) + t] = make_int4(se0, se1, se2, se3);
  }
  __syncthreads();

  const int d = w * 16 + mrow;
  floatx4 accp = zero;
#pragma unroll
  for (int ks = 0; ks < 4; ks++) {
    const float4 p0 = *(const float4*)&S_s[mrow][ks * 32 + kgrp * 8];
    const float4 p1 = *(const float4*)&S_s[mrow][ks * 32 + kgrp * 8 + 4];
    short8 a;
    a[0] = (short)f32_to_bf16(p0.x); a[1] = (short)f32_to_bf16(p0.y);
    a[2] = (short)f32_to_bf16(p0.z); a[3] = (short)f32_to_bf16(p0.w);
    a[4] = (short)f32_to_bf16(p1.x); a[5] = (short)f32_to_bf16(p1.y);
    a[6] = (short)f32_to_bf16(p1.z); a[7] = (short)f32_to_bf16(p1.w);
    const short8 b = *(const short8*)&vcT[((size_t)h * 64 + d) * 128 + ks * 32 + kgrp * 8];
    accp = __builtin_amdgcn_mfma_f32_16x16x32_bf16(a, b, accp, 0, 0, 0);
  }
#pragma unroll
  for (int r = 0; r < 4; r++)
    oc[(size_t)(t0 + kgrp * 4 + r) * 1024 + h * 64 + d] = accp[r];
}

// ------------- selected branch only: per-wave per-(h,t), writes osel -------------
__global__ __launch_bounds__(256) void nsa_sel(
    const unsigned short* __restrict__ qhf, const unsigned short* __restrict__ khfT,
    const unsigned short* __restrict__ vhf, const int4* __restrict__ sel,
    float* __restrict__ osel) {
  __shared__ float ps[4][64];
  __shared__ int tks[4][64];
  const int bid = blockIdx.x;
  const int h = ((bid & 7) << 1) | ((bid >> 3) & 1);
  const int w = threadIdx.x >> 6, lane = threadIdx.x & 63;
  const int t = (bid >> 4) * 4 + w;

  const unsigned short* kT = khfT + (size_t)h * 131072;
  const unsigned short* vhh = vhf + (size_t)h * 131072;

  uint4 qr[8];
  {
    const uint4* qp = (const uint4*)(qhf + (size_t)t * 1024 + h * 64);
#pragma unroll
    for (int j = 0; j < 8; j++) qr[j] = qp[j];
  }
  const int4 s4 = sel[((size_t)h << 11) + t];

  const int g16 = lane >> 4;
  const int blk = (g16 == 0) ? s4.x : (g16 == 1) ? s4.y : (g16 == 2) ? s4.z : s4.w;
  const int tok = blk * 16 + (lane & 15);
  tks[w][lane] = tok;
  {
    float a0 = 0.f, a1 = 0.f, a2 = 0.f, a3 = 0.f;
#pragma unroll
    for (int dc = 0; dc < 8; dc++) {
      const uint4 kk = *(const uint4*)(kT + ((size_t)dc * 2048 + tok) * 8);
      a0 = fdot2u(kk.x, qr[dc].x, a0);
      a1 = fdot2u(kk.y, qr[dc].y, a1);
      a2 = fdot2u(kk.z, qr[dc].z, a2);
      a3 = fdot2u(kk.w, qr[dc].w, a3);
    }
    const float sv_ = (tok <= t) ? ((a0 + a1) + (a2 + a3)) * 0.125f : NEGC;
    const float Ms = wred_max(sv_);
    const float es = __expf(sv_ - Ms);
    ps[w][lane] = es * (1.f / wred_sum(es));
  }

  const int dd = lane & 31, s = lane >> 5;
  const float4* ps4 = (const float4*)ps[w];
  const int4* tk4p = (const int4*)tks[w];

  float osx = 0.f, osy = 0.f;
#pragma unroll
  for (int jc = 0; jc < 8; jc++) {
    const float4 p4 = ps4[s * 8 + jc];
    const int4 t4 = tk4p[s * 8 + jc];
    const float pa[4] = {p4.x, p4.y, p4.z, p4.w};
    const int ta[4] = {t4.x, t4.y, t4.z, t4.w};
#pragma unroll
    for (int u = 0; u < 4; u++) {
      const unsigned int vv = *(const unsigned int*)(vhh + (size_t)ta[u] * 64 + 2 * dd);
      const h2 v2 = __builtin_bit_cast(h2, vv);
      osx += pa[u] * (float)v2[0];
      osy += pa[u] * (float)v2[1];
    }
  }
  osx += __shfl_xor(osx, 32, 64);
  osy += __shfl_xor(osy, 32, 64);

  if (lane < 32)
    *(float2*)&osel[(size_t)t * 1024 + h * 64 + 2 * dd] = make_float2(osx, osy);
}

// ------------- window branch via MFMA + gated combine -> outf -------------
__global__ __launch_bounds__(256) void nsa_win(
    const unsigned short* __restrict__ qhf, const unsigned short* __restrict__ khfT,
    const unsigned short* __restrict__ vhfT, const float* __restrict__ oc,
    const float* __restrict__ osel, const float* __restrict__ gates,
    unsigned short* __restrict__ outf) {
  __shared__ unsigned short P_lds[4][16][72];
  const int bid = blockIdx.x;
  const int h = bid & 15, tq0 = (bid >> 4) * 64;
  const int w = threadIdx.x >> 6, lane = threadIdx.x & 63;
  const int cc = lane & 15, kgrp = lane >> 4;
  const int qt0 = tq0 + w * 16;
  const int kb = qt0 - 32;

  const unsigned short* kT = khfT + (size_t)h * 131072;
  const unsigned short* vT = vhfT + (size_t)h * 131072;

  short8 aq[2];
#pragma unroll
  for (int ks = 0; ks < 2; ks++)
    aq[ks] = *(const short8*)&qhf[(size_t)(qt0 + cc) * 1024 + h * 64 + ks * 32 + kgrp * 8];

  floatx4 zero = {0.f, 0.f, 0.f, 0.f};
  floatx4 accs[3] = {zero, zero, zero};
#pragma unroll
  for (int ni = 0; ni < 3; ni++) {
    const int tokc = min(max(kb + ni * 16 + cc, 0), T_LEN - 1);
#pragma unroll
    for (int ks = 0; ks < 2; ks++) {
      const short8 bk = *(const short8*)&kT[((size_t)(ks * 4 + kgrp) * 2048 + tokc) * 8];
      accs[ni] = __builtin_amdgcn_mfma_f32_16x16x32_f16(
          __builtin_bit_cast(h8, aq[ks]), __builtin_bit_cast(h8, bk), accs[ni], 0, 0, 0);
    }
  }

#pragma unroll
  for (int r = 0; r < 4; r++) {
    const int t = qt0 + kgrp * 4 + r;
    float sc[3];
#pragma unroll
    for (int ni = 0; ni < 3; ni++) {
      const int s = kb + ni * 16 + cc;
      const int ds = t - s;
      sc[ni] = (s >= 0 && ds >= 0 && ds <= 32) ? accs[ni][r] * 0.125f : NEGC;
    }
    float m3 = fmaxf(fmaxf(sc[0], sc[1]), sc[2]);
#pragma unroll
    for (int o = 1; o <= 8; o <<= 1) m3 = fmaxf(m3, __shfl_xor(m3, o, 64));
    float e0 = __expf(sc[0] - m3), e1 = __expf(sc[1] - m3), e2 = __expf(sc[2] - m3);
    float sum = e0 + e1 + e2;
#pragma unroll
    for (int o = 1; o <= 8; o <<= 1) sum += __shfl_xor(sum, o, 64);
    const float inv = 1.f / sum;
    const int row = kgrp * 4 + r;
    P_lds[w][row][cc]      = f32_to_f16u(e0 * inv);
    P_lds[w][row][16 + cc] = f32_to_f16u(e1 * inv);
    P_lds[w][row][32 + cc] = f32_to_f16u(e2 * inv);
  }
  {
    const int rr = lane >> 2, c0 = 48 + (lane & 3) * 4;
    *(ushort4*)&P_lds[w][rr][c0] = make_ushort4(0, 0, 0, 0);
  }
  __syncthreads();

  floatx4 accp[4] = {zero, zero, zero, zero};
#pragma unroll
  for (int ks2 = 0; ks2 < 2; ks2++) {
    const short8 ap = *(const short8*)&P_lds[w][cc][ks2 * 32 + kgrp * 8];
    const int tok0 = min(max(kb + ks2 * 32 + kgrp * 8, 0), T_LEN - 8);
#pragma unroll
    for (int ni = 0; ni < 4; ni++) {
      const short8 bv = *(const short8*)&vT[(size_t)(ni * 16 + cc) * 2048 + tok0];
      accp[ni] = __builtin_amdgcn_mfma_f32_16x16x32_f16(
          __builtin_bit_cast(h8, ap), __builtin_bit_cast(h8, bv), accp[ni], 0, 0, 0);
    }
  }

#pragma unroll
  for (int r = 0; r < 4; r++) {
    const int t = qt0 + kgrp * 4 + r;
    const float g0 = gates[t * 3 + 0], g1 = gates[t * 3 + 1], g2 = gates[t * 3 + 2];
#pragma unroll
    for (int ni = 0; ni < 4; ni++) {
      const int d = ni * 16 + cc;
      const float ocv = oc[(size_t)t * 1024 + h * 64 + d];
      const float osv = osel[(size_t)t * 1024 + h * 64 + d];
      outf[(size_t)t * 1024 + h * 64 + d] =
          f32_to_bf16(g0 * ocv + g1 * osv + g2 * accp[ni][r]);
    }
  }
}

// ---------------- launch ----------------
extern "C" void kernel_launch(void* const* d_in, const int* in_sizes, int n_in,
                              void* d_out, int out_size, void* d_ws, size_t ws_size,
                              hipStream_t stream) {
  const float* x   = (const float*)d_in[0];
  const float* Wq  = (const float*)d_in[1];
  const float* Wk  = (const float*)d_in[2];
  const float* Wv  = (const float*)d_in[3];
  const float* Wo  = (const float*)d_in[4];
  const float* Wck = (const float*)d_in[5];
  const float* Wcv = (const float*)d_in[6];
  const float* Wg  = (const float*)d_in[7];
  const float* bg  = (const float*)d_in[8];
  float* out = (float*)d_out;

  float* ws = (float*)d_ws;
  // region A [0,24 MB): C until compress; then osel [0,8), oc [8,16), outf [16,20)
  float*          C    = ws;
  float*          osel = ws;                                // [0,8 MB)
  float*          oc   = ws + 2097152;                      // [8,16 MB)
  unsigned short* outf = (unsigned short*)(ws + 4194304);   // [16,20 MB)
  // region B [24,36 MB): Axf (4 MB) until qkv GEMM; then qh + smalls
  unsigned short* Axf   = (unsigned short*)(ws + 6291456);
  float*          qh    = ws + 6291456;                     // [24,32 MB)
  unsigned short* Wot   = (unsigned short*)(ws + 8388608);  // [32,34 MB)
  unsigned short* kc_hi = (unsigned short*)(ws + 8912896);
  unsigned short* kc_lo = (unsigned short*)(ws + 8978432);
  unsigned short* vcT   = (unsigned short*)(ws + 9043968);
  int4*           sel   = (int4*)(ws + 9109504);
  unsigned short* WckT_hi = (unsigned short*)(ws + 9240576);
  unsigned short* WckT_lo = (unsigned short*)(ws + 9273344);
  unsigned short* WcvT_hi = (unsigned short*)(ws + 9306112);
  unsigned short* WcvT_lo = (unsigned short*)(ws + 9338880);
  float*          gates   = ws + 9371648;
  // region C [36,48 MB): Bqkv f16 (6 MB) until qkv GEMM; then qhf/khfT/vhf f16
  unsigned short* Bqkv = (unsigned short*)(ws + 9437184);   // 3072x1024 f16, 6 MB
  unsigned short* qhf  = (unsigned short*)(ws + 9437184);   // [36,40 MB)
  unsigned short* khfT = (unsigned short*)(ws + 10485760);  // [40,44 MB)
  unsigned short* vhf  = (unsigned short*)(ws + 11534336);  // [44,48 MB)
  // vhfT scratch lives in d_out (read by nsa_win, then gemm_bt64 overwrites out)
  unsigned short* vhfT = (unsigned short*)d_out;            // 16x64x2048 f16, 4 MB

  // 1. operand preparation (f16 single-pass QKV operands)
  cast_x_k<<<2048, 256, 0, stream>>>(x, Axf);
  cast_wqkv<<<dim3(32, 32, 3), dim3(32, 8), 0, stream>>>(Wq, Wk, Wv, Bqkv);

  // 2. merged q|k|v GEMM: 128x192 tile, grid (16,16) = 1 block/CU exactly
  qkv_gemm<<<dim3(16, 16), 256, 0, stream>>>(Axf, Bqkv, C);

  // 3. reorg (+ V transpose for window MFMA) + gates; late weight casts
  reorg_qkv<<<6144, 256, 0, stream>>>(C, qh, qhf, khfT, vhf);
  transp_v<<<dim3(64, 2, 16), dim3(32, 8), 0, stream>>>(vhf, vhfT);
  gates_k<<<512, 256, 0, stream>>>(C, Wg, bg, gates);
  cast_wt1<<<dim3(32, 32), dim3(32, 8), 0, stream>>>(Wo, Wot);
  cast_wct<<<dim3(2, 32, 2), dim3(32, 8), 0, stream>>>(Wck, Wcv, WckT_hi, WckT_lo, WcvT_hi, WcvT_lo);

  // 4. compression (reads C; C dead after) + compressed branch (oc aliases C tail)
  compress_mfma<<<dim3(128, 2), 512, 0, stream>>>(C, WckT_hi, WckT_lo, WcvT_hi, WcvT_lo,
                                                  kc_hi, kc_lo, vcT);
  cscore_k<<<2048, 256, 0, stream>>>(qh, kc_hi, kc_lo, vcT, oc, sel);

  // 5. selected branch (scalar, per-query) -> osel; window branch (MFMA) + combine
  nsa_sel<<<8192, 256, 0, stream>>>(qhf, khfT, vhf, sel, osel);
  nsa_win<<<512, 256, 0, stream>>>(qhf, khfT, vhfT, oc, osel, gates, outf);

  // 6. output projection (BK=64 counted-vmcnt, 16 steps)
  gemm_bt64<<<dim3(8, 32), 256, 0, stream>>>(outf, Wot, out, 1024, 1024, 1024);
}

// Round 9
// 244.021 us; speedup vs baseline: 1.0138x; 1.0138x over previous
//
#include <hip/hip_runtime.h>
#include <hip/hip_bf16.h>
#include <float.h>

#define T_LEN 2048
#define DM    1024
#define NB    128
#define NEGC  (-1e9f)

typedef __attribute__((ext_vector_type(8))) short short8;
typedef __attribute__((ext_vector_type(4))) float floatx4;
typedef _Float16 h2 __attribute__((ext_vector_type(2)));
typedef _Float16 h8 __attribute__((ext_vector_type(8)));

// ---------------- helpers ----------------
__device__ __forceinline__ float wred_max(float v) {
#pragma unroll
  for (int o = 32; o > 0; o >>= 1) v = fmaxf(v, __shfl_xor(v, o, 64));
  return v;
}
__device__ __forceinline__ float wred_sum(float v) {
#pragma unroll
  for (int o = 32; o > 0; o >>= 1) v += __shfl_xor(v, o, 64);
  return v;
}
__device__ __forceinline__ unsigned short f32_to_bf16(float f) {
  unsigned int b = __float_as_uint(f);
  return (unsigned short)((b + 0x7fffu + ((b >> 16) & 1u)) >> 16);
}
__device__ __forceinline__ float bf16_to_f32(unsigned short u) {
  return __uint_as_float(((unsigned int)u) << 16);
}
__device__ __forceinline__ unsigned int pack_h2(float a, float b) {
  h2 r; r[0] = (_Float16)a; r[1] = (_Float16)b;
  return __builtin_bit_cast(unsigned int, r);
}
__device__ __forceinline__ unsigned short f32_to_f16u(float f) {
  h2 r; r[0] = (_Float16)f; r[1] = (_Float16)0.f;
  return (unsigned short)(__builtin_bit_cast(unsigned int, r) & 0xffffu);
}
__device__ __forceinline__ float fdot2u(unsigned int a, unsigned int b, float c) {
#if __has_builtin(__builtin_amdgcn_fdot2)
  return __builtin_amdgcn_fdot2(__builtin_bit_cast(h2, a), __builtin_bit_cast(h2, b), c, false);
#else
  const h2 av = __builtin_bit_cast(h2, a), bv = __builtin_bit_cast(h2, b);
  return c + (float)av[0] * (float)bv[0] + (float)av[1] * (float)bv[1];
#endif
}
__device__ __forceinline__ void lds_async16(unsigned short* l, const unsigned short* g) {
  __builtin_amdgcn_global_load_lds(
      (const __attribute__((address_space(1))) unsigned int*)g,
      (__attribute__((address_space(3))) unsigned int*)l, 16, 0, 0);
}

// ====== 64x128-tile MFMA GEMM core — BK=32, 2-phase counted-vmcnt ======
// CONSOLIDATED BEST (r5 config, restored after r7/r8 falsifications):
// the per-step cost is exposed-latency-bound and minimized by BK=32 (small
// step), ~3 blocks/CU (TLP fills the stage wait), counted vmcnt(3) 1-ahead
// prefetch. Departures both regressed: BK=64 -> 2.7 us/step (r7); 128x192
// tile @ 1 block/CU (1 wave/SIMD, no TLP) -> 1.5 us/step (r8).
// Per wave per step: 3 lds_async16; after stage(t+1) outstanding=6, wait
// vmcnt(3) = tile t landed, t+1 stays in flight across the barrier.
// LDS layout per 16-row group (512 shorts): chunk(k/8)*128 + mrow*8 -> dest
// lane-contiguous (global_load_lds req); fragment ds_read_b128 hits bank
// mrow*4 mod 32 (2-way alias = free).
template <bool F16>
__device__ __forceinline__ void gemm64_core(
    const unsigned short* __restrict__ A, const unsigned short* __restrict__ Bt,
    float* __restrict__ C, int K, int lda, int row0, int bcol0, int ccol0, int ldc,
    unsigned short* As, unsigned short* Bs) {
  const int tid = threadIdx.x;
  const int w = tid >> 6, lane = tid & 63;
  const int wr = w >> 1, wc = w & 1;
  const int mrow = lane & 15, kgrp = lane >> 4;

  const int sr = (w << 4) + mrow;          // staged row 0..63
  const int sc = kgrp;                     // staged chunk 0..3

  floatx4 zero = {0.f, 0.f, 0.f, 0.f};
  floatx4 acc[2][4];
#pragma unroll
  for (int i = 0; i < 2; i++)
#pragma unroll
    for (int j = 0; j < 4; j++) acc[i][j] = zero;

  const int nt = K >> 5;
  const unsigned short* Ap  = A  + (size_t)(row0 + sr) * lda + sc * 8;
  const unsigned short* Bp0 = Bt + (size_t)(bcol0 + sr) * K + sc * 8;
  const unsigned short* Bp1 = Bt + (size_t)(bcol0 + 64 + sr) * K + sc * 8;

  auto stage = [&](int t, int b) {
    lds_async16(&As[b * 2048 + w * 512], Ap + t * 32);
    lds_async16(&Bs[b * 4096 + w * 512], Bp0 + t * 32);
    lds_async16(&Bs[b * 4096 + 2048 + w * 512], Bp1 + t * 32);
  };

  stage(0, 0);
  int cur = 0;
  for (int t = 0; t < nt; t++) {
    if (t + 1 < nt) {
      stage(t + 1, cur ^ 1);                              // outstanding: 6
      asm volatile("s_waitcnt vmcnt(3)" ::: "memory");    // buf[t] landed; t+1 in flight
    } else {
      asm volatile("s_waitcnt vmcnt(0)" ::: "memory");    // final tile: drain
    }
    __builtin_amdgcn_s_barrier();
    const unsigned short* as = As + cur * 2048;
    const unsigned short* bs = Bs + cur * 4096;
    short8 af[2], bf4[4];
#pragma unroll
    for (int mi = 0; mi < 2; mi++)
      af[mi] = *(const short8*)&as[(wr * 2 + mi) * 512 + kgrp * 128 + mrow * 8];
#pragma unroll
    for (int ni = 0; ni < 4; ni++)
      bf4[ni] = *(const short8*)&bs[(wc * 4 + ni) * 512 + kgrp * 128 + mrow * 8];
#pragma unroll
    for (int mi = 0; mi < 2; mi++)
#pragma unroll
      for (int ni = 0; ni < 4; ni++) {
        if constexpr (F16)
          acc[mi][ni] = __builtin_amdgcn_mfma_f32_16x16x32_f16(
              __builtin_bit_cast(h8, af[mi]), __builtin_bit_cast(h8, bf4[ni]),
              acc[mi][ni], 0, 0, 0);
        else
          acc[mi][ni] = __builtin_amdgcn_mfma_f32_16x16x32_bf16(af[mi], bf4[ni],
                                                                acc[mi][ni], 0, 0, 0);
      }
    asm volatile("" ::: "memory");
    __builtin_amdgcn_s_barrier();       // all reads of buf[cur] done before overwrite
    cur ^= 1;
  }
#pragma unroll
  for (int mi = 0; mi < 2; mi++)
#pragma unroll
    for (int ni = 0; ni < 4; ni++) {
      float* Cp = C + (size_t)(row0 + wr * 32 + mi * 16 + kgrp * 4) * ldc
                    + ccol0 + wc * 64 + ni * 16 + mrow;
      Cp[0] = acc[mi][ni][0];
      Cp[(size_t)ldc] = acc[mi][ni][1];
      Cp[(size_t)2 * ldc] = acc[mi][ni][2];
      Cp[(size_t)3 * ldc] = acc[mi][ni][3];
    }
}

// merged q|k|v GEMM: grid (24, 32) = 768 blocks (3/CU), f16 K=1024 single pass.
__global__ __launch_bounds__(256) void qkv_gemm(const unsigned short* __restrict__ Axf,
                                                const unsigned short* __restrict__ Bqkv,
                                                float* __restrict__ C) {
  __shared__ __align__(16) unsigned short As[2 * 64 * 32];
  __shared__ __align__(16) unsigned short Bs[2 * 128 * 32];
  gemm64_core<true>(Axf, Bqkv, C, 1024, 1024, blockIdx.y * 64,
                    blockIdx.x * 128, blockIdx.x * 128, 3072, As, Bs);
}

// final output projection (bf16 inputs), grid (8,32)
__global__ __launch_bounds__(256) void gemm_bt64(const unsigned short* __restrict__ A,
                                                 const unsigned short* __restrict__ Bt,
                                                 float* __restrict__ C,
                                                 int K, int lda, int ldc) {
  __shared__ __align__(16) unsigned short As[2 * 64 * 32];
  __shared__ __align__(16) unsigned short Bs[2 * 128 * 32];
  gemm64_core<false>(A, Bt, C, K, lda, blockIdx.y * 64,
                     blockIdx.x * 128, blockIdx.x * 128, ldc, As, Bs);
}

// ---------------- cast x -> f16 (2048 x 1024) ----------------
__global__ __launch_bounds__(256) void cast_x_k(const float* __restrict__ x,
                                                unsigned short* __restrict__ Axf) {
  const int gid = blockIdx.x * 256 + threadIdx.x;
  float4 xv = ((const float4*)x)[gid];
  const unsigned int p0 = pack_h2(xv.x, xv.y);
  const unsigned int p1 = pack_h2(xv.z, xv.w);
  *(uint2*)&Axf[(size_t)gid * 4] = make_uint2(p0, p1);
}

// ---- transpose-cast Wq/Wk/Wv (by blockIdx.z) into Bqkv f16 (3072n x 1024k) ----
__global__ void cast_wqkv(const float* __restrict__ Wq, const float* __restrict__ Wk,
                          const float* __restrict__ Wv, unsigned short* __restrict__ Bt) {
  __shared__ float tile[32][33];
  const float* W = (blockIdx.z == 0) ? Wq : (blockIdx.z == 1) ? Wk : Wv;
  const int n0 = blockIdx.z * 1024;
  const int kt0 = blockIdx.y * 32, nt0 = blockIdx.x * 32;
  const int tx = threadIdx.x, ty = threadIdx.y;
#pragma unroll
  for (int i = 0; i < 32; i += 8)
    tile[ty + i][tx] = W[(size_t)(kt0 + ty + i) * 1024 + nt0 + tx];
  __syncthreads();
#pragma unroll
  for (int i = 0; i < 32; i += 8) {
    const int n = nt0 + ty + i, kk = kt0 + tx;
    Bt[(size_t)(n0 + n) * 1024 + kk] = f32_to_f16u(tile[tx][ty + i]);
  }
}

// ---- transpose-cast 1024x1024 W -> Bt (1024n x 1024k) bf16 ----
__global__ void cast_wt1(const float* __restrict__ W, unsigned short* __restrict__ Bt) {
  __shared__ float tile[32][33];
  const int kt0 = blockIdx.y * 32, nt0 = blockIdx.x * 32;
  const int tx = threadIdx.x, ty = threadIdx.y;
#pragma unroll
  for (int i = 0; i < 32; i += 8)
    tile[ty + i][tx] = W[(size_t)(kt0 + ty + i) * 1024 + nt0 + tx];
  __syncthreads();
#pragma unroll
  for (int i = 0; i < 32; i += 8) {
    const int n = nt0 + ty + i, kk = kt0 + tx;
    Bt[(size_t)n * 1024 + kk] = f32_to_bf16(tile[tx][ty + i]);
  }
}

// ---- transpose-cast Wck/Wcv (1024x64) -> (64,1024) hi/lo bf16 ----
__global__ void cast_wct(const float* __restrict__ Wck, const float* __restrict__ Wcv,
                         unsigned short* __restrict__ KT_hi, unsigned short* __restrict__ KT_lo,
                         unsigned short* __restrict__ VT_hi, unsigned short* __restrict__ VT_lo) {
  __shared__ float tile[32][33];
  const float* W = blockIdx.z ? Wcv : Wck;
  unsigned short* Bh = blockIdx.z ? VT_hi : KT_hi;
  unsigned short* Bl = blockIdx.z ? VT_lo : KT_lo;
  const int kt0 = blockIdx.y * 32, nt0 = blockIdx.x * 32;
  const int tx = threadIdx.x, ty = threadIdx.y;
#pragma unroll
  for (int i = 0; i < 32; i += 8)
    tile[ty + i][tx] = W[(size_t)(kt0 + ty + i) * 64 + nt0 + tx];
  __syncthreads();
#pragma unroll
  for (int i = 0; i < 32; i += 8) {
    const int n = nt0 + ty + i, kk = kt0 + tx;
    const float f = tile[tx][ty + i];
    const unsigned short hb = f32_to_bf16(f);
    Bh[(size_t)n * 1024 + kk] = hb;
    Bl[(size_t)n * 1024 + kk] = f32_to_bf16(f - bf16_to_f32(hb));
  }
}

// ---------------- reorg: C(t,3072) -> qh f32, qhf f16 (T,1024),
//                  khfT f16 (H, 8, T, 8), vhf f16 (H, T, 64) ----------------
__global__ __launch_bounds__(256) void reorg_qkv(const float* __restrict__ C,
                                                 float* __restrict__ qh,
                                                 unsigned short* __restrict__ qhf,
                                                 unsigned short* __restrict__ khfT,
                                                 unsigned short* __restrict__ vhf) {
  const int gid = blockIdx.x * 256 + threadIdx.x;
  const int t = gid / 768;
  const int c = (gid - t * 768) * 4;
  float4 val = *(const float4*)&C[(size_t)t * 3072 + c];
  const unsigned int p0 = pack_h2(val.x, val.y);
  const unsigned int p1 = pack_h2(val.z, val.w);
  if (c < 1024) {
    *(float4*)&qh[(size_t)t * 1024 + c] = val;
    *(uint2*)&qhf[(size_t)t * 1024 + c] = make_uint2(p0, p1);
  } else if (c < 2048) {
    const int h = (c >> 6) & 15, d = c & 63;
    const int dc = d >> 3, j = d & 7;
    *(uint2*)&khfT[((size_t)(h * 8 + dc) * 2048 + t) * 8 + j] = make_uint2(p0, p1);
  } else {
    const int h = (c >> 6) & 15, d = c & 63;
    *(uint2*)&vhf[((size_t)h * 2048 + t) * 64 + d] = make_uint2(p0, p1);
  }
}

// ---- transpose vhf [h][t][64] -> vhfT [h][d][2048] f16 (for window PV MFMA) ----
__global__ void transp_v(const unsigned short* __restrict__ vhf,
                         unsigned short* __restrict__ vhfT) {
  __shared__ unsigned short tile[32][34];
  const int h = blockIdx.z;
  const int t0 = blockIdx.x * 32, d0 = blockIdx.y * 32;
  const int tx = threadIdx.x, ty = threadIdx.y;
#pragma unroll
  for (int i = 0; i < 32; i += 8)
    tile[ty + i][tx] = vhf[((size_t)h * 2048 + t0 + ty + i) * 64 + d0 + tx];
  __syncthreads();
#pragma unroll
  for (int i = 0; i < 32; i += 8)
    vhfT[((size_t)h * 64 + d0 + ty + i) * 2048 + t0 + tx] = tile[tx][ty + i];
}

// ---------------- compress via MFMA (reads k/v straight from C) ----------------
__global__ __launch_bounds__(512) void compress_mfma(
    const float* __restrict__ C,
    const unsigned short* __restrict__ KT_hi, const unsigned short* __restrict__ KT_lo,
    const unsigned short* __restrict__ VT_hi, const unsigned short* __restrict__ VT_lo,
    unsigned short* __restrict__ kc_hi, unsigned short* __restrict__ kc_lo,
    unsigned short* __restrict__ vcT) {
  __shared__ float red[8][64][17];
  const int isv = blockIdx.y;
  const unsigned short* Bh = isv ? VT_hi : KT_hi;
  const unsigned short* Bl = isv ? VT_lo : KT_lo;
  const int tid = threadIdx.x, w = tid >> 6, lane = tid & 63;
  const int mrow = lane & 15, kgrp = lane >> 4;
  const int m0 = blockIdx.x * 16;
  const int m = m0 + mrow;
  const int hh = m >> 7, nb = m & 127;
  const int cbase = 1024 + isv * 1024 + hh * 64;

  floatx4 zero = {0.f, 0.f, 0.f, 0.f};
  floatx4 acc[4] = {zero, zero, zero, zero};

  const int kbeg = w << 7;
  for (int k0 = kbeg; k0 < kbeg + 128; k0 += 32) {
    const int c = k0 + kgrp * 8;
    const float* ap = &C[(size_t)(nb * 16 + (c >> 6)) * 3072 + cbase + (c & 63)];
    float4 q0 = *(const float4*)ap;
    float4 q1 = *(const float4*)(ap + 4);
    float qq[8] = {q0.x, q0.y, q0.z, q0.w, q1.x, q1.y, q1.z, q1.w};
    short8 a_hi, a_lo;
#pragma unroll
    for (int j = 0; j < 8; j++) {
      unsigned short hb = f32_to_bf16(qq[j]);
      a_hi[j] = (short)hb;
      a_lo[j] = (short)f32_to_bf16(qq[j] - bf16_to_f32(hb));
    }
#pragma unroll
    for (int ni = 0; ni < 4; ni++) {
      const size_t boff = (size_t)(ni * 16 + mrow) * 1024 + k0 + kgrp * 8;
      short8 b_hi = *(const short8*)&Bh[boff];
      short8 b_lo = *(const short8*)&Bl[boff];
      acc[ni] = __builtin_amdgcn_mfma_f32_16x16x32_bf16(a_hi, b_hi, acc[ni], 0, 0, 0);
      acc[ni] = __builtin_amdgcn_mfma_f32_16x16x32_bf16(a_lo, b_hi, acc[ni], 0, 0, 0);
      acc[ni] = __builtin_amdgcn_mfma_f32_16x16x32_bf16(a_hi, b_lo, acc[ni], 0, 0, 0);
    }
  }

#pragma unroll
  for (int ni = 0; ni < 4; ni++)
#pragma unroll
    for (int r = 0; r < 4; r++) red[w][lane][ni * 4 + r] = acc[ni][r];
  __syncthreads();

  if (w < 4) {
#pragma unroll
    for (int r = 0; r < 4; r++) {
      const int j = w * 4 + r;
      float val = 0.f;
#pragma unroll
      for (int ww = 0; ww < 8; ww++) val += red[ww][lane][j];
      const int mo = m0 + kgrp * 4 + r;
      const int d = w * 16 + mrow;
      if (!isv) {
        const unsigned short hb = f32_to_bf16(val);
        kc_hi[(size_t)mo * 64 + d] = hb;
        kc_lo[(size_t)mo * 64 + d] = f32_to_bf16(val - bf16_to_f32(hb));
      } else {
        vcT[(size_t)(mo >> 7) * 8192 + (size_t)d * 128 + (mo & 127)] = f32_to_bf16(val);
      }
    }
  }
}

// ---------------- gates ----------------
__global__ __launch_bounds__(256) void gates_k(const float* __restrict__ C,
                                               const float* __restrict__ Wg,
                                               const float* __restrict__ bg,
                                               float* __restrict__ gates) {
  const int w = threadIdx.x >> 6, lane = threadIdx.x & 63;
  const int t = blockIdx.x * 4 + w;
  float m = 0.f;
#pragma unroll
  for (int h = 0; h < 16; h++) m += C[(size_t)t * 3072 + h * 64 + lane];
  m *= (1.f / 16.f);
  float g0 = wred_sum(m * Wg[lane * 3 + 0]);
  float g1 = wred_sum(m * Wg[lane * 3 + 1]);
  float g2 = wred_sum(m * Wg[lane * 3 + 2]);
  if (lane == 0) {
    g0 += bg[0]; g1 += bg[1]; g2 += bg[2];
    float mx = fmaxf(g0, fmaxf(g1, g2));
    float e0 = __expf(g0 - mx), e1 = __expf(g1 - mx), e2 = __expf(g2 - mx);
    float inv = 1.f / (e0 + e1 + e2);
    gates[t * 3 + 0] = e0 * inv;
    gates[t * 3 + 1] = e1 * inv;
    gates[t * 3 + 2] = e2 * inv;
  }
}

// ------- cscore: MFMA scores + softmax + top-4 + fused PV (r7 fast argmax) -------
__global__ __launch_bounds__(256) void cscore_k(
    const float* __restrict__ qh, const unsigned short* __restrict__ kc_hi,
    const unsigned short* __restrict__ kc_lo, const unsigned short* __restrict__ vcT,
    float* __restrict__ oc, int4* __restrict__ sel) {
  __shared__ float S_s[16][132];
  const int h = blockIdx.x >> 7, t0 = (blockIdx.x & 127) * 16;
  const int tid = threadIdx.x, w = tid >> 6, lane = tid & 63;
  const int mrow = lane & 15, kgrp = lane >> 4;

  short8 a_hi[2], a_lo[2];
#pragma unroll
  for (int ks = 0; ks < 2; ks++) {
    const float* qp = &qh[(size_t)(t0 + mrow) * 1024 + h * 64 + ks * 32 + kgrp * 8];
    float4 q0 = *(const float4*)qp;
    float4 q1 = *(const float4*)(qp + 4);
    float qq[8] = {q0.x, q0.y, q0.z, q0.w, q1.x, q1.y, q1.z, q1.w};
#pragma unroll
    for (int j = 0; j < 8; j++) {
      unsigned short hb = f32_to_bf16(qq[j]);
      a_hi[ks][j] = (short)hb;
      a_lo[ks][j] = (short)f32_to_bf16(qq[j] - bf16_to_f32(hb));
    }
  }
  floatx4 zero = {0.f, 0.f, 0.f, 0.f};
  floatx4 acc[2] = {zero, zero};
#pragma unroll
  for (int ni = 0; ni < 2; ni++) {
    const int nb = w * 32 + ni * 16 + mrow;
#pragma unroll
    for (int ks = 0; ks < 2; ks++) {
      const size_t off = ((size_t)h * 128 + nb) * 64 + ks * 32 + kgrp * 8;
      short8 b_hi = *(const short8*)&kc_hi[off];
      short8 b_lo = *(const short8*)&kc_lo[off];
      acc[ni] = __builtin_amdgcn_mfma_f32_16x16x32_bf16(a_hi[ks], b_hi, acc[ni], 0, 0, 0);
      acc[ni] = __builtin_amdgcn_mfma_f32_16x16x32_bf16(a_lo[ks], b_hi, acc[ni], 0, 0, 0);
      acc[ni] = __builtin_amdgcn_mfma_f32_16x16x32_bf16(a_hi[ks], b_lo, acc[ni], 0, 0, 0);
    }
  }
#pragma unroll
  for (int ni = 0; ni < 2; ni++) {
    const int n = w * 32 + ni * 16 + mrow;
#pragma unroll
    for (int r = 0; r < 4; r++) {
      const int row = kgrp * 4 + r;
      const int count = (t0 + row) >> 4;
      S_s[row][n] = (n < count) ? acc[ni][r] * 0.125f : NEGC;
    }
  }
  __syncthreads();

#pragma unroll
  for (int qq = 0; qq < 4; qq++) {
    const int row = w * 4 + qq, t = t0 + row, count = t >> 4;
    const float2 sv = *(const float2*)&S_s[row][2 * lane];
    const float s0 = sv.x, s1 = sv.y;
    const float M = wred_max(fmaxf(s0, s1));
    const float e0 = __expf(s0 - M), e1 = __expf(s1 - M);
    const float inv = 1.f / wred_sum(e0 + e1);
    S_s[row][2 * lane]     = (count == 0) ? 0.f : e0 * inv;
    S_s[row][2 * lane + 1] = (count == 0) ? 0.f : e1 * inv;

    float c0 = s0, c1 = s1;
    float curM = M;
    int se0 = 0, se1 = 0, se2 = 0, se3 = 0;
#pragma unroll
    for (int j = 0; j < 4; j++) {
      if (j) curM = wred_max(fmaxf(c0, c1));
      const unsigned long long b = __ballot((c0 == curM) || (c1 == curM));
      const int lidx = (int)__builtin_ctzll(b);
      const float c0l = __shfl(c0, lidx, 64);
      const int isc0 = (c0l == curM);
      const int idx = 2 * lidx + (isc0 ? 0 : 1);
      if (j == 0) se0 = idx; else if (j == 1) se1 = idx;
      else if (j == 2) se2 = idx; else se3 = idx;
      if (lane == lidx) { if (isc0) c0 = -FLT_MAX; else c1 = -FLT_MAX; }
    }
    if (lane == 0) sel[((size_t)h << 11) + t] = make_int4(se0, se1, se2, se3);
  }
  __syncthreads();

  const int d = w * 16 + mrow;
  floatx4 accp = zero;
#pragma unroll
  for (int ks = 0; ks < 4; ks++) {
    const float4 p0 = *(const float4*)&S_s[mrow][ks * 32 + kgrp * 8];
    const float4 p1 = *(const float4*)&S_s[mrow][ks * 32 + kgrp * 8 + 4];
    short8 a;
    a[0] = (short)f32_to_bf16(p0.x); a[1] = (short)f32_to_bf16(p0.y);
    a[2] = (short)f32_to_bf16(p0.z); a[3] = (short)f32_to_bf16(p0.w);
    a[4] = (short)f32_to_bf16(p1.x); a[5] = (short)f32_to_bf16(p1.y);
    a[6] = (short)f32_to_bf16(p1.z); a[7] = (short)f32_to_bf16(p1.w);
    const short8 b = *(const short8*)&vcT[((size_t)h * 64 + d) * 128 + ks * 32 + kgrp * 8];
    accp = __builtin_amdgcn_mfma_f32_16x16x32_bf16(a, b, accp, 0, 0, 0);
  }
#pragma unroll
  for (int r = 0; r < 4; r++)
    oc[(size_t)(t0 + kgrp * 4 + r) * 1024 + h * 64 + d] = accp[r];
}

// ------------- selected branch only: per-wave per-(h,t), writes osel -------------
__global__ __launch_bounds__(256) void nsa_sel(
    const unsigned short* __restrict__ qhf, const unsigned short* __restrict__ khfT,
    const unsigned short* __restrict__ vhf, const int4* __restrict__ sel,
    float* __restrict__ osel) {
  __shared__ float ps[4][64];
  __shared__ int tks[4][64];
  const int bid = blockIdx.x;
  const int h = ((bid & 7) << 1) | ((bid >> 3) & 1);
  const int w = threadIdx.x >> 6, lane = threadIdx.x & 63;
  const int t = (bid >> 4) * 4 + w;

  const unsigned short* kT = khfT + (size_t)h * 131072;
  const unsigned short* vhh = vhf + (size_t)h * 131072;

  uint4 qr[8];
  {
    const uint4* qp = (const uint4*)(qhf + (size_t)t * 1024 + h * 64);
#pragma unroll
    for (int j = 0; j < 8; j++) qr[j] = qp[j];
  }
  const int4 s4 = sel[((size_t)h << 11) + t];

  const int g16 = lane >> 4;
  const int blk = (g16 == 0) ? s4.x : (g16 == 1) ? s4.y : (g16 == 2) ? s4.z : s4.w;
  const int tok = blk * 16 + (lane & 15);
  tks[w][lane] = tok;
  {
    float a0 = 0.f, a1 = 0.f, a2 = 0.f, a3 = 0.f;
#pragma unroll
    for (int dc = 0; dc < 8; dc++) {
      const uint4 kk = *(const uint4*)(kT + ((size_t)dc * 2048 + tok) * 8);
      a0 = fdot2u(kk.x, qr[dc].x, a0);
      a1 = fdot2u(kk.y, qr[dc].y, a1);
      a2 = fdot2u(kk.z, qr[dc].z, a2);
      a3 = fdot2u(kk.w, qr[dc].w, a3);
    }
    const float sv_ = (tok <= t) ? ((a0 + a1) + (a2 + a3)) * 0.125f : NEGC;
    const float Ms = wred_max(sv_);
    const float es = __expf(sv_ - Ms);
    ps[w][lane] = es * (1.f / wred_sum(es));
  }

  const int dd = lane & 31, s = lane >> 5;
  const float4* ps4 = (const float4*)ps[w];
  const int4* tk4p = (const int4*)tks[w];

  float osx = 0.f, osy = 0.f;
#pragma unroll
  for (int jc = 0; jc < 8; jc++) {
    const float4 p4 = ps4[s * 8 + jc];
    const int4 t4 = tk4p[s * 8 + jc];
    const float pa[4] = {p4.x, p4.y, p4.z, p4.w};
    const int ta[4] = {t4.x, t4.y, t4.z, t4.w};
#pragma unroll
    for (int u = 0; u < 4; u++) {
      const unsigned int vv = *(const unsigned int*)(vhh + (size_t)ta[u] * 64 + 2 * dd);
      const h2 v2 = __builtin_bit_cast(h2, vv);
      osx += pa[u] * (float)v2[0];
      osy += pa[u] * (float)v2[1];
    }
  }
  osx += __shfl_xor(osx, 32, 64);
  osy += __shfl_xor(osy, 32, 64);

  if (lane < 32)
    *(float2*)&osel[(size_t)t * 1024 + h * 64 + 2 * dd] = make_float2(osx, osy);
}

// ------------- window branch via MFMA + gated combine -> outf -------------
__global__ __launch_bounds__(256) void nsa_win(
    const unsigned short* __restrict__ qhf, const unsigned short* __restrict__ khfT,
    const unsigned short* __restrict__ vhfT, const float* __restrict__ oc,
    const float* __restrict__ osel, const float* __restrict__ gates,
    unsigned short* __restrict__ outf) {
  __shared__ unsigned short P_lds[4][16][72];
  const int bid = blockIdx.x;
  const int h = bid & 15, tq0 = (bid >> 4) * 64;
  const int w = threadIdx.x >> 6, lane = threadIdx.x & 63;
  const int cc = lane & 15, kgrp = lane >> 4;
  const int qt0 = tq0 + w * 16;
  const int kb = qt0 - 32;

  const unsigned short* kT = khfT + (size_t)h * 131072;
  const unsigned short* vT = vhfT + (size_t)h * 131072;

  short8 aq[2];
#pragma unroll
  for (int ks = 0; ks < 2; ks++)
    aq[ks] = *(const short8*)&qhf[(size_t)(qt0 + cc) * 1024 + h * 64 + ks * 32 + kgrp * 8];

  floatx4 zero = {0.f, 0.f, 0.f, 0.f};
  floatx4 accs[3] = {zero, zero, zero};
#pragma unroll
  for (int ni = 0; ni < 3; ni++) {
    const int tokc = min(max(kb + ni * 16 + cc, 0), T_LEN - 1);
#pragma unroll
    for (int ks = 0; ks < 2; ks++) {
      const short8 bk = *(const short8*)&kT[((size_t)(ks * 4 + kgrp) * 2048 + tokc) * 8];
      accs[ni] = __builtin_amdgcn_mfma_f32_16x16x32_f16(
          __builtin_bit_cast(h8, aq[ks]), __builtin_bit_cast(h8, bk), accs[ni], 0, 0, 0);
    }
  }

#pragma unroll
  for (int r = 0; r < 4; r++) {
    const int t = qt0 + kgrp * 4 + r;
    float sc[3];
#pragma unroll
    for (int ni = 0; ni < 3; ni++) {
      const int s = kb + ni * 16 + cc;
      const int ds = t - s;
      sc[ni] = (s >= 0 && ds >= 0 && ds <= 32) ? accs[ni][r] * 0.125f : NEGC;
    }
    float m3 = fmaxf(fmaxf(sc[0], sc[1]), sc[2]);
#pragma unroll
    for (int o = 1; o <= 8; o <<= 1) m3 = fmaxf(m3, __shfl_xor(m3, o, 64));
    float e0 = __expf(sc[0] - m3), e1 = __expf(sc[1] - m3), e2 = __expf(sc[2] - m3);
    float sum = e0 + e1 + e2;
#pragma unroll
    for (int o = 1; o <= 8; o <<= 1) sum += __shfl_xor(sum, o, 64);
    const float inv = 1.f / sum;
    const int row = kgrp * 4 + r;
    P_lds[w][row][cc]      = f32_to_f16u(e0 * inv);
    P_lds[w][row][16 + cc] = f32_to_f16u(e1 * inv);
    P_lds[w][row][32 + cc] = f32_to_f16u(e2 * inv);
  }
  {
    const int rr = lane >> 2, c0 = 48 + (lane & 3) * 4;
    *(ushort4*)&P_lds[w][rr][c0] = make_ushort4(0, 0, 0, 0);
  }
  __syncthreads();

  floatx4 accp[4] = {zero, zero, zero, zero};
#pragma unroll
  for (int ks2 = 0; ks2 < 2; ks2++) {
    const short8 ap = *(const short8*)&P_lds[w][cc][ks2 * 32 + kgrp * 8];
    const int tok0 = min(max(kb + ks2 * 32 + kgrp * 8, 0), T_LEN - 8);
#pragma unroll
    for (int ni = 0; ni < 4; ni++) {
      const short8 bv = *(const short8*)&vT[(size_t)(ni * 16 + cc) * 2048 + tok0];
      accp[ni] = __builtin_amdgcn_mfma_f32_16x16x32_f16(
          __builtin_bit_cast(h8, ap), __builtin_bit_cast(h8, bv), accp[ni], 0, 0, 0);
    }
  }

#pragma unroll
  for (int r = 0; r < 4; r++) {
    const int t = qt0 + kgrp * 4 + r;
    const float g0 = gates[t * 3 + 0], g1 = gates[t * 3 + 1], g2 = gates[t * 3 + 2];
#pragma unroll
    for (int ni = 0; ni < 4; ni++) {
      const int d = ni * 16 + cc;
      const float ocv = oc[(size_t)t * 1024 + h * 64 + d];
      const float osv = osel[(size_t)t * 1024 + h * 64 + d];
      outf[(size_t)t * 1024 + h * 64 + d] =
          f32_to_bf16(g0 * ocv + g1 * osv + g2 * accp[ni][r]);
    }
  }
}

// ---------------- launch ----------------
extern "C" void kernel_launch(void* const* d_in, const int* in_sizes, int n_in,
                              void* d_out, int out_size, void* d_ws, size_t ws_size,
                              hipStream_t stream) {
  const float* x   = (const float*)d_in[0];
  const float* Wq  = (const float*)d_in[1];
  const float* Wk  = (const float*)d_in[2];
  const float* Wv  = (const float*)d_in[3];
  const float* Wo  = (const float*)d_in[4];
  const float* Wck = (const float*)d_in[5];
  const float* Wcv = (const float*)d_in[6];
  const float* Wg  = (const float*)d_in[7];
  const float* bg  = (const float*)d_in[8];
  float* out = (float*)d_out;

  float* ws = (float*)d_ws;
  // region A [0,24 MB): C until compress; then osel [0,8), oc [8,16), outf [16,20)
  float*          C    = ws;
  float*          osel = ws;                                // [0,8 MB)
  float*          oc   = ws + 2097152;                      // [8,16 MB)
  unsigned short* outf = (unsigned short*)(ws + 4194304);   // [16,20 MB)
  // region B [24,36 MB): Axf (4 MB) until qkv GEMM; then qh + smalls
  unsigned short* Axf   = (unsigned short*)(ws + 6291456);
  float*          qh    = ws + 6291456;                     // [24,32 MB)
  unsigned short* Wot   = (unsigned short*)(ws + 8388608);  // [32,34 MB)
  unsigned short* kc_hi = (unsigned short*)(ws + 8912896);
  unsigned short* kc_lo = (unsigned short*)(ws + 8978432);
  unsigned short* vcT   = (unsigned short*)(ws + 9043968);
  int4*           sel   = (int4*)(ws + 9109504);
  unsigned short* WckT_hi = (unsigned short*)(ws + 9240576);
  unsigned short* WckT_lo = (unsigned short*)(ws + 9273344);
  unsigned short* WcvT_hi = (unsigned short*)(ws + 9306112);
  unsigned short* WcvT_lo = (unsigned short*)(ws + 9338880);
  float*          gates   = ws + 9371648;
  // region C [36,48 MB): Bqkv f16 (6 MB) until qkv GEMM; then qhf/khfT/vhf f16
  unsigned short* Bqkv = (unsigned short*)(ws + 9437184);   // 3072x1024 f16, 6 MB
  unsigned short* qhf  = (unsigned short*)(ws + 9437184);   // [36,40 MB)
  unsigned short* khfT = (unsigned short*)(ws + 10485760);  // [40,44 MB)
  unsigned short* vhf  = (unsigned short*)(ws + 11534336);  // [44,48 MB)
  // vhfT scratch lives in d_out (read by nsa_win, then gemm_bt64 overwrites out)
  unsigned short* vhfT = (unsigned short*)d_out;            // 16x64x2048 f16, 4 MB

  // 1. operand preparation (f16 single-pass QKV operands)
  cast_x_k<<<2048, 256, 0, stream>>>(x, Axf);
  cast_wqkv<<<dim3(32, 32, 3), dim3(32, 8), 0, stream>>>(Wq, Wk, Wv, Bqkv);

  // 2. merged q|k|v GEMM: 64x128 BK=32 counted-vmcnt, 768 blocks (3/CU) — r5 best
  qkv_gemm<<<dim3(24, 32), 256, 0, stream>>>(Axf, Bqkv, C);

  // 3. reorg (+ V transpose for window MFMA) + gates; late weight casts
  reorg_qkv<<<6144, 256, 0, stream>>>(C, qh, qhf, khfT, vhf);
  transp_v<<<dim3(64, 2, 16), dim3(32, 8), 0, stream>>>(vhf, vhfT);
  gates_k<<<512, 256, 0, stream>>>(C, Wg, bg, gates);
  cast_wt1<<<dim3(32, 32), dim3(32, 8), 0, stream>>>(Wo, Wot);
  cast_wct<<<dim3(2, 32, 2), dim3(32, 8), 0, stream>>>(Wck, Wcv, WckT_hi, WckT_lo, WcvT_hi, WcvT_lo);

  // 4. compression (reads C; C dead after) + compressed branch (oc aliases C tail)
  compress_mfma<<<dim3(128, 2), 512, 0, stream>>>(C, WckT_hi, WckT_lo, WcvT_hi, WcvT_lo,
                                                  kc_hi, kc_lo, vcT);
  cscore_k<<<2048, 256, 0, stream>>>(qh, kc_hi, kc_lo, vcT, oc, sel);

  // 5. selected branch (scalar, per-query) -> osel; window branch (MFMA) + combine
  nsa_sel<<<8192, 256, 0, stream>>>(qhf, khfT, vhf, sel, osel);
  nsa_win<<<512, 256, 0, stream>>>(qhf, khfT, vhfT, oc, osel, gates, outf);

  // 6. output projection (64x128 BK=32 counted-vmcnt)
  gemm_bt64<<<dim3(8, 32), 256, 0, stream>>>(outf, Wot, out, 1024, 1024, 1024);
}

// Round 10
// 242.363 us; speedup vs baseline: 1.0207x; 1.0068x over previous
//
#include <hip/hip_runtime.h>
#include <hip/hip_bf16.h>
#include <float.h>

#define T_LEN 2048
#define DM    1024
#define NB    128
#define NEGC  (-1e9f)

typedef __attribute__((ext_vector_type(8))) short short8;
typedef __attribute__((ext_vector_type(4))) float floatx4;
typedef _Float16 h2 __attribute__((ext_vector_type(2)));
typedef _Float16 h8 __attribute__((ext_vector_type(8)));

// ---------------- helpers ----------------
__device__ __forceinline__ float wred_max(float v) {
#pragma unroll
  for (int o = 32; o > 0; o >>= 1) v = fmaxf(v, __shfl_xor(v, o, 64));
  return v;
}
__device__ __forceinline__ float wred_sum(float v) {
#pragma unroll
  for (int o = 32; o > 0; o >>= 1) v += __shfl_xor(v, o, 64);
  return v;
}
__device__ __forceinline__ unsigned short f32_to_bf16(float f) {
  unsigned int b = __float_as_uint(f);
  return (unsigned short)((b + 0x7fffu + ((b >> 16) & 1u)) >> 16);
}
__device__ __forceinline__ float bf16_to_f32(unsigned short u) {
  return __uint_as_float(((unsigned int)u) << 16);
}
__device__ __forceinline__ unsigned int pack_h2(float a, float b) {
  h2 r; r[0] = (_Float16)a; r[1] = (_Float16)b;
  return __builtin_bit_cast(unsigned int, r);
}
__device__ __forceinline__ unsigned short f32_to_f16u(float f) {
  h2 r; r[0] = (_Float16)f; r[1] = (_Float16)0.f;
  return (unsigned short)(__builtin_bit_cast(unsigned int, r) & 0xffffu);
}
__device__ __forceinline__ float fdot2u(unsigned int a, unsigned int b, float c) {
#if __has_builtin(__builtin_amdgcn_fdot2)
  return __builtin_amdgcn_fdot2(__builtin_bit_cast(h2, a), __builtin_bit_cast(h2, b), c, false);
#else
  const h2 av = __builtin_bit_cast(h2, a), bv = __builtin_bit_cast(h2, b);
  return c + (float)av[0] * (float)bv[0] + (float)av[1] * (float)bv[1];
#endif
}
__device__ __forceinline__ void lds_async16(unsigned short* l, const unsigned short* g) {
  __builtin_amdgcn_global_load_lds(
      (const __attribute__((address_space(1))) unsigned int*)g,
      (__attribute__((address_space(3))) unsigned int*)l, 16, 0, 0);
}

// ====== 64x128-tile MFMA GEMM core — BK=32, 3-buffer 2-AHEAD counted-vmcnt ======
// r10 experiment on the r5-proven skeleton: the only change is prefetch depth
// 1 -> 2 (3 LDS buffers, 36 KB — LDS allows 4 blocks/CU, grid keeps 3).
// Discriminates the two surviving GEMM-floor models:
//   (a) staging-issue/BW floor (~13 B/cy/CU)  -> null result, GEMMs are done;
//   (b) exposed-L2-latency floor (1-deep prefetch gives loads only ~1 step
//       of slack; 2-deep gives ~2 steps)      -> qkv ~36 -> ~27-30 us.
// vmcnt: after stage(t+2) outstanding = 9 (t,t+1,t+2); vmcnt(6) retires the
// 3 oldest = tile t. Tail: vmcnt(3) at t=nt-2, vmcnt(0) at t=nt-1.
// Buffer safety: buf[(t+2)%3] last read at tile t-1; those reads completed
// before iteration t-1's closing barrier (ds_reads drain before MFMA use,
// which precedes the barrier) — same invariant as the working 2-buffer core.
template <bool F16>
__device__ __forceinline__ void gemm64_core(
    const unsigned short* __restrict__ A, const unsigned short* __restrict__ Bt,
    float* __restrict__ C, int K, int lda, int row0, int bcol0, int ccol0, int ldc,
    unsigned short* As, unsigned short* Bs) {
  const int tid = threadIdx.x;
  const int w = tid >> 6, lane = tid & 63;
  const int wr = w >> 1, wc = w & 1;
  const int mrow = lane & 15, kgrp = lane >> 4;

  const int sr = (w << 4) + mrow;          // staged row 0..63
  const int sc = kgrp;                     // staged chunk 0..3

  floatx4 zero = {0.f, 0.f, 0.f, 0.f};
  floatx4 acc[2][4];
#pragma unroll
  for (int i = 0; i < 2; i++)
#pragma unroll
    for (int j = 0; j < 4; j++) acc[i][j] = zero;

  const int nt = K >> 5;
  const unsigned short* Ap  = A  + (size_t)(row0 + sr) * lda + sc * 8;
  const unsigned short* Bp0 = Bt + (size_t)(bcol0 + sr) * K + sc * 8;
  const unsigned short* Bp1 = Bt + (size_t)(bcol0 + 64 + sr) * K + sc * 8;

  auto stage = [&](int t, int b) {
    lds_async16(&As[b * 2048 + w * 512], Ap + t * 32);
    lds_async16(&Bs[b * 4096 + w * 512], Bp0 + t * 32);
    lds_async16(&Bs[b * 4096 + 2048 + w * 512], Bp1 + t * 32);
  };

  stage(0, 0);
  if (nt > 1) stage(1, 1);
  int cur = 0;
  for (int t = 0; t < nt; t++) {
    if (t + 2 < nt) {
      const int nx = (cur + 2 >= 3) ? cur - 1 : cur + 2;
      stage(t + 2, nx);                                   // outstanding: 9
      asm volatile("s_waitcnt vmcnt(6)" ::: "memory");    // tile t landed; t+1,t+2 in flight
    } else if (t + 1 < nt) {
      asm volatile("s_waitcnt vmcnt(3)" ::: "memory");    // tile t landed; t+1 in flight
    } else {
      asm volatile("s_waitcnt vmcnt(0)" ::: "memory");    // final tile: drain
    }
    __builtin_amdgcn_s_barrier();
    const unsigned short* as = As + cur * 2048;
    const unsigned short* bs = Bs + cur * 4096;
    short8 af[2], bf4[4];
#pragma unroll
    for (int mi = 0; mi < 2; mi++)
      af[mi] = *(const short8*)&as[(wr * 2 + mi) * 512 + kgrp * 128 + mrow * 8];
#pragma unroll
    for (int ni = 0; ni < 4; ni++)
      bf4[ni] = *(const short8*)&bs[(wc * 4 + ni) * 512 + kgrp * 128 + mrow * 8];
#pragma unroll
    for (int mi = 0; mi < 2; mi++)
#pragma unroll
      for (int ni = 0; ni < 4; ni++) {
        if constexpr (F16)
          acc[mi][ni] = __builtin_amdgcn_mfma_f32_16x16x32_f16(
              __builtin_bit_cast(h8, af[mi]), __builtin_bit_cast(h8, bf4[ni]),
              acc[mi][ni], 0, 0, 0);
        else
          acc[mi][ni] = __builtin_amdgcn_mfma_f32_16x16x32_bf16(af[mi], bf4[ni],
                                                                acc[mi][ni], 0, 0, 0);
      }
    asm volatile("" ::: "memory");
    __builtin_amdgcn_s_barrier();       // all reads of buf[cur] done before overwrite
    cur = (cur + 1 == 3) ? 0 : cur + 1;
  }
#pragma unroll
  for (int mi = 0; mi < 2; mi++)
#pragma unroll
    for (int ni = 0; ni < 4; ni++) {
      float* Cp = C + (size_t)(row0 + wr * 32 + mi * 16 + kgrp * 4) * ldc
                    + ccol0 + wc * 64 + ni * 16 + mrow;
      Cp[0] = acc[mi][ni][0];
      Cp[(size_t)ldc] = acc[mi][ni][1];
      Cp[(size_t)2 * ldc] = acc[mi][ni][2];
      Cp[(size_t)3 * ldc] = acc[mi][ni][3];
    }
}

// merged q|k|v GEMM: grid (24, 32) = 768 blocks (3/CU), f16 K=1024 single pass.
__global__ __launch_bounds__(256) void qkv_gemm(const unsigned short* __restrict__ Axf,
                                                const unsigned short* __restrict__ Bqkv,
                                                float* __restrict__ C) {
  __shared__ __align__(16) unsigned short As[3 * 64 * 32];
  __shared__ __align__(16) unsigned short Bs[3 * 128 * 32];
  gemm64_core<true>(Axf, Bqkv, C, 1024, 1024, blockIdx.y * 64,
                    blockIdx.x * 128, blockIdx.x * 128, 3072, As, Bs);
}

// final output projection (bf16 inputs), grid (8,32)
__global__ __launch_bounds__(256) void gemm_bt64(const unsigned short* __restrict__ A,
                                                 const unsigned short* __restrict__ Bt,
                                                 float* __restrict__ C,
                                                 int K, int lda, int ldc) {
  __shared__ __align__(16) unsigned short As[3 * 64 * 32];
  __shared__ __align__(16) unsigned short Bs[3 * 128 * 32];
  gemm64_core<false>(A, Bt, C, K, lda, blockIdx.y * 64,
                     blockIdx.x * 128, blockIdx.x * 128, ldc, As, Bs);
}

// ---------------- cast x -> f16 (2048 x 1024) ----------------
__global__ __launch_bounds__(256) void cast_x_k(const float* __restrict__ x,
                                                unsigned short* __restrict__ Axf) {
  const int gid = blockIdx.x * 256 + threadIdx.x;
  float4 xv = ((const float4*)x)[gid];
  const unsigned int p0 = pack_h2(xv.x, xv.y);
  const unsigned int p1 = pack_h2(xv.z, xv.w);
  *(uint2*)&Axf[(size_t)gid * 4] = make_uint2(p0, p1);
}

// ---- transpose-cast Wq/Wk/Wv (by blockIdx.z) into Bqkv f16 (3072n x 1024k) ----
__global__ void cast_wqkv(const float* __restrict__ Wq, const float* __restrict__ Wk,
                          const float* __restrict__ Wv, unsigned short* __restrict__ Bt) {
  __shared__ float tile[32][33];
  const float* W = (blockIdx.z == 0) ? Wq : (blockIdx.z == 1) ? Wk : Wv;
  const int n0 = blockIdx.z * 1024;
  const int kt0 = blockIdx.y * 32, nt0 = blockIdx.x * 32;
  const int tx = threadIdx.x, ty = threadIdx.y;
#pragma unroll
  for (int i = 0; i < 32; i += 8)
    tile[ty + i][tx] = W[(size_t)(kt0 + ty + i) * 1024 + nt0 + tx];
  __syncthreads();
#pragma unroll
  for (int i = 0; i < 32; i += 8) {
    const int n = nt0 + ty + i, kk = kt0 + tx;
    Bt[(size_t)(n0 + n) * 1024 + kk] = f32_to_f16u(tile[tx][ty + i]);
  }
}

// ---- transpose-cast 1024x1024 W -> Bt (1024n x 1024k) bf16 ----
__global__ void cast_wt1(const float* __restrict__ W, unsigned short* __restrict__ Bt) {
  __shared__ float tile[32][33];
  const int kt0 = blockIdx.y * 32, nt0 = blockIdx.x * 32;
  const int tx = threadIdx.x, ty = threadIdx.y;
#pragma unroll
  for (int i = 0; i < 32; i += 8)
    tile[ty + i][tx] = W[(size_t)(kt0 + ty + i) * 1024 + nt0 + tx];
  __syncthreads();
#pragma unroll
  for (int i = 0; i < 32; i += 8) {
    const int n = nt0 + ty + i, kk = kt0 + tx;
    Bt[(size_t)n * 1024 + kk] = f32_to_bf16(tile[tx][ty + i]);
  }
}

// ---- transpose-cast Wck/Wcv (1024x64) -> (64,1024) hi/lo bf16 ----
__global__ void cast_wct(const float* __restrict__ Wck, const float* __restrict__ Wcv,
                         unsigned short* __restrict__ KT_hi, unsigned short* __restrict__ KT_lo,
                         unsigned short* __restrict__ VT_hi, unsigned short* __restrict__ VT_lo) {
  __shared__ float tile[32][33];
  const float* W = blockIdx.z ? Wcv : Wck;
  unsigned short* Bh = blockIdx.z ? VT_hi : KT_hi;
  unsigned short* Bl = blockIdx.z ? VT_lo : KT_lo;
  const int kt0 = blockIdx.y * 32, nt0 = blockIdx.x * 32;
  const int tx = threadIdx.x, ty = threadIdx.y;
#pragma unroll
  for (int i = 0; i < 32; i += 8)
    tile[ty + i][tx] = W[(size_t)(kt0 + ty + i) * 64 + nt0 + tx];
  __syncthreads();
#pragma unroll
  for (int i = 0; i < 32; i += 8) {
    const int n = nt0 + ty + i, kk = kt0 + tx;
    const float f = tile[tx][ty + i];
    const unsigned short hb = f32_to_bf16(f);
    Bh[(size_t)n * 1024 + kk] = hb;
    Bl[(size_t)n * 1024 + kk] = f32_to_bf16(f - bf16_to_f32(hb));
  }
}

// ---------------- reorg: C(t,3072) -> qh f32, qhf f16 (T,1024),
//                  khfT f16 (H, 8, T, 8), vhf f16 (H, T, 64) ----------------
__global__ __launch_bounds__(256) void reorg_qkv(const float* __restrict__ C,
                                                 float* __restrict__ qh,
                                                 unsigned short* __restrict__ qhf,
                                                 unsigned short* __restrict__ khfT,
                                                 unsigned short* __restrict__ vhf) {
  const int gid = blockIdx.x * 256 + threadIdx.x;
  const int t = gid / 768;
  const int c = (gid - t * 768) * 4;
  float4 val = *(const float4*)&C[(size_t)t * 3072 + c];
  const unsigned int p0 = pack_h2(val.x, val.y);
  const unsigned int p1 = pack_h2(val.z, val.w);
  if (c < 1024) {
    *(float4*)&qh[(size_t)t * 1024 + c] = val;
    *(uint2*)&qhf[(size_t)t * 1024 + c] = make_uint2(p0, p1);
  } else if (c < 2048) {
    const int h = (c >> 6) & 15, d = c & 63;
    const int dc = d >> 3, j = d & 7;
    *(uint2*)&khfT[((size_t)(h * 8 + dc) * 2048 + t) * 8 + j] = make_uint2(p0, p1);
  } else {
    const int h = (c >> 6) & 15, d = c & 63;
    *(uint2*)&vhf[((size_t)h * 2048 + t) * 64 + d] = make_uint2(p0, p1);
  }
}

// ---- transpose vhf [h][t][64] -> vhfT [h][d][2048] f16 (for window PV MFMA) ----
__global__ void transp_v(const unsigned short* __restrict__ vhf,
                         unsigned short* __restrict__ vhfT) {
  __shared__ unsigned short tile[32][34];
  const int h = blockIdx.z;
  const int t0 = blockIdx.x * 32, d0 = blockIdx.y * 32;
  const int tx = threadIdx.x, ty = threadIdx.y;
#pragma unroll
  for (int i = 0; i < 32; i += 8)
    tile[ty + i][tx] = vhf[((size_t)h * 2048 + t0 + ty + i) * 64 + d0 + tx];
  __syncthreads();
#pragma unroll
  for (int i = 0; i < 32; i += 8)
    vhfT[((size_t)h * 64 + d0 + ty + i) * 2048 + t0 + tx] = tile[tx][ty + i];
}

// ---------------- compress via MFMA (reads k/v straight from C) ----------------
__global__ __launch_bounds__(512) void compress_mfma(
    const float* __restrict__ C,
    const unsigned short* __restrict__ KT_hi, const unsigned short* __restrict__ KT_lo,
    const unsigned short* __restrict__ VT_hi, const unsigned short* __restrict__ VT_lo,
    unsigned short* __restrict__ kc_hi, unsigned short* __restrict__ kc_lo,
    unsigned short* __restrict__ vcT) {
  __shared__ float red[8][64][17];
  const int isv = blockIdx.y;
  const unsigned short* Bh = isv ? VT_hi : KT_hi;
  const unsigned short* Bl = isv ? VT_lo : KT_lo;
  const int tid = threadIdx.x, w = tid >> 6, lane = tid & 63;
  const int mrow = lane & 15, kgrp = lane >> 4;
  const int m0 = blockIdx.x * 16;
  const int m = m0 + mrow;
  const int hh = m >> 7, nb = m & 127;
  const int cbase = 1024 + isv * 1024 + hh * 64;

  floatx4 zero = {0.f, 0.f, 0.f, 0.f};
  floatx4 acc[4] = {zero, zero, zero, zero};

  const int kbeg = w << 7;
  for (int k0 = kbeg; k0 < kbeg + 128; k0 += 32) {
    const int c = k0 + kgrp * 8;
    const float* ap = &C[(size_t)(nb * 16 + (c >> 6)) * 3072 + cbase + (c & 63)];
    float4 q0 = *(const float4*)ap;
    float4 q1 = *(const float4*)(ap + 4);
    float qq[8] = {q0.x, q0.y, q0.z, q0.w, q1.x, q1.y, q1.z, q1.w};
    short8 a_hi, a_lo;
#pragma unroll
    for (int j = 0; j < 8; j++) {
      unsigned short hb = f32_to_bf16(qq[j]);
      a_hi[j] = (short)hb;
      a_lo[j] = (short)f32_to_bf16(qq[j] - bf16_to_f32(hb));
    }
#pragma unroll
    for (int ni = 0; ni < 4; ni++) {
      const size_t boff = (size_t)(ni * 16 + mrow) * 1024 + k0 + kgrp * 8;
      short8 b_hi = *(const short8*)&Bh[boff];
      short8 b_lo = *(const short8*)&Bl[boff];
      acc[ni] = __builtin_amdgcn_mfma_f32_16x16x32_bf16(a_hi, b_hi, acc[ni], 0, 0, 0);
      acc[ni] = __builtin_amdgcn_mfma_f32_16x16x32_bf16(a_lo, b_hi, acc[ni], 0, 0, 0);
      acc[ni] = __builtin_amdgcn_mfma_f32_16x16x32_bf16(a_hi, b_lo, acc[ni], 0, 0, 0);
    }
  }

#pragma unroll
  for (int ni = 0; ni < 4; ni++)
#pragma unroll
    for (int r = 0; r < 4; r++) red[w][lane][ni * 4 + r] = acc[ni][r];
  __syncthreads();

  if (w < 4) {
#pragma unroll
    for (int r = 0; r < 4; r++) {
      const int j = w * 4 + r;
      float val = 0.f;
#pragma unroll
      for (int ww = 0; ww < 8; ww++) val += red[ww][lane][j];
      const int mo = m0 + kgrp * 4 + r;
      const int d = w * 16 + mrow;
      if (!isv) {
        const unsigned short hb = f32_to_bf16(val);
        kc_hi[(size_t)mo * 64 + d] = hb;
        kc_lo[(size_t)mo * 64 + d] = f32_to_bf16(val - bf16_to_f32(hb));
      } else {
        vcT[(size_t)(mo >> 7) * 8192 + (size_t)d * 128 + (mo & 127)] = f32_to_bf16(val);
      }
    }
  }
}

// ---------------- gates ----------------
__global__ __launch_bounds__(256) void gates_k(const float* __restrict__ C,
                                               const float* __restrict__ Wg,
                                               const float* __restrict__ bg,
                                               float* __restrict__ gates) {
  const int w = threadIdx.x >> 6, lane = threadIdx.x & 63;
  const int t = blockIdx.x * 4 + w;
  float m = 0.f;
#pragma unroll
  for (int h = 0; h < 16; h++) m += C[(size_t)t * 3072 + h * 64 + lane];
  m *= (1.f / 16.f);
  float g0 = wred_sum(m * Wg[lane * 3 + 0]);
  float g1 = wred_sum(m * Wg[lane * 3 + 1]);
  float g2 = wred_sum(m * Wg[lane * 3 + 2]);
  if (lane == 0) {
    g0 += bg[0]; g1 += bg[1]; g2 += bg[2];
    float mx = fmaxf(g0, fmaxf(g1, g2));
    float e0 = __expf(g0 - mx), e1 = __expf(g1 - mx), e2 = __expf(g2 - mx);
    float inv = 1.f / (e0 + e1 + e2);
    gates[t * 3 + 0] = e0 * inv;
    gates[t * 3 + 1] = e1 * inv;
    gates[t * 3 + 2] = e2 * inv;
  }
}

// ------- cscore: MFMA scores + softmax + top-4 + fused PV (r7 fast argmax) -------
__global__ __launch_bounds__(256) void cscore_k(
    const float* __restrict__ qh, const unsigned short* __restrict__ kc_hi,
    const unsigned short* __restrict__ kc_lo, const unsigned short* __restrict__ vcT,
    float* __restrict__ oc, int4* __restrict__ sel) {
  __shared__ float S_s[16][132];
  const int h = blockIdx.x >> 7, t0 = (blockIdx.x & 127) * 16;
  const int tid = threadIdx.x, w = tid >> 6, lane = tid & 63;
  const int mrow = lane & 15, kgrp = lane >> 4;

  short8 a_hi[2], a_lo[2];
#pragma unroll
  for (int ks = 0; ks < 2; ks++) {
    const float* qp = &qh[(size_t)(t0 + mrow) * 1024 + h * 64 + ks * 32 + kgrp * 8];
    float4 q0 = *(const float4*)qp;
    float4 q1 = *(const float4*)(qp + 4);
    float qq[8] = {q0.x, q0.y, q0.z, q0.w, q1.x, q1.y, q1.z, q1.w};
#pragma unroll
    for (int j = 0; j < 8; j++) {
      unsigned short hb = f32_to_bf16(qq[j]);
      a_hi[ks][j] = (short)hb;
      a_lo[ks][j] = (short)f32_to_bf16(qq[j] - bf16_to_f32(hb));
    }
  }
  floatx4 zero = {0.f, 0.f, 0.f, 0.f};
  floatx4 acc[2] = {zero, zero};
#pragma unroll
  for (int ni = 0; ni < 2; ni++) {
    const int nb = w * 32 + ni * 16 + mrow;
#pragma unroll
    for (int ks = 0; ks < 2; ks++) {
      const size_t off = ((size_t)h * 128 + nb) * 64 + ks * 32 + kgrp * 8;
      short8 b_hi = *(const short8*)&kc_hi[off];
      short8 b_lo = *(const short8*)&kc_lo[off];
      acc[ni] = __builtin_amdgcn_mfma_f32_16x16x32_bf16(a_hi[ks], b_hi, acc[ni], 0, 0, 0);
      acc[ni] = __builtin_amdgcn_mfma_f32_16x16x32_bf16(a_lo[ks], b_hi, acc[ni], 0, 0, 0);
      acc[ni] = __builtin_amdgcn_mfma_f32_16x16x32_bf16(a_hi[ks], b_lo, acc[ni], 0, 0, 0);
    }
  }
#pragma unroll
  for (int ni = 0; ni < 2; ni++) {
    const int n = w * 32 + ni * 16 + mrow;
#pragma unroll
    for (int r = 0; r < 4; r++) {
      const int row = kgrp * 4 + r;
      const int count = (t0 + row) >> 4;
      S_s[row][n] = (n < count) ? acc[ni][r] * 0.125f : NEGC;
    }
  }
  __syncthreads();

#pragma unroll
  for (int qq = 0; qq < 4; qq++) {
    const int row = w * 4 + qq, t = t0 + row, count = t >> 4;
    const float2 sv = *(const float2*)&S_s[row][2 * lane];
    const float s0 = sv.x, s1 = sv.y;
    const float M = wred_max(fmaxf(s0, s1));
    const float e0 = __expf(s0 - M), e1 = __expf(s1 - M);
    const float inv = 1.f / wred_sum(e0 + e1);
    S_s[row][2 * lane]     = (count == 0) ? 0.f : e0 * inv;
    S_s[row][2 * lane + 1] = (count == 0) ? 0.f : e1 * inv;

    float c0 = s0, c1 = s1;
    float curM = M;
    int se0 = 0, se1 = 0, se2 = 0, se3 = 0;
#pragma unroll
    for (int j = 0; j < 4; j++) {
      if (j) curM = wred_max(fmaxf(c0, c1));
      const unsigned long long b = __ballot((c0 == curM) || (c1 == curM));
      const int lidx = (int)__builtin_ctzll(b);
      const float c0l = __shfl(c0, lidx, 64);
      const int isc0 = (c0l == curM);
      const int idx = 2 * lidx + (isc0 ? 0 : 1);
      if (j == 0) se0 = idx; else if (j == 1) se1 = idx;
      else if (j == 2) se2 = idx; else se3 = idx;
      if (lane == lidx) { if (isc0) c0 = -FLT_MAX; else c1 = -FLT_MAX; }
    }
    if (lane == 0) sel[((size_t)h << 11) + t] = make_int4(se0, se1, se2, se3);
  }
  __syncthreads();

  const int d = w * 16 + mrow;
  floatx4 accp = zero;
#pragma unroll
  for (int ks = 0; ks < 4; ks++) {
    const float4 p0 = *(const float4*)&S_s[mrow][ks * 32 + kgrp * 8];
    const float4 p1 = *(const float4*)&S_s[mrow][ks * 32 + kgrp * 8 + 4];
    short8 a;
    a[0] = (short)f32_to_bf16(p0.x); a[1] = (short)f32_to_bf16(p0.y);
    a[2] = (short)f32_to_bf16(p0.z); a[3] = (short)f32_to_bf16(p0.w);
    a[4] = (short)f32_to_bf16(p1.x); a[5] = (short)f32_to_bf16(p1.y);
    a[6] = (short)f32_to_bf16(p1.z); a[7] = (short)f32_to_bf16(p1.w);
    const short8 b = *(const short8*)&vcT[((size_t)h * 64 + d) * 128 + ks * 32 + kgrp * 8];
    accp = __builtin_amdgcn_mfma_f32_16x16x32_bf16(a, b, accp, 0, 0, 0);
  }
#pragma unroll
  for (int r = 0; r < 4; r++)
    oc[(size_t)(t0 + kgrp * 4 + r) * 1024 + h * 64 + d] = accp[r];
}

// ------------- selected branch only: per-wave per-(h,t), writes osel -------------
__global__ __launch_bounds__(256) void nsa_sel(
    const unsigned short* __restrict__ qhf, const unsigned short* __restrict__ khfT,
    const unsigned short* __restrict__ vhf, const int4* __restrict__ sel,
    float* __restrict__ osel) {
  __shared__ float ps[4][64];
  __shared__ int tks[4][64];
  const int bid = blockIdx.x;
  const int h = ((bid & 7) << 1) | ((bid >> 3) & 1);
  const int w = threadIdx.x >> 6, lane = threadIdx.x & 63;
  const int t = (bid >> 4) * 4 + w;

  const unsigned short* kT = khfT + (size_t)h * 131072;
  const unsigned short* vhh = vhf + (size_t)h * 131072;

  uint4 qr[8];
  {
    const uint4* qp = (const uint4*)(qhf + (size_t)t * 1024 + h * 64);
#pragma unroll
    for (int j = 0; j < 8; j++) qr[j] = qp[j];
  }
  const int4 s4 = sel[((size_t)h << 11) + t];

  const int g16 = lane >> 4;
  const int blk = (g16 == 0) ? s4.x : (g16 == 1) ? s4.y : (g16 == 2) ? s4.z : s4.w;
  const int tok = blk * 16 + (lane & 15);
  tks[w][lane] = tok;
  {
    float a0 = 0.f, a1 = 0.f, a2 = 0.f, a3 = 0.f;
#pragma unroll
    for (int dc = 0; dc < 8; dc++) {
      const uint4 kk = *(const uint4*)(kT + ((size_t)dc * 2048 + tok) * 8);
      a0 = fdot2u(kk.x, qr[dc].x, a0);
      a1 = fdot2u(kk.y, qr[dc].y, a1);
      a2 = fdot2u(kk.z, qr[dc].z, a2);
      a3 = fdot2u(kk.w, qr[dc].w, a3);
    }
    const float sv_ = (tok <= t) ? ((a0 + a1) + (a2 + a3)) * 0.125f : NEGC;
    const float Ms = wred_max(sv_);
    const float es = __expf(sv_ - Ms);
    ps[w][lane] = es * (1.f / wred_sum(es));
  }

  const int dd = lane & 31, s = lane >> 5;
  const float4* ps4 = (const float4*)ps[w];
  const int4* tk4p = (const int4*)tks[w];

  float osx = 0.f, osy = 0.f;
#pragma unroll
  for (int jc = 0; jc < 8; jc++) {
    const float4 p4 = ps4[s * 8 + jc];
    const int4 t4 = tk4p[s * 8 + jc];
    const float pa[4] = {p4.x, p4.y, p4.z, p4.w};
    const int ta[4] = {t4.x, t4.y, t4.z, t4.w};
#pragma unroll
    for (int u = 0; u < 4; u++) {
      const unsigned int vv = *(const unsigned int*)(vhh + (size_t)ta[u] * 64 + 2 * dd);
      const h2 v2 = __builtin_bit_cast(h2, vv);
      osx += pa[u] * (float)v2[0];
      osy += pa[u] * (float)v2[1];
    }
  }
  osx += __shfl_xor(osx, 32, 64);
  osy += __shfl_xor(osy, 32, 64);

  if (lane < 32)
    *(float2*)&osel[(size_t)t * 1024 + h * 64 + 2 * dd] = make_float2(osx, osy);
}

// ------------- window branch via MFMA + gated combine -> outf -------------
__global__ __launch_bounds__(256) void nsa_win(
    const unsigned short* __restrict__ qhf, const unsigned short* __restrict__ khfT,
    const unsigned short* __restrict__ vhfT, const float* __restrict__ oc,
    const float* __restrict__ osel, const float* __restrict__ gates,
    unsigned short* __restrict__ outf) {
  __shared__ unsigned short P_lds[4][16][72];
  const int bid = blockIdx.x;
  const int h = bid & 15, tq0 = (bid >> 4) * 64;
  const int w = threadIdx.x >> 6, lane = threadIdx.x & 63;
  const int cc = lane & 15, kgrp = lane >> 4;
  const int qt0 = tq0 + w * 16;
  const int kb = qt0 - 32;

  const unsigned short* kT = khfT + (size_t)h * 131072;
  const unsigned short* vT = vhfT + (size_t)h * 131072;

  short8 aq[2];
#pragma unroll
  for (int ks = 0; ks < 2; ks++)
    aq[ks] = *(const short8*)&qhf[(size_t)(qt0 + cc) * 1024 + h * 64 + ks * 32 + kgrp * 8];

  floatx4 zero = {0.f, 0.f, 0.f, 0.f};
  floatx4 accs[3] = {zero, zero, zero};
#pragma unroll
  for (int ni = 0; ni < 3; ni++) {
    const int tokc = min(max(kb + ni * 16 + cc, 0), T_LEN - 1);
#pragma unroll
    for (int ks = 0; ks < 2; ks++) {
      const short8 bk = *(const short8*)&kT[((size_t)(ks * 4 + kgrp) * 2048 + tokc) * 8];
      accs[ni] = __builtin_amdgcn_mfma_f32_16x16x32_f16(
          __builtin_bit_cast(h8, aq[ks]), __builtin_bit_cast(h8, bk), accs[ni], 0, 0, 0);
    }
  }

#pragma unroll
  for (int r = 0; r < 4; r++) {
    const int t = qt0 + kgrp * 4 + r;
    float sc[3];
#pragma unroll
    for (int ni = 0; ni < 3; ni++) {
      const int s = kb + ni * 16 + cc;
      const int ds = t - s;
      sc[ni] = (s >= 0 && ds >= 0 && ds <= 32) ? accs[ni][r] * 0.125f : NEGC;
    }
    float m3 = fmaxf(fmaxf(sc[0], sc[1]), sc[2]);
#pragma unroll
    for (int o = 1; o <= 8; o <<= 1) m3 = fmaxf(m3, __shfl_xor(m3, o, 64));
    float e0 = __expf(sc[0] - m3), e1 = __expf(sc[1] - m3), e2 = __expf(sc[2] - m3);
    float sum = e0 + e1 + e2;
#pragma unroll
    for (int o = 1; o <= 8; o <<= 1) sum += __shfl_xor(sum, o, 64);
    const float inv = 1.f / sum;
    const int row = kgrp * 4 + r;
    P_lds[w][row][cc]      = f32_to_f16u(e0 * inv);
    P_lds[w][row][16 + cc] = f32_to_f16u(e1 * inv);
    P_lds[w][row][32 + cc] = f32_to_f16u(e2 * inv);
  }
  {
    const int rr = lane >> 2, c0 = 48 + (lane & 3) * 4;
    *(ushort4*)&P_lds[w][rr][c0] = make_ushort4(0, 0, 0, 0);
  }
  __syncthreads();

  floatx4 accp[4] = {zero, zero, zero, zero};
#pragma unroll
  for (int ks2 = 0; ks2 < 2; ks2++) {
    const short8 ap = *(const short8*)&P_lds[w][cc][ks2 * 32 + kgrp * 8];
    const int tok0 = min(max(kb + ks2 * 32 + kgrp * 8, 0), T_LEN - 8);
#pragma unroll
    for (int ni = 0; ni < 4; ni++) {
      const short8 bv = *(const short8*)&vT[(size_t)(ni * 16 + cc) * 2048 + tok0];
      accp[ni] = __builtin_amdgcn_mfma_f32_16x16x32_f16(
          __builtin_bit_cast(h8, ap), __builtin_bit_cast(h8, bv), accp[ni], 0, 0, 0);
    }
  }

#pragma unroll
  for (int r = 0; r < 4; r++) {
    const int t = qt0 + kgrp * 4 + r;
    const float g0 = gates[t * 3 + 0], g1 = gates[t * 3 + 1], g2 = gates[t * 3 + 2];
#pragma unroll
    for (int ni = 0; ni < 4; ni++) {
      const int d = ni * 16 + cc;
      const float ocv = oc[(size_t)t * 1024 + h * 64 + d];
      const float osv = osel[(size_t)t * 1024 + h * 64 + d];
      outf[(size_t)t * 1024 + h * 64 + d] =
          f32_to_bf16(g0 * ocv + g1 * osv + g2 * accp[ni][r]);
    }
  }
}

// ---------------- launch ----------------
extern "C" void kernel_launch(void* const* d_in, const int* in_sizes, int n_in,
                              void* d_out, int out_size, void* d_ws, size_t ws_size,
                              hipStream_t stream) {
  const float* x   = (const float*)d_in[0];
  const float* Wq  = (const float*)d_in[1];
  const float* Wk  = (const float*)d_in[2];
  const float* Wv  = (const float*)d_in[3];
  const float* Wo  = (const float*)d_in[4];
  const float* Wck = (const float*)d_in[5];
  const float* Wcv = (const float*)d_in[6];
  const float* Wg  = (const float*)d_in[7];
  const float* bg  = (const float*)d_in[8];
  float* out = (float*)d_out;

  float* ws = (float*)d_ws;
  // region A [0,24 MB): C until compress; then osel [0,8), oc [8,16), outf [16,20)
  float*          C    = ws;
  float*          osel = ws;                                // [0,8 MB)
  float*          oc   = ws + 2097152;                      // [8,16 MB)
  unsigned short* outf = (unsigned short*)(ws + 4194304);   // [16,20 MB)
  // region B [24,36 MB): Axf (4 MB) until qkv GEMM; then qh + smalls
  unsigned short* Axf   = (unsigned short*)(ws + 6291456);
  float*          qh    = ws + 6291456;                     // [24,32 MB)
  unsigned short* Wot   = (unsigned short*)(ws + 8388608);  // [32,34 MB)
  unsigned short* kc_hi = (unsigned short*)(ws + 8912896);
  unsigned short* kc_lo = (unsigned short*)(ws + 8978432);
  unsigned short* vcT   = (unsigned short*)(ws + 9043968);
  int4*           sel   = (int4*)(ws + 9109504);
  unsigned short* WckT_hi = (unsigned short*)(ws + 9240576);
  unsigned short* WckT_lo = (unsigned short*)(ws + 9273344);
  unsigned short* WcvT_hi = (unsigned short*)(ws + 9306112);
  unsigned short* WcvT_lo = (unsigned short*)(ws + 9338880);
  float*          gates   = ws + 9371648;
  // region C [36,48 MB): Bqkv f16 (6 MB) until qkv GEMM; then qhf/khfT/vhf f16
  unsigned short* Bqkv = (unsigned short*)(ws + 9437184);   // 3072x1024 f16, 6 MB
  unsigned short* qhf  = (unsigned short*)(ws + 9437184);   // [36,40 MB)
  unsigned short* khfT = (unsigned short*)(ws + 10485760);  // [40,44 MB)
  unsigned short* vhf  = (unsigned short*)(ws + 11534336);  // [44,48 MB)
  // vhfT scratch lives in d_out (read by nsa_win, then gemm_bt64 overwrites out)
  unsigned short* vhfT = (unsigned short*)d_out;            // 16x64x2048 f16, 4 MB

  // 1. operand preparation (f16 single-pass QKV operands)
  cast_x_k<<<2048, 256, 0, stream>>>(x, Axf);
  cast_wqkv<<<dim3(32, 32, 3), dim3(32, 8), 0, stream>>>(Wq, Wk, Wv, Bqkv);

  // 2. merged q|k|v GEMM: 64x128 BK=32, 3-buffer 2-ahead counted-vmcnt
  qkv_gemm<<<dim3(24, 32), 256, 0, stream>>>(Axf, Bqkv, C);

  // 3. reorg (+ V transpose for window MFMA) + gates; late weight casts
  reorg_qkv<<<6144, 256, 0, stream>>>(C, qh, qhf, khfT, vhf);
  transp_v<<<dim3(64, 2, 16), dim3(32, 8), 0, stream>>>(vhf, vhfT);
  gates_k<<<512, 256, 0, stream>>>(C, Wg, bg, gates);
  cast_wt1<<<dim3(32, 32), dim3(32, 8), 0, stream>>>(Wo, Wot);
  cast_wct<<<dim3(2, 32, 2), dim3(32, 8), 0, stream>>>(Wck, Wcv, WckT_hi, WckT_lo, WcvT_hi, WcvT_lo);

  // 4. compression (reads C; C dead after) + compressed branch (oc aliases C tail)
  compress_mfma<<<dim3(128, 2), 512, 0, stream>>>(C, WckT_hi, WckT_lo, WcvT_hi, WcvT_lo,
                                                  kc_hi, kc_lo, vcT);
  cscore_k<<<2048, 256, 0, stream>>>(qh, kc_hi, kc_lo, vcT, oc, sel);

  // 5. selected branch (scalar, per-query) -> osel; window branch (MFMA) + combine
  nsa_sel<<<8192, 256, 0, stream>>>(qhf, khfT, vhf, sel, osel);
  nsa_win<<<512, 256, 0, stream>>>(qhf, khfT, vhfT, oc, osel, gates, outf);

  // 6. output projection (64x128 BK=32, 3-buffer 2-ahead counted-vmcnt)
  gemm_bt64<<<dim3(8, 32), 256, 0, stream>>>(outf, Wot, out, 1024, 1024, 1024);
}

// Round 11
// 234.890 us; speedup vs baseline: 1.0532x; 1.0318x over previous
//
#include <hip/hip_runtime.h>
#include <hip/hip_bf16.h>
#include <float.h>

#define T_LEN 2048
#define DM    1024
#define NB    128
#define NEGC  (-1e9f)

typedef __attribute__((ext_vector_type(8))) short short8;
typedef __attribute__((ext_vector_type(4))) float floatx4;
typedef _Float16 h2 __attribute__((ext_vector_type(2)));
typedef _Float16 h8 __attribute__((ext_vector_type(8)));

// ---------------- helpers ----------------
__device__ __forceinline__ float wred_max(float v) {
#pragma unroll
  for (int o = 32; o > 0; o >>= 1) v = fmaxf(v, __shfl_xor(v, o, 64));
  return v;
}
__device__ __forceinline__ float wred_sum(float v) {
#pragma unroll
  for (int o = 32; o > 0; o >>= 1) v += __shfl_xor(v, o, 64);
  return v;
}
__device__ __forceinline__ unsigned short f32_to_bf16(float f) {
  unsigned int b = __float_as_uint(f);
  return (unsigned short)((b + 0x7fffu + ((b >> 16) & 1u)) >> 16);
}
__device__ __forceinline__ float bf16_to_f32(unsigned short u) {
  return __uint_as_float(((unsigned int)u) << 16);
}
__device__ __forceinline__ unsigned int pack_h2(float a, float b) {
  h2 r; r[0] = (_Float16)a; r[1] = (_Float16)b;
  return __builtin_bit_cast(unsigned int, r);
}
__device__ __forceinline__ unsigned short f32_to_f16u(float f) {
  h2 r; r[0] = (_Float16)f; r[1] = (_Float16)0.f;
  return (unsigned short)(__builtin_bit_cast(unsigned int, r) & 0xffffu);
}
__device__ __forceinline__ float fdot2u(unsigned int a, unsigned int b, float c) {
#if __has_builtin(__builtin_amdgcn_fdot2)
  return __builtin_amdgcn_fdot2(__builtin_bit_cast(h2, a), __builtin_bit_cast(h2, b), c, false);
#else
  const h2 av = __builtin_bit_cast(h2, a), bv = __builtin_bit_cast(h2, b);
  return c + (float)av[0] * (float)bv[0] + (float)av[1] * (float)bv[1];
#endif
}
__device__ __forceinline__ void lds_async16(unsigned short* l, const unsigned short* g) {
  __builtin_amdgcn_global_load_lds(
      (const __attribute__((address_space(1))) unsigned int*)g,
      (__attribute__((address_space(3))) unsigned int*)l, 16, 0, 0);
}

// ====== 64x128-tile MFMA GEMM core — BK=32, 3-buffer counted-vmcnt (r10) ======
// qkv declared DONE at this structure (r10 null: 2-ahead == 1-ahead == 43 us,
// 297 TF ~= the known plain-HIP 2-barrier value at this shape).
template <bool F16>
__device__ __forceinline__ void gemm64_core(
    const unsigned short* __restrict__ A, const unsigned short* __restrict__ Bt,
    float* __restrict__ C, int K, int lda, int row0, int bcol0, int ccol0, int ldc,
    unsigned short* As, unsigned short* Bs) {
  const int tid = threadIdx.x;
  const int w = tid >> 6, lane = tid & 63;
  const int wr = w >> 1, wc = w & 1;
  const int mrow = lane & 15, kgrp = lane >> 4;

  const int sr = (w << 4) + mrow;          // staged row 0..63
  const int sc = kgrp;                     // staged chunk 0..3

  floatx4 zero = {0.f, 0.f, 0.f, 0.f};
  floatx4 acc[2][4];
#pragma unroll
  for (int i = 0; i < 2; i++)
#pragma unroll
    for (int j = 0; j < 4; j++) acc[i][j] = zero;

  const int nt = K >> 5;
  const unsigned short* Ap  = A  + (size_t)(row0 + sr) * lda + sc * 8;
  const unsigned short* Bp0 = Bt + (size_t)(bcol0 + sr) * K + sc * 8;
  const unsigned short* Bp1 = Bt + (size_t)(bcol0 + 64 + sr) * K + sc * 8;

  auto stage = [&](int t, int b) {
    lds_async16(&As[b * 2048 + w * 512], Ap + t * 32);
    lds_async16(&Bs[b * 4096 + w * 512], Bp0 + t * 32);
    lds_async16(&Bs[b * 4096 + 2048 + w * 512], Bp1 + t * 32);
  };

  stage(0, 0);
  if (nt > 1) stage(1, 1);
  int cur = 0;
  for (int t = 0; t < nt; t++) {
    if (t + 2 < nt) {
      const int nx = (cur + 2 >= 3) ? cur - 1 : cur + 2;
      stage(t + 2, nx);                                   // outstanding: 9
      asm volatile("s_waitcnt vmcnt(6)" ::: "memory");    // tile t landed
    } else if (t + 1 < nt) {
      asm volatile("s_waitcnt vmcnt(3)" ::: "memory");
    } else {
      asm volatile("s_waitcnt vmcnt(0)" ::: "memory");
    }
    __builtin_amdgcn_s_barrier();
    const unsigned short* as = As + cur * 2048;
    const unsigned short* bs = Bs + cur * 4096;
    short8 af[2], bf4[4];
#pragma unroll
    for (int mi = 0; mi < 2; mi++)
      af[mi] = *(const short8*)&as[(wr * 2 + mi) * 512 + kgrp * 128 + mrow * 8];
#pragma unroll
    for (int ni = 0; ni < 4; ni++)
      bf4[ni] = *(const short8*)&bs[(wc * 4 + ni) * 512 + kgrp * 128 + mrow * 8];
#pragma unroll
    for (int mi = 0; mi < 2; mi++)
#pragma unroll
      for (int ni = 0; ni < 4; ni++) {
        if constexpr (F16)
          acc[mi][ni] = __builtin_amdgcn_mfma_f32_16x16x32_f16(
              __builtin_bit_cast(h8, af[mi]), __builtin_bit_cast(h8, bf4[ni]),
              acc[mi][ni], 0, 0, 0);
        else
          acc[mi][ni] = __builtin_amdgcn_mfma_f32_16x16x32_bf16(af[mi], bf4[ni],
                                                                acc[mi][ni], 0, 0, 0);
      }
    asm volatile("" ::: "memory");
    __builtin_amdgcn_s_barrier();
    cur = (cur + 1 == 3) ? 0 : cur + 1;
  }
#pragma unroll
  for (int mi = 0; mi < 2; mi++)
#pragma unroll
    for (int ni = 0; ni < 4; ni++) {
      float* Cp = C + (size_t)(row0 + wr * 32 + mi * 16 + kgrp * 4) * ldc
                    + ccol0 + wc * 64 + ni * 16 + mrow;
      Cp[0] = acc[mi][ni][0];
      Cp[(size_t)ldc] = acc[mi][ni][1];
      Cp[(size_t)2 * ldc] = acc[mi][ni][2];
      Cp[(size_t)3 * ldc] = acc[mi][ni][3];
    }
}

// merged q|k|v GEMM: grid (24, 32) = 768 blocks (3/CU), f16 K=1024 single pass.
__global__ __launch_bounds__(256) void qkv_gemm(const unsigned short* __restrict__ Axf,
                                                const unsigned short* __restrict__ Bqkv,
                                                float* __restrict__ C) {
  __shared__ __align__(16) unsigned short As[3 * 64 * 32];
  __shared__ __align__(16) unsigned short Bs[3 * 128 * 32];
  gemm64_core<true>(Axf, Bqkv, C, 1024, 1024, blockIdx.y * 64,
                    blockIdx.x * 128, blockIdx.x * 128, 3072, As, Bs);
}

// ====== output projection — 64x64 tile, grid (16,32) = 512 blocks (2/CU) ======
// r11 fix: the old (8,32)=256-block launch was 1 wave/SIMD — the exact
// occupancy poison r8 measured (1.5 us/step, no TLP to hide the stage wait).
// 64x64 halves flops/staged-byte (irrelevant: latency regime, r8) but doubles
// blocks/CU. 2 loads/wave/step; 2-ahead: outstanding 6 -> vmcnt(4) = tile t.
__global__ __launch_bounds__(256) void gemm_bt64(const unsigned short* __restrict__ A,
                                                 const unsigned short* __restrict__ Bt,
                                                 float* __restrict__ C,
                                                 int K, int lda, int ldc) {
  __shared__ __align__(16) unsigned short As[3 * 2048];
  __shared__ __align__(16) unsigned short Bs[3 * 2048];
  const int tid = threadIdx.x;
  const int w = tid >> 6, lane = tid & 63;
  const int wr = w >> 1, wc = w & 1;
  const int mrow = lane & 15, kgrp = lane >> 4;
  const int row0 = blockIdx.y * 64, col0 = blockIdx.x * 64;

  const int sr = (w << 4) + mrow;

  floatx4 zero = {0.f, 0.f, 0.f, 0.f};
  floatx4 acc[2][2];
#pragma unroll
  for (int i = 0; i < 2; i++)
#pragma unroll
    for (int j = 0; j < 2; j++) acc[i][j] = zero;

  const int nt = K >> 5;
  const unsigned short* Ap = A + (size_t)(row0 + sr) * lda + kgrp * 8;
  const unsigned short* Bp = Bt + (size_t)(col0 + sr) * K + kgrp * 8;

  auto stage = [&](int t, int b) {
    lds_async16(&As[b * 2048 + w * 512], Ap + t * 32);
    lds_async16(&Bs[b * 2048 + w * 512], Bp + t * 32);
  };

  stage(0, 0);
  if (nt > 1) stage(1, 1);
  int cur = 0;
  for (int t = 0; t < nt; t++) {
    if (t + 2 < nt) {
      const int nx = (cur + 2 >= 3) ? cur - 1 : cur + 2;
      stage(t + 2, nx);                                   // outstanding: 6
      asm volatile("s_waitcnt vmcnt(4)" ::: "memory");    // tile t landed
    } else if (t + 1 < nt) {
      asm volatile("s_waitcnt vmcnt(2)" ::: "memory");
    } else {
      asm volatile("s_waitcnt vmcnt(0)" ::: "memory");
    }
    __builtin_amdgcn_s_barrier();
    const unsigned short* as = As + cur * 2048;
    const unsigned short* bs = Bs + cur * 2048;
    short8 af[2], bf2[2];
#pragma unroll
    for (int mi = 0; mi < 2; mi++)
      af[mi] = *(const short8*)&as[(wr * 2 + mi) * 512 + kgrp * 128 + mrow * 8];
#pragma unroll
    for (int ni = 0; ni < 2; ni++)
      bf2[ni] = *(const short8*)&bs[(wc * 2 + ni) * 512 + kgrp * 128 + mrow * 8];
#pragma unroll
    for (int mi = 0; mi < 2; mi++)
#pragma unroll
      for (int ni = 0; ni < 2; ni++)
        acc[mi][ni] = __builtin_amdgcn_mfma_f32_16x16x32_bf16(af[mi], bf2[ni],
                                                              acc[mi][ni], 0, 0, 0);
    asm volatile("" ::: "memory");
    __builtin_amdgcn_s_barrier();
    cur = (cur + 1 == 3) ? 0 : cur + 1;
  }
#pragma unroll
  for (int mi = 0; mi < 2; mi++)
#pragma unroll
    for (int ni = 0; ni < 2; ni++) {
      float* Cp = C + (size_t)(row0 + wr * 32 + mi * 16 + kgrp * 4) * ldc
                    + col0 + wc * 32 + ni * 16 + mrow;
      Cp[0] = acc[mi][ni][0];
      Cp[(size_t)ldc] = acc[mi][ni][1];
      Cp[(size_t)2 * ldc] = acc[mi][ni][2];
      Cp[(size_t)3 * ldc] = acc[mi][ni][3];
    }
}

// ---------------- cast x -> f16 (2048 x 1024) ----------------
__global__ __launch_bounds__(256) void cast_x_k(const float* __restrict__ x,
                                                unsigned short* __restrict__ Axf) {
  const int gid = blockIdx.x * 256 + threadIdx.x;
  float4 xv = ((const float4*)x)[gid];
  const unsigned int p0 = pack_h2(xv.x, xv.y);
  const unsigned int p1 = pack_h2(xv.z, xv.w);
  *(uint2*)&Axf[(size_t)gid * 4] = make_uint2(p0, p1);
}

// ---- merged weight transpose-casts (r11: was 3 kernels, saves 2 launch gaps)
// z 0-2: Wq/Wk/Wv -> Bqkv f16 (3072n x 1024k); z=3: Wo -> Wot bf16;
// z 4-5: Wck/Wcv (1024x64) -> (64,1024) hi/lo bf16 (x>=2 blocks no-op).
__global__ void cast_weights(const float* __restrict__ Wq, const float* __restrict__ Wk,
                             const float* __restrict__ Wv, const float* __restrict__ Wo,
                             const float* __restrict__ Wck, const float* __restrict__ Wcv,
                             unsigned short* __restrict__ Bqkv, unsigned short* __restrict__ Wot,
                             unsigned short* __restrict__ KT_hi, unsigned short* __restrict__ KT_lo,
                             unsigned short* __restrict__ VT_hi, unsigned short* __restrict__ VT_lo) {
  __shared__ float tile[32][33];
  const int z = blockIdx.z;
  const int tx = threadIdx.x, ty = threadIdx.y;
  const int kt0 = blockIdx.y * 32, nt0 = blockIdx.x * 32;
  if (z < 3) {
    const float* W = (z == 0) ? Wq : (z == 1) ? Wk : Wv;
#pragma unroll
    for (int i = 0; i < 32; i += 8)
      tile[ty + i][tx] = W[(size_t)(kt0 + ty + i) * 1024 + nt0 + tx];
    __syncthreads();
#pragma unroll
    for (int i = 0; i < 32; i += 8) {
      const int n = nt0 + ty + i, kk = kt0 + tx;
      Bqkv[(size_t)(z * 1024 + n) * 1024 + kk] = f32_to_f16u(tile[tx][ty + i]);
    }
  } else if (z == 3) {
#pragma unroll
    for (int i = 0; i < 32; i += 8)
      tile[ty + i][tx] = Wo[(size_t)(kt0 + ty + i) * 1024 + nt0 + tx];
    __syncthreads();
#pragma unroll
    for (int i = 0; i < 32; i += 8) {
      const int n = nt0 + ty + i, kk = kt0 + tx;
      Wot[(size_t)n * 1024 + kk] = f32_to_bf16(tile[tx][ty + i]);
    }
  } else {
    if (nt0 >= 64) return;
    const float* W = (z == 5) ? Wcv : Wck;
    unsigned short* Bh = (z == 5) ? VT_hi : KT_hi;
    unsigned short* Bl = (z == 5) ? VT_lo : KT_lo;
#pragma unroll
    for (int i = 0; i < 32; i += 8)
      tile[ty + i][tx] = W[(size_t)(kt0 + ty + i) * 64 + nt0 + tx];
    __syncthreads();
#pragma unroll
    for (int i = 0; i < 32; i += 8) {
      const int n = nt0 + ty + i, kk = kt0 + tx;
      const float f = tile[tx][ty + i];
      const unsigned short hb = f32_to_bf16(f);
      Bh[(size_t)n * 1024 + kk] = hb;
      Bl[(size_t)n * 1024 + kk] = f32_to_bf16(f - bf16_to_f32(hb));
    }
  }
}

// ---------------- reorg: C(t,3072) -> qh f32, qhf f16 (T,1024),
//                  khfT f16 (H, 8, T, 8), vhf f16 (H, T, 64) ----------------
__global__ __launch_bounds__(256) void reorg_qkv(const float* __restrict__ C,
                                                 float* __restrict__ qh,
                                                 unsigned short* __restrict__ qhf,
                                                 unsigned short* __restrict__ khfT,
                                                 unsigned short* __restrict__ vhf) {
  const int gid = blockIdx.x * 256 + threadIdx.x;
  const int t = gid / 768;
  const int c = (gid - t * 768) * 4;
  float4 val = *(const float4*)&C[(size_t)t * 3072 + c];
  const unsigned int p0 = pack_h2(val.x, val.y);
  const unsigned int p1 = pack_h2(val.z, val.w);
  if (c < 1024) {
    *(float4*)&qh[(size_t)t * 1024 + c] = val;
    *(uint2*)&qhf[(size_t)t * 1024 + c] = make_uint2(p0, p1);
  } else if (c < 2048) {
    const int h = (c >> 6) & 15, d = c & 63;
    const int dc = d >> 3, j = d & 7;
    *(uint2*)&khfT[((size_t)(h * 8 + dc) * 2048 + t) * 8 + j] = make_uint2(p0, p1);
  } else {
    const int h = (c >> 6) & 15, d = c & 63;
    *(uint2*)&vhf[((size_t)h * 2048 + t) * 64 + d] = make_uint2(p0, p1);
  }
}

// ---- transpose vhf [h][t][64] -> vhfT [h][d][2048] f16 (for window PV MFMA) ----
__global__ void transp_v(const unsigned short* __restrict__ vhf,
                         unsigned short* __restrict__ vhfT) {
  __shared__ unsigned short tile[32][34];
  const int h = blockIdx.z;
  const int t0 = blockIdx.x * 32, d0 = blockIdx.y * 32;
  const int tx = threadIdx.x, ty = threadIdx.y;
#pragma unroll
  for (int i = 0; i < 32; i += 8)
    tile[ty + i][tx] = vhf[((size_t)h * 2048 + t0 + ty + i) * 64 + d0 + tx];
  __syncthreads();
#pragma unroll
  for (int i = 0; i < 32; i += 8)
    vhfT[((size_t)h * 64 + d0 + ty + i) * 2048 + t0 + tx] = tile[tx][ty + i];
}

// ---------------- compress via MFMA (reads k/v straight from C) ----------------
__global__ __launch_bounds__(512) void compress_mfma(
    const float* __restrict__ C,
    const unsigned short* __restrict__ KT_hi, const unsigned short* __restrict__ KT_lo,
    const unsigned short* __restrict__ VT_hi, const unsigned short* __restrict__ VT_lo,
    unsigned short* __restrict__ kc_hi, unsigned short* __restrict__ kc_lo,
    unsigned short* __restrict__ vcT) {
  __shared__ float red[8][64][17];
  const int isv = blockIdx.y;
  const unsigned short* Bh = isv ? VT_hi : KT_hi;
  const unsigned short* Bl = isv ? VT_lo : KT_lo;
  const int tid = threadIdx.x, w = tid >> 6, lane = tid & 63;
  const int mrow = lane & 15, kgrp = lane >> 4;
  const int m0 = blockIdx.x * 16;
  const int m = m0 + mrow;
  const int hh = m >> 7, nb = m & 127;
  const int cbase = 1024 + isv * 1024 + hh * 64;

  floatx4 zero = {0.f, 0.f, 0.f, 0.f};
  floatx4 acc[4] = {zero, zero, zero, zero};

  const int kbeg = w << 7;
  for (int k0 = kbeg; k0 < kbeg + 128; k0 += 32) {
    const int c = k0 + kgrp * 8;
    const float* ap = &C[(size_t)(nb * 16 + (c >> 6)) * 3072 + cbase + (c & 63)];
    float4 q0 = *(const float4*)ap;
    float4 q1 = *(const float4*)(ap + 4);
    float qq[8] = {q0.x, q0.y, q0.z, q0.w, q1.x, q1.y, q1.z, q1.w};
    short8 a_hi, a_lo;
#pragma unroll
    for (int j = 0; j < 8; j++) {
      unsigned short hb = f32_to_bf16(qq[j]);
      a_hi[j] = (short)hb;
      a_lo[j] = (short)f32_to_bf16(qq[j] - bf16_to_f32(hb));
    }
#pragma unroll
    for (int ni = 0; ni < 4; ni++) {
      const size_t boff = (size_t)(ni * 16 + mrow) * 1024 + k0 + kgrp * 8;
      short8 b_hi = *(const short8*)&Bh[boff];
      short8 b_lo = *(const short8*)&Bl[boff];
      acc[ni] = __builtin_amdgcn_mfma_f32_16x16x32_bf16(a_hi, b_hi, acc[ni], 0, 0, 0);
      acc[ni] = __builtin_amdgcn_mfma_f32_16x16x32_bf16(a_lo, b_hi, acc[ni], 0, 0, 0);
      acc[ni] = __builtin_amdgcn_mfma_f32_16x16x32_bf16(a_hi, b_lo, acc[ni], 0, 0, 0);
    }
  }

#pragma unroll
  for (int ni = 0; ni < 4; ni++)
#pragma unroll
    for (int r = 0; r < 4; r++) red[w][lane][ni * 4 + r] = acc[ni][r];
  __syncthreads();

  if (w < 4) {
#pragma unroll
    for (int r = 0; r < 4; r++) {
      const int j = w * 4 + r;
      float val = 0.f;
#pragma unroll
      for (int ww = 0; ww < 8; ww++) val += red[ww][lane][j];
      const int mo = m0 + kgrp * 4 + r;
      const int d = w * 16 + mrow;
      if (!isv) {
        const unsigned short hb = f32_to_bf16(val);
        kc_hi[(size_t)mo * 64 + d] = hb;
        kc_lo[(size_t)mo * 64 + d] = f32_to_bf16(val - bf16_to_f32(hb));
      } else {
        vcT[(size_t)(mo >> 7) * 8192 + (size_t)d * 128 + (mo & 127)] = f32_to_bf16(val);
      }
    }
  }
}

// ---------------- gates ----------------
__global__ __launch_bounds__(256) void gates_k(const float* __restrict__ C,
                                               const float* __restrict__ Wg,
                                               const float* __restrict__ bg,
                                               float* __restrict__ gates) {
  const int w = threadIdx.x >> 6, lane = threadIdx.x & 63;
  const int t = blockIdx.x * 4 + w;
  float m = 0.f;
#pragma unroll
  for (int h = 0; h < 16; h++) m += C[(size_t)t * 3072 + h * 64 + lane];
  m *= (1.f / 16.f);
  float g0 = wred_sum(m * Wg[lane * 3 + 0]);
  float g1 = wred_sum(m * Wg[lane * 3 + 1]);
  float g2 = wred_sum(m * Wg[lane * 3 + 2]);
  if (lane == 0) {
    g0 += bg[0]; g1 += bg[1]; g2 += bg[2];
    float mx = fmaxf(g0, fmaxf(g1, g2));
    float e0 = __expf(g0 - mx), e1 = __expf(g1 - mx), e2 = __expf(g2 - mx);
    float inv = 1.f / (e0 + e1 + e2);
    gates[t * 3 + 0] = e0 * inv;
    gates[t * 3 + 1] = e1 * inv;
    gates[t * 3 + 2] = e2 * inv;
  }
}

// ------- cscore: MFMA scores + softmax + top-4 + fused PV (r7 fast argmax) -------
__global__ __launch_bounds__(256) void cscore_k(
    const float* __restrict__ qh, const unsigned short* __restrict__ kc_hi,
    const unsigned short* __restrict__ kc_lo, const unsigned short* __restrict__ vcT,
    float* __restrict__ oc, int4* __restrict__ sel) {
  __shared__ float S_s[16][132];
  const int h = blockIdx.x >> 7, t0 = (blockIdx.x & 127) * 16;
  const int tid = threadIdx.x, w = tid >> 6, lane = tid & 63;
  const int mrow = lane & 15, kgrp = lane >> 4;

  short8 a_hi[2], a_lo[2];
#pragma unroll
  for (int ks = 0; ks < 2; ks++) {
    const float* qp = &qh[(size_t)(t0 + mrow) * 1024 + h * 64 + ks * 32 + kgrp * 8];
    float4 q0 = *(const float4*)qp;
    float4 q1 = *(const float4*)(qp + 4);
    float qq[8] = {q0.x, q0.y, q0.z, q0.w, q1.x, q1.y, q1.z, q1.w};
#pragma unroll
    for (int j = 0; j < 8; j++) {
      unsigned short hb = f32_to_bf16(qq[j]);
      a_hi[ks][j] = (short)hb;
      a_lo[ks][j] = (short)f32_to_bf16(qq[j] - bf16_to_f32(hb));
    }
  }
  floatx4 zero = {0.f, 0.f, 0.f, 0.f};
  floatx4 acc[2] = {zero, zero};
#pragma unroll
  for (int ni = 0; ni < 2; ni++) {
    const int nb = w * 32 + ni * 16 + mrow;
#pragma unroll
    for (int ks = 0; ks < 2; ks++) {
      const size_t off = ((size_t)h * 128 + nb) * 64 + ks * 32 + kgrp * 8;
      short8 b_hi = *(const short8*)&kc_hi[off];
      short8 b_lo = *(const short8*)&kc_lo[off];
      acc[ni] = __builtin_amdgcn_mfma_f32_16x16x32_bf16(a_hi[ks], b_hi, acc[ni], 0, 0, 0);
      acc[ni] = __builtin_amdgcn_mfma_f32_16x16x32_bf16(a_lo[ks], b_hi, acc[ni], 0, 0, 0);
      acc[ni] = __builtin_amdgcn_mfma_f32_16x16x32_bf16(a_hi[ks], b_lo, acc[ni], 0, 0, 0);
    }
  }
#pragma unroll
  for (int ni = 0; ni < 2; ni++) {
    const int n = w * 32 + ni * 16 + mrow;
#pragma unroll
    for (int r = 0; r < 4; r++) {
      const int row = kgrp * 4 + r;
      const int count = (t0 + row) >> 4;
      S_s[row][n] = (n < count) ? acc[ni][r] * 0.125f : NEGC;
    }
  }
  __syncthreads();

#pragma unroll
  for (int qq = 0; qq < 4; qq++) {
    const int row = w * 4 + qq, t = t0 + row, count = t >> 4;
    const float2 sv = *(const float2*)&S_s[row][2 * lane];
    const float s0 = sv.x, s1 = sv.y;
    const float M = wred_max(fmaxf(s0, s1));
    const float e0 = __expf(s0 - M), e1 = __expf(s1 - M);
    const float inv = 1.f / wred_sum(e0 + e1);
    S_s[row][2 * lane]     = (count == 0) ? 0.f : e0 * inv;
    S_s[row][2 * lane + 1] = (count == 0) ? 0.f : e1 * inv;

    float c0 = s0, c1 = s1;
    float curM = M;
    int se0 = 0, se1 = 0, se2 = 0, se3 = 0;
#pragma unroll
    for (int j = 0; j < 4; j++) {
      if (j) curM = wred_max(fmaxf(c0, c1));
      const unsigned long long b = __ballot((c0 == curM) || (c1 == curM));
      const int lidx = (int)__builtin_ctzll(b);
      const float c0l = __shfl(c0, lidx, 64);
      const int isc0 = (c0l == curM);
      const int idx = 2 * lidx + (isc0 ? 0 : 1);
      if (j == 0) se0 = idx; else if (j == 1) se1 = idx;
      else if (j == 2) se2 = idx; else se3 = idx;
      if (lane == lidx) { if (isc0) c0 = -FLT_MAX; else c1 = -FLT_MAX; }
    }
    if (lane == 0) sel[((size_t)h << 11) + t] = make_int4(se0, se1, se2, se3);
  }
  __syncthreads();

  const int d = w * 16 + mrow;
  floatx4 accp = zero;
#pragma unroll
  for (int ks = 0; ks < 4; ks++) {
    const float4 p0 = *(const float4*)&S_s[mrow][ks * 32 + kgrp * 8];
    const float4 p1 = *(const float4*)&S_s[mrow][ks * 32 + kgrp * 8 + 4];
    short8 a;
    a[0] = (short)f32_to_bf16(p0.x); a[1] = (short)f32_to_bf16(p0.y);
    a[2] = (short)f32_to_bf16(p0.z); a[3] = (short)f32_to_bf16(p0.w);
    a[4] = (short)f32_to_bf16(p1.x); a[5] = (short)f32_to_bf16(p1.y);
    a[6] = (short)f32_to_bf16(p1.z); a[7] = (short)f32_to_bf16(p1.w);
    const short8 b = *(const short8*)&vcT[((size_t)h * 64 + d) * 128 + ks * 32 + kgrp * 8];
    accp = __builtin_amdgcn_mfma_f32_16x16x32_bf16(a, b, accp, 0, 0, 0);
  }
#pragma unroll
  for (int r = 0; r < 4; r++)
    oc[(size_t)(t0 + kgrp * 4 + r) * 1024 + h * 64 + d] = accp[r];
}

// ------------- selected branch only: per-wave per-(h,t), writes osel -------------
__global__ __launch_bounds__(256) void nsa_sel(
    const unsigned short* __restrict__ qhf, const unsigned short* __restrict__ khfT,
    const unsigned short* __restrict__ vhf, const int4* __restrict__ sel,
    float* __restrict__ osel) {
  __shared__ float ps[4][64];
  __shared__ int tks[4][64];
  const int bid = blockIdx.x;
  const int h = ((bid & 7) << 1) | ((bid >> 3) & 1);
  const int w = threadIdx.x >> 6, lane = threadIdx.x & 63;
  const int t = (bid >> 4) * 4 + w;

  const unsigned short* kT = khfT + (size_t)h * 131072;
  const unsigned short* vhh = vhf + (size_t)h * 131072;

  uint4 qr[8];
  {
    const uint4* qp = (const uint4*)(qhf + (size_t)t * 1024 + h * 64);
#pragma unroll
    for (int j = 0; j < 8; j++) qr[j] = qp[j];
  }
  const int4 s4 = sel[((size_t)h << 11) + t];

  const int g16 = lane >> 4;
  const int blk = (g16 == 0) ? s4.x : (g16 == 1) ? s4.y : (g16 == 2) ? s4.z : s4.w;
  const int tok = blk * 16 + (lane & 15);
  tks[w][lane] = tok;
  {
    float a0 = 0.f, a1 = 0.f, a2 = 0.f, a3 = 0.f;
#pragma unroll
    for (int dc = 0; dc < 8; dc++) {
      const uint4 kk = *(const uint4*)(kT + ((size_t)dc * 2048 + tok) * 8);
      a0 = fdot2u(kk.x, qr[dc].x, a0);
      a1 = fdot2u(kk.y, qr[dc].y, a1);
      a2 = fdot2u(kk.z, qr[dc].z, a2);
      a3 = fdot2u(kk.w, qr[dc].w, a3);
    }
    const float sv_ = (tok <= t) ? ((a0 + a1) + (a2 + a3)) * 0.125f : NEGC;
    const float Ms = wred_max(sv_);
    const float es = __expf(sv_ - Ms);
    ps[w][lane] = es * (1.f / wred_sum(es));
  }

  const int dd = lane & 31, s = lane >> 5;
  const float4* ps4 = (const float4*)ps[w];
  const int4* tk4p = (const int4*)tks[w];

  float osx = 0.f, osy = 0.f;
#pragma unroll
  for (int jc = 0; jc < 8; jc++) {
    const float4 p4 = ps4[s * 8 + jc];
    const int4 t4 = tk4p[s * 8 + jc];
    const float pa[4] = {p4.x, p4.y, p4.z, p4.w};
    const int ta[4] = {t4.x, t4.y, t4.z, t4.w};
#pragma unroll
    for (int u = 0; u < 4; u++) {
      const unsigned int vv = *(const unsigned int*)(vhh + (size_t)ta[u] * 64 + 2 * dd);
      const h2 v2 = __builtin_bit_cast(h2, vv);
      osx += pa[u] * (float)v2[0];
      osy += pa[u] * (float)v2[1];
    }
  }
  osx += __shfl_xor(osx, 32, 64);
  osy += __shfl_xor(osy, 32, 64);

  if (lane < 32)
    *(float2*)&osel[(size_t)t * 1024 + h * 64 + 2 * dd] = make_float2(osx, osy);
}

// ------------- window branch via MFMA + gated combine -> outf -------------
__global__ __launch_bounds__(256) void nsa_win(
    const unsigned short* __restrict__ qhf, const unsigned short* __restrict__ khfT,
    const unsigned short* __restrict__ vhfT, const float* __restrict__ oc,
    const float* __restrict__ osel, const float* __restrict__ gates,
    unsigned short* __restrict__ outf) {
  __shared__ unsigned short P_lds[4][16][72];
  const int bid = blockIdx.x;
  const int h = bid & 15, tq0 = (bid >> 4) * 64;
  const int w = threadIdx.x >> 6, lane = threadIdx.x & 63;
  const int cc = lane & 15, kgrp = lane >> 4;
  const int qt0 = tq0 + w * 16;
  const int kb = qt0 - 32;

  const unsigned short* kT = khfT + (size_t)h * 131072;
  const unsigned short* vT = vhfT + (size_t)h * 131072;

  short8 aq[2];
#pragma unroll
  for (int ks = 0; ks < 2; ks++)
    aq[ks] = *(const short8*)&qhf[(size_t)(qt0 + cc) * 1024 + h * 64 + ks * 32 + kgrp * 8];

  floatx4 zero = {0.f, 0.f, 0.f, 0.f};
  floatx4 accs[3] = {zero, zero, zero};
#pragma unroll
  for (int ni = 0; ni < 3; ni++) {
    const int tokc = min(max(kb + ni * 16 + cc, 0), T_LEN - 1);
#pragma unroll
    for (int ks = 0; ks < 2; ks++) {
      const short8 bk = *(const short8*)&kT[((size_t)(ks * 4 + kgrp) * 2048 + tokc) * 8];
      accs[ni] = __builtin_amdgcn_mfma_f32_16x16x32_f16(
          __builtin_bit_cast(h8, aq[ks]), __builtin_bit_cast(h8, bk), accs[ni], 0, 0, 0);
    }
  }

#pragma unroll
  for (int r = 0; r < 4; r++) {
    const int t = qt0 + kgrp * 4 + r;
    float sc[3];
#pragma unroll
    for (int ni = 0; ni < 3; ni++) {
      const int s = kb + ni * 16 + cc;
      const int ds = t - s;
      sc[ni] = (s >= 0 && ds >= 0 && ds <= 32) ? accs[ni][r] * 0.125f : NEGC;
    }
    float m3 = fmaxf(fmaxf(sc[0], sc[1]), sc[2]);
#pragma unroll
    for (int o = 1; o <= 8; o <<= 1) m3 = fmaxf(m3, __shfl_xor(m3, o, 64));
    float e0 = __expf(sc[0] - m3), e1 = __expf(sc[1] - m3), e2 = __expf(sc[2] - m3);
    float sum = e0 + e1 + e2;
#pragma unroll
    for (int o = 1; o <= 8; o <<= 1) sum += __shfl_xor(sum, o, 64);
    const float inv = 1.f / sum;
    const int row = kgrp * 4 + r;
    P_lds[w][row][cc]      = f32_to_f16u(e0 * inv);
    P_lds[w][row][16 + cc] = f32_to_f16u(e1 * inv);
    P_lds[w][row][32 + cc] = f32_to_f16u(e2 * inv);
  }
  {
    const int rr = lane >> 2, c0 = 48 + (lane & 3) * 4;
    *(ushort4*)&P_lds[w][rr][c0] = make_ushort4(0, 0, 0, 0);
  }
  __syncthreads();

  floatx4 accp[4] = {zero, zero, zero, zero};
#pragma unroll
  for (int ks2 = 0; ks2 < 2; ks2++) {
    const short8 ap = *(const short8*)&P_lds[w][cc][ks2 * 32 + kgrp * 8];
    const int tok0 = min(max(kb + ks2 * 32 + kgrp * 8, 0), T_LEN - 8);
#pragma unroll
    for (int ni = 0; ni < 4; ni++) {
      const short8 bv = *(const short8*)&vT[(size_t)(ni * 16 + cc) * 2048 + tok0];
      accp[ni] = __builtin_amdgcn_mfma_f32_16x16x32_f16(
          __builtin_bit_cast(h8, ap), __builtin_bit_cast(h8, bv), accp[ni], 0, 0, 0);
    }
  }

#pragma unroll
  for (int r = 0; r < 4; r++) {
    const int t = qt0 + kgrp * 4 + r;
    const float g0 = gates[t * 3 + 0], g1 = gates[t * 3 + 1], g2 = gates[t * 3 + 2];
#pragma unroll
    for (int ni = 0; ni < 4; ni++) {
      const int d = ni * 16 + cc;
      const float ocv = oc[(size_t)t * 1024 + h * 64 + d];
      const float osv = osel[(size_t)t * 1024 + h * 64 + d];
      outf[(size_t)t * 1024 + h * 64 + d] =
          f32_to_bf16(g0 * ocv + g1 * osv + g2 * accp[ni][r]);
    }
  }
}

// ---------------- launch ----------------
extern "C" void kernel_launch(void* const* d_in, const int* in_sizes, int n_in,
                              void* d_out, int out_size, void* d_ws, size_t ws_size,
                              hipStream_t stream) {
  const float* x   = (const float*)d_in[0];
  const float* Wq  = (const float*)d_in[1];
  const float* Wk  = (const float*)d_in[2];
  const float* Wv  = (const float*)d_in[3];
  const float* Wo  = (const float*)d_in[4];
  const float* Wck = (const float*)d_in[5];
  const float* Wcv = (const float*)d_in[6];
  const float* Wg  = (const float*)d_in[7];
  const float* bg  = (const float*)d_in[8];
  float* out = (float*)d_out;

  float* ws = (float*)d_ws;
  // region A [0,24 MB): C until compress; then osel [0,8), oc [8,16), outf [16,20)
  float*          C    = ws;
  float*          osel = ws;                                // [0,8 MB)
  float*          oc   = ws + 2097152;                      // [8,16 MB)
  unsigned short* outf = (unsigned short*)(ws + 4194304);   // [16,20 MB)
  // region B [24,36 MB): Axf (4 MB) until qkv GEMM; then qh + smalls
  unsigned short* Axf   = (unsigned short*)(ws + 6291456);
  float*          qh    = ws + 6291456;                     // [24,32 MB)
  unsigned short* Wot   = (unsigned short*)(ws + 8388608);  // [32,34 MB)
  unsigned short* kc_hi = (unsigned short*)(ws + 8912896);
  unsigned short* kc_lo = (unsigned short*)(ws + 8978432);
  unsigned short* vcT   = (unsigned short*)(ws + 9043968);
  int4*           sel   = (int4*)(ws + 9109504);
  unsigned short* WckT_hi = (unsigned short*)(ws + 9240576);
  unsigned short* WckT_lo = (unsigned short*)(ws + 9273344);
  unsigned short* WcvT_hi = (unsigned short*)(ws + 9306112);
  unsigned short* WcvT_lo = (unsigned short*)(ws + 9338880);
  float*          gates   = ws + 9371648;
  // region C [36,48 MB): Bqkv f16 (6 MB) until qkv GEMM; then qhf/khfT/vhf f16
  unsigned short* Bqkv = (unsigned short*)(ws + 9437184);   // 3072x1024 f16, 6 MB
  unsigned short* qhf  = (unsigned short*)(ws + 9437184);   // [36,40 MB)
  unsigned short* khfT = (unsigned short*)(ws + 10485760);  // [40,44 MB)
  unsigned short* vhf  = (unsigned short*)(ws + 11534336);  // [44,48 MB)
  // vhfT scratch lives in d_out (read by nsa_win, then gemm_bt64 overwrites out)
  unsigned short* vhfT = (unsigned short*)d_out;            // 16x64x2048 f16, 4 MB

  // 1. operand preparation (merged weight casts: 1 kernel, was 3)
  cast_x_k<<<2048, 256, 0, stream>>>(x, Axf);
  cast_weights<<<dim3(32, 32, 6), dim3(32, 8), 0, stream>>>(
      Wq, Wk, Wv, Wo, Wck, Wcv, Bqkv, Wot, WckT_hi, WckT_lo, WcvT_hi, WcvT_lo);

  // 2. merged q|k|v GEMM: 64x128 BK=32, 3-buffer counted-vmcnt (structural floor)
  qkv_gemm<<<dim3(24, 32), 256, 0, stream>>>(Axf, Bqkv, C);

  // 3. reorg (+ V transpose for window MFMA) + gates
  reorg_qkv<<<6144, 256, 0, stream>>>(C, qh, qhf, khfT, vhf);
  transp_v<<<dim3(64, 2, 16), dim3(32, 8), 0, stream>>>(vhf, vhfT);
  gates_k<<<512, 256, 0, stream>>>(C, Wg, bg, gates);

  // 4. compression (reads C; C dead after) + compressed branch (oc aliases C tail)
  compress_mfma<<<dim3(128, 2), 512, 0, stream>>>(C, WckT_hi, WckT_lo, WcvT_hi, WcvT_lo,
                                                  kc_hi, kc_lo, vcT);
  cscore_k<<<2048, 256, 0, stream>>>(qh, kc_hi, kc_lo, vcT, oc, sel);

  // 5. selected branch (scalar, per-query) -> osel; window branch (MFMA) + combine
  nsa_sel<<<8192, 256, 0, stream>>>(qhf, khfT, vhf, sel, osel);
  nsa_win<<<512, 256, 0, stream>>>(qhf, khfT, vhfT, oc, osel, gates, outf);

  // 6. output projection: 64x64 tile, 512 blocks (2/CU) — r11 occupancy fix
  gemm_bt64<<<dim3(16, 32), 256, 0, stream>>>(outf, Wot, out, 1024, 1024, 1024);
}

// Round 13
// 230.651 us; speedup vs baseline: 1.0725x; 1.0184x over previous
//
#include <hip/hip_runtime.h>
#include <hip/hip_bf16.h>
#include <float.h>

#define T_LEN 2048
#define DM    1024
#define NB    128
#define NEGC  (-1e9f)

typedef __attribute__((ext_vector_type(8))) short short8;
typedef __attribute__((ext_vector_type(4))) float floatx4;
typedef _Float16 h2 __attribute__((ext_vector_type(2)));
typedef _Float16 h8 __attribute__((ext_vector_type(8)));

// ---------------- helpers ----------------
__device__ __forceinline__ float wred_max(float v) {
#pragma unroll
  for (int o = 32; o > 0; o >>= 1) v = fmaxf(v, __shfl_xor(v, o, 64));
  return v;
}
__device__ __forceinline__ float wred_sum(float v) {
#pragma unroll
  for (int o = 32; o > 0; o >>= 1) v += __shfl_xor(v, o, 64);
  return v;
}
__device__ __forceinline__ unsigned short f32_to_bf16(float f) {
  unsigned int b = __float_as_uint(f);
  return (unsigned short)((b + 0x7fffu + ((b >> 16) & 1u)) >> 16);
}
__device__ __forceinline__ float bf16_to_f32(unsigned short u) {
  return __uint_as_float(((unsigned int)u) << 16);
}
__device__ __forceinline__ unsigned int pack_h2(float a, float b) {
  h2 r; r[0] = (_Float16)a; r[1] = (_Float16)b;
  return __builtin_bit_cast(unsigned int, r);
}
__device__ __forceinline__ unsigned short f32_to_f16u(float f) {
  h2 r; r[0] = (_Float16)f; r[1] = (_Float16)0.f;
  return (unsigned short)(__builtin_bit_cast(unsigned int, r) & 0xffffu);
}
__device__ __forceinline__ float fdot2u(unsigned int a, unsigned int b, float c) {
#if __has_builtin(__builtin_amdgcn_fdot2)
  return __builtin_amdgcn_fdot2(__builtin_bit_cast(h2, a), __builtin_bit_cast(h2, b), c, false);
#else
  const h2 av = __builtin_bit_cast(h2, a), bv = __builtin_bit_cast(h2, b);
  return c + (float)av[0] * (float)bv[0] + (float)av[1] * (float)bv[1];
#endif
}
__device__ __forceinline__ void lds_async16(unsigned short* l, const unsigned short* g) {
  __builtin_amdgcn_global_load_lds(
      (const __attribute__((address_space(1))) unsigned int*)g,
      (__attribute__((address_space(3))) unsigned int*)l, 16, 0, 0);
}

// ====== 64x128-tile MFMA GEMM core — BK=32, 3-buffer counted-vmcnt (r10) ======
// qkv DONE at this structure (r10 null: 2-ahead == 1-ahead == 43 us, 297 TF
// ~= the known plain-HIP 2-barrier value at this shape).
template <bool F16>
__device__ __forceinline__ void gemm64_core(
    const unsigned short* __restrict__ A, const unsigned short* __restrict__ Bt,
    float* __restrict__ C, int K, int lda, int row0, int bcol0, int ccol0, int ldc,
    unsigned short* As, unsigned short* Bs) {
  const int tid = threadIdx.x;
  const int w = tid >> 6, lane = tid & 63;
  const int wr = w >> 1, wc = w & 1;
  const int mrow = lane & 15, kgrp = lane >> 4;

  const int sr = (w << 4) + mrow;          // staged row 0..63
  const int sc = kgrp;                     // staged chunk 0..3

  floatx4 zero = {0.f, 0.f, 0.f, 0.f};
  floatx4 acc[2][4];
#pragma unroll
  for (int i = 0; i < 2; i++)
#pragma unroll
    for (int j = 0; j < 4; j++) acc[i][j] = zero;

  const int nt = K >> 5;
  const unsigned short* Ap  = A  + (size_t)(row0 + sr) * lda + sc * 8;
  const unsigned short* Bp0 = Bt + (size_t)(bcol0 + sr) * K + sc * 8;
  const unsigned short* Bp1 = Bt + (size_t)(bcol0 + 64 + sr) * K + sc * 8;

  auto stage = [&](int t, int b) {
    lds_async16(&As[b * 2048 + w * 512], Ap + t * 32);
    lds_async16(&Bs[b * 4096 + w * 512], Bp0 + t * 32);
    lds_async16(&Bs[b * 4096 + 2048 + w * 512], Bp1 + t * 32);
  };

  stage(0, 0);
  if (nt > 1) stage(1, 1);
  int cur = 0;
  for (int t = 0; t < nt; t++) {
    if (t + 2 < nt) {
      const int nx = (cur + 2 >= 3) ? cur - 1 : cur + 2;
      stage(t + 2, nx);                                   // outstanding: 9
      asm volatile("s_waitcnt vmcnt(6)" ::: "memory");    // tile t landed
    } else if (t + 1 < nt) {
      asm volatile("s_waitcnt vmcnt(3)" ::: "memory");
    } else {
      asm volatile("s_waitcnt vmcnt(0)" ::: "memory");
    }
    __builtin_amdgcn_s_barrier();
    const unsigned short* as = As + cur * 2048;
    const unsigned short* bs = Bs + cur * 4096;
    short8 af[2], bf4[4];
#pragma unroll
    for (int mi = 0; mi < 2; mi++)
      af[mi] = *(const short8*)&as[(wr * 2 + mi) * 512 + kgrp * 128 + mrow * 8];
#pragma unroll
    for (int ni = 0; ni < 4; ni++)
      bf4[ni] = *(const short8*)&bs[(wc * 4 + ni) * 512 + kgrp * 128 + mrow * 8];
#pragma unroll
    for (int mi = 0; mi < 2; mi++)
#pragma unroll
      for (int ni = 0; ni < 4; ni++) {
        if constexpr (F16)
          acc[mi][ni] = __builtin_amdgcn_mfma_f32_16x16x32_f16(
              __builtin_bit_cast(h8, af[mi]), __builtin_bit_cast(h8, bf4[ni]),
              acc[mi][ni], 0, 0, 0);
        else
          acc[mi][ni] = __builtin_amdgcn_mfma_f32_16x16x32_bf16(af[mi], bf4[ni],
                                                                acc[mi][ni], 0, 0, 0);
      }
    asm volatile("" ::: "memory");
    __builtin_amdgcn_s_barrier();
    cur = (cur + 1 == 3) ? 0 : cur + 1;
  }
#pragma unroll
  for (int mi = 0; mi < 2; mi++)
#pragma unroll
    for (int ni = 0; ni < 4; ni++) {
      float* Cp = C + (size_t)(row0 + wr * 32 + mi * 16 + kgrp * 4) * ldc
                    + ccol0 + wc * 64 + ni * 16 + mrow;
      Cp[0] = acc[mi][ni][0];
      Cp[(size_t)ldc] = acc[mi][ni][1];
      Cp[(size_t)2 * ldc] = acc[mi][ni][2];
      Cp[(size_t)3 * ldc] = acc[mi][ni][3];
    }
}

// merged q|k|v GEMM: grid (24, 32) = 768 blocks (3/CU), f16 K=1024 single pass.
__global__ __launch_bounds__(256) void qkv_gemm(const unsigned short* __restrict__ Axf,
                                                const unsigned short* __restrict__ Bqkv,
                                                float* __restrict__ C) {
  __shared__ __align__(16) unsigned short As[3 * 64 * 32];
  __shared__ __align__(16) unsigned short Bs[3 * 128 * 32];
  gemm64_core<true>(Axf, Bqkv, C, 1024, 1024, blockIdx.y * 64,
                    blockIdx.x * 128, blockIdx.x * 128, 3072, As, Bs);
}

// ====== output projection — 64x64 tile, grid (16,32) = 512 blocks (2/CU) ======
// (r11 occupancy fix: 2 waves/SIMD so TLP hides the stage wait.)
__global__ __launch_bounds__(256) void gemm_bt64(const unsigned short* __restrict__ A,
                                                 const unsigned short* __restrict__ Bt,
                                                 float* __restrict__ C,
                                                 int K, int lda, int ldc) {
  __shared__ __align__(16) unsigned short As[3 * 2048];
  __shared__ __align__(16) unsigned short Bs[3 * 2048];
  const int tid = threadIdx.x;
  const int w = tid >> 6, lane = tid & 63;
  const int wr = w >> 1, wc = w & 1;
  const int mrow = lane & 15, kgrp = lane >> 4;
  const int row0 = blockIdx.y * 64, col0 = blockIdx.x * 64;

  const int sr = (w << 4) + mrow;

  floatx4 zero = {0.f, 0.f, 0.f, 0.f};
  floatx4 acc[2][2];
#pragma unroll
  for (int i = 0; i < 2; i++)
#pragma unroll
    for (int j = 0; j < 2; j++) acc[i][j] = zero;

  const int nt = K >> 5;
  const unsigned short* Ap = A + (size_t)(row0 + sr) * lda + kgrp * 8;
  const unsigned short* Bp = Bt + (size_t)(col0 + sr) * K + kgrp * 8;

  auto stage = [&](int t, int b) {
    lds_async16(&As[b * 2048 + w * 512], Ap + t * 32);
    lds_async16(&Bs[b * 2048 + w * 512], Bp + t * 32);
  };

  stage(0, 0);
  if (nt > 1) stage(1, 1);
  int cur = 0;
  for (int t = 0; t < nt; t++) {
    if (t + 2 < nt) {
      const int nx = (cur + 2 >= 3) ? cur - 1 : cur + 2;
      stage(t + 2, nx);                                   // outstanding: 6
      asm volatile("s_waitcnt vmcnt(4)" ::: "memory");    // tile t landed
    } else if (t + 1 < nt) {
      asm volatile("s_waitcnt vmcnt(2)" ::: "memory");
    } else {
      asm volatile("s_waitcnt vmcnt(0)" ::: "memory");
    }
    __builtin_amdgcn_s_barrier();
    const unsigned short* as = As + cur * 2048;
    const unsigned short* bs = Bs + cur * 2048;
    short8 af[2], bf2[2];
#pragma unroll
    for (int mi = 0; mi < 2; mi++)
      af[mi] = *(const short8*)&as[(wr * 2 + mi) * 512 + kgrp * 128 + mrow * 8];
#pragma unroll
    for (int ni = 0; ni < 2; ni++)
      bf2[ni] = *(const short8*)&bs[(wc * 2 + ni) * 512 + kgrp * 128 + mrow * 8];
#pragma unroll
    for (int mi = 0; mi < 2; mi++)
#pragma unroll
      for (int ni = 0; ni < 2; ni++)
        acc[mi][ni] = __builtin_amdgcn_mfma_f32_16x16x32_bf16(af[mi], bf2[ni],
                                                              acc[mi][ni], 0, 0, 0);
    asm volatile("" ::: "memory");
    __builtin_amdgcn_s_barrier();
    cur = (cur + 1 == 3) ? 0 : cur + 1;
  }
#pragma unroll
  for (int mi = 0; mi < 2; mi++)
#pragma unroll
    for (int ni = 0; ni < 2; ni++) {
      float* Cp = C + (size_t)(row0 + wr * 32 + mi * 16 + kgrp * 4) * ldc
                    + col0 + wc * 32 + ni * 16 + mrow;
      Cp[0] = acc[mi][ni][0];
      Cp[(size_t)ldc] = acc[mi][ni][1];
      Cp[(size_t)2 * ldc] = acc[mi][ni][2];
      Cp[(size_t)3 * ldc] = acc[mi][ni][3];
    }
}

// ---- merged operand prep (r12: +x cast; was cast_x + 3 weight kernels at r10)
// z 0-2: Wq/Wk/Wv -> Bqkv f16 (3072n x 1024k); z=3: Wo -> Wot bf16;
// z 4-5: Wck/Wcv (1024x64) -> (64,1024) hi/lo bf16 (x>=2 blocks no-op);
// z 6-7: x -> Axf f16 flat copy-cast (1024 blocks/slice, 1 float4/thread).
__global__ void cast_weights(const float* __restrict__ x,
                             const float* __restrict__ Wq, const float* __restrict__ Wk,
                             const float* __restrict__ Wv, const float* __restrict__ Wo,
                             const float* __restrict__ Wck, const float* __restrict__ Wcv,
                             unsigned short* __restrict__ Axf,
                             unsigned short* __restrict__ Bqkv, unsigned short* __restrict__ Wot,
                             unsigned short* __restrict__ KT_hi, unsigned short* __restrict__ KT_lo,
                             unsigned short* __restrict__ VT_hi, unsigned short* __restrict__ VT_lo) {
  __shared__ float tile[32][33];
  const int z = blockIdx.z;
  const int tx = threadIdx.x, ty = threadIdx.y;
  const int kt0 = blockIdx.y * 32, nt0 = blockIdx.x * 32;
  if (z < 3) {
    const float* W = (z == 0) ? Wq : (z == 1) ? Wk : Wv;
#pragma unroll
    for (int i = 0; i < 32; i += 8)
      tile[ty + i][tx] = W[(size_t)(kt0 + ty + i) * 1024 + nt0 + tx];
    __syncthreads();
#pragma unroll
    for (int i = 0; i < 32; i += 8) {
      const int n = nt0 + ty + i, kk = kt0 + tx;
      Bqkv[(size_t)(z * 1024 + n) * 1024 + kk] = f32_to_f16u(tile[tx][ty + i]);
    }
  } else if (z == 3) {
#pragma unroll
    for (int i = 0; i < 32; i += 8)
      tile[ty + i][tx] = Wo[(size_t)(kt0 + ty + i) * 1024 + nt0 + tx];
    __syncthreads();
#pragma unroll
    for (int i = 0; i < 32; i += 8) {
      const int n = nt0 + ty + i, kk = kt0 + tx;
      Wot[(size_t)n * 1024 + kk] = f32_to_bf16(tile[tx][ty + i]);
    }
  } else if (z < 6) {
    if (nt0 >= 64) return;
    const float* W = (z == 5) ? Wcv : Wck;
    unsigned short* Bh = (z == 5) ? VT_hi : KT_hi;
    unsigned short* Bl = (z == 5) ? VT_lo : KT_lo;
#pragma unroll
    for (int i = 0; i < 32; i += 8)
      tile[ty + i][tx] = W[(size_t)(kt0 + ty + i) * 64 + nt0 + tx];
    __syncthreads();
#pragma unroll
    for (int i = 0; i < 32; i += 8) {
      const int n = nt0 + ty + i, kk = kt0 + tx;
      const float f = tile[tx][ty + i];
      const unsigned short hb = f32_to_bf16(f);
      Bh[(size_t)n * 1024 + kk] = hb;
      Bl[(size_t)n * 1024 + kk] = f32_to_bf16(f - bf16_to_f32(hb));
    }
  } else {
    // x -> f16: flat; slice z-6 covers 1024 blocks x 256 thr x 1 float4
    const size_t q4 = ((size_t)(z - 6) * 1024 + blockIdx.y * 32 + blockIdx.x) * 256
                      + ty * 32 + tx;
    const float4 xv = ((const float4*)x)[q4];
    const unsigned int p0 = pack_h2(xv.x, xv.y);
    const unsigned int p1 = pack_h2(xv.z, xv.w);
    *(uint2*)&Axf[q4 * 4] = make_uint2(p0, p1);
  }
}

// ---------------- reorg + gates merged (r12; saves a launch gap) ----------------
// bid < 6144: C(t,3072) -> qhf f16 (T,1024), khfT f16 (H,8,T,8), vhf f16
// (H,T,64). qh DELETED (cscore now reads C directly; oc relocated so C stays
// alive through cscore). bid >= 6144: gates (reads C q-cols, writes gates[t]).
__global__ __launch_bounds__(256) void reorg_qkv(const float* __restrict__ C,
                                                 unsigned short* __restrict__ qhf,
                                                 unsigned short* __restrict__ khfT,
                                                 unsigned short* __restrict__ vhf,
                                                 const float* __restrict__ Wg,
                                                 const float* __restrict__ bg,
                                                 float* __restrict__ gates) {
  const int bid = blockIdx.x;
  if (bid < 6144) {
    const int gid = bid * 256 + threadIdx.x;
    const int t = gid / 768;
    const int c = (gid - t * 768) * 4;
    float4 val = *(const float4*)&C[(size_t)t * 3072 + c];
    const unsigned int p0 = pack_h2(val.x, val.y);
    const unsigned int p1 = pack_h2(val.z, val.w);
    if (c < 1024) {
      *(uint2*)&qhf[(size_t)t * 1024 + c] = make_uint2(p0, p1);
    } else if (c < 2048) {
      const int h = (c >> 6) & 15, d = c & 63;
      const int dc = d >> 3, j = d & 7;
      *(uint2*)&khfT[((size_t)(h * 8 + dc) * 2048 + t) * 8 + j] = make_uint2(p0, p1);
    } else {
      const int h = (c >> 6) & 15, d = c & 63;
      *(uint2*)&vhf[((size_t)h * 2048 + t) * 64 + d] = make_uint2(p0, p1);
    }
  } else {
    const int w = threadIdx.x >> 6, lane = threadIdx.x & 63;
    const int t = (bid - 6144) * 4 + w;
    float m = 0.f;
#pragma unroll
    for (int h = 0; h < 16; h++) m += C[(size_t)t * 3072 + h * 64 + lane];
    m *= (1.f / 16.f);
    float g0 = wred_sum(m * Wg[lane * 3 + 0]);
    float g1 = wred_sum(m * Wg[lane * 3 + 1]);
    float g2 = wred_sum(m * Wg[lane * 3 + 2]);
    if (lane == 0) {
      g0 += bg[0]; g1 += bg[1]; g2 += bg[2];
      float mx = fmaxf(g0, fmaxf(g1, g2));
      float e0 = __expf(g0 - mx), e1 = __expf(g1 - mx), e2 = __expf(g2 - mx);
      float inv = 1.f / (e0 + e1 + e2);
      gates[t * 3 + 0] = e0 * inv;
      gates[t * 3 + 1] = e1 * inv;
      gates[t * 3 + 2] = e2 * inv;
    }
  }
}

// ---- transpose vhf [h][t][64] -> vhfT [h][d][2048] f16 (for window PV MFMA) ----
__global__ void transp_v(const unsigned short* __restrict__ vhf,
                         unsigned short* __restrict__ vhfT) {
  __shared__ unsigned short tile[32][34];
  const int h = blockIdx.z;
  const int t0 = blockIdx.x * 32, d0 = blockIdx.y * 32;
  const int tx = threadIdx.x, ty = threadIdx.y;
#pragma unroll
  for (int i = 0; i < 32; i += 8)
    tile[ty + i][tx] = vhf[((size_t)h * 2048 + t0 + ty + i) * 64 + d0 + tx];
  __syncthreads();
#pragma unroll
  for (int i = 0; i < 32; i += 8)
    vhfT[((size_t)h * 64 + d0 + ty + i) * 2048 + t0 + tx] = tile[tx][ty + i];
}

// ---------------- compress via MFMA (reads k/v straight from C) ----------------
__global__ __launch_bounds__(512) void compress_mfma(
    const float* __restrict__ C,
    const unsigned short* __restrict__ KT_hi, const unsigned short* __restrict__ KT_lo,
    const unsigned short* __restrict__ VT_hi, const unsigned short* __restrict__ VT_lo,
    unsigned short* __restrict__ kc_hi, unsigned short* __restrict__ kc_lo,
    unsigned short* __restrict__ vcT) {
  __shared__ float red[8][64][17];
  const int isv = blockIdx.y;
  const unsigned short* Bh = isv ? VT_hi : KT_hi;
  const unsigned short* Bl = isv ? VT_lo : KT_lo;
  const int tid = threadIdx.x, w = tid >> 6, lane = tid & 63;
  const int mrow = lane & 15, kgrp = lane >> 4;
  const int m0 = blockIdx.x * 16;
  const int m = m0 + mrow;
  const int hh = m >> 7, nb = m & 127;
  const int cbase = 1024 + isv * 1024 + hh * 64;

  floatx4 zero = {0.f, 0.f, 0.f, 0.f};
  floatx4 acc[4] = {zero, zero, zero, zero};

  const int kbeg = w << 7;
  for (int k0 = kbeg; k0 < kbeg + 128; k0 += 32) {
    const int c = k0 + kgrp * 8;
    const float* ap = &C[(size_t)(nb * 16 + (c >> 6)) * 3072 + cbase + (c & 63)];
    float4 q0 = *(const float4*)ap;
    float4 q1 = *(const float4*)(ap + 4);
    float qq[8] = {q0.x, q0.y, q0.z, q0.w, q1.x, q1.y, q1.z, q1.w};
    short8 a_hi, a_lo;
#pragma unroll
    for (int j = 0; j < 8; j++) {
      unsigned short hb = f32_to_bf16(qq[j]);
      a_hi[j] = (short)hb;
      a_lo[j] = (short)f32_to_bf16(qq[j] - bf16_to_f32(hb));
    }
#pragma unroll
    for (int ni = 0; ni < 4; ni++) {
      const size_t boff = (size_t)(ni * 16 + mrow) * 1024 + k0 + kgrp * 8;
      short8 b_hi = *(const short8*)&Bh[boff];
      short8 b_lo = *(const short8*)&Bl[boff];
      acc[ni] = __builtin_amdgcn_mfma_f32_16x16x32_bf16(a_hi, b_hi, acc[ni], 0, 0, 0);
      acc[ni] = __builtin_amdgcn_mfma_f32_16x16x32_bf16(a_lo, b_hi, acc[ni], 0, 0, 0);
      acc[ni] = __builtin_amdgcn_mfma_f32_16x16x32_bf16(a_hi, b_lo, acc[ni], 0, 0, 0);
    }
  }

#pragma unroll
  for (int ni = 0; ni < 4; ni++)
#pragma unroll
    for (int r = 0; r < 4; r++) red[w][lane][ni * 4 + r] = acc[ni][r];
  __syncthreads();

  if (w < 4) {
#pragma unroll
    for (int r = 0; r < 4; r++) {
      const int j = w * 4 + r;
      float val = 0.f;
#pragma unroll
      for (int ww = 0; ww < 8; ww++) val += red[ww][lane][j];
      const int mo = m0 + kgrp * 4 + r;
      const int d = w * 16 + mrow;
      if (!isv) {
        const unsigned short hb = f32_to_bf16(val);
        kc_hi[(size_t)mo * 64 + d] = hb;
        kc_lo[(size_t)mo * 64 + d] = f32_to_bf16(val - bf16_to_f32(hb));
      } else {
        vcT[(size_t)(mo >> 7) * 8192 + (size_t)d * 128 + (mo & 127)] = f32_to_bf16(val);
      }
    }
  }
}

// ------- cscore: MFMA scores + softmax + top-4 + fused PV (r7 fast argmax) -------
// r12: reads q straight from C (qh deleted; oc relocated so C is alive here).
__global__ __launch_bounds__(256) void cscore_k(
    const float* __restrict__ C, const unsigned short* __restrict__ kc_hi,
    const unsigned short* __restrict__ kc_lo, const unsigned short* __restrict__ vcT,
    float* __restrict__ oc, int4* __restrict__ sel) {
  __shared__ float S_s[16][132];
  const int h = blockIdx.x >> 7, t0 = (blockIdx.x & 127) * 16;
  const int tid = threadIdx.x, w = tid >> 6, lane = tid & 63;
  const int mrow = lane & 15, kgrp = lane >> 4;

  short8 a_hi[2], a_lo[2];
#pragma unroll
  for (int ks = 0; ks < 2; ks++) {
    const float* qp = &C[(size_t)(t0 + mrow) * 3072 + h * 64 + ks * 32 + kgrp * 8];
    float4 q0 = *(const float4*)qp;
    float4 q1 = *(const float4*)(qp + 4);
    float qq[8] = {q0.x, q0.y, q0.z, q0.w, q1.x, q1.y, q1.z, q1.w};
#pragma unroll
    for (int j = 0; j < 8; j++) {
      unsigned short hb = f32_to_bf16(qq[j]);
      a_hi[ks][j] = (short)hb;
      a_lo[ks][j] = (short)f32_to_bf16(qq[j] - bf16_to_f32(hb));
    }
  }
  floatx4 zero = {0.f, 0.f, 0.f, 0.f};
  floatx4 acc[2] = {zero, zero};
#pragma unroll
  for (int ni = 0; ni < 2; ni++) {
    const int nb = w * 32 + ni * 16 + mrow;
#pragma unroll
    for (int ks = 0; ks < 2; ks++) {
      const size_t off = ((size_t)h * 128 + nb) * 64 + ks * 32 + kgrp * 8;
      short8 b_hi = *(const short8*)&kc_hi[off];
      short8 b_lo = *(const short8*)&kc_lo[off];
      acc[ni] = __builtin_amdgcn_mfma_f32_16x16x32_bf16(a_hi[ks], b_hi, acc[ni], 0, 0, 0);
      acc[ni] = __builtin_amdgcn_mfma_f32_16x16x32_bf16(a_lo[ks], b_hi, acc[ni], 0, 0, 0);
      acc[ni] = __builtin_amdgcn_mfma_f32_16x16x32_bf16(a_hi[ks], b_lo, acc[ni], 0, 0, 0);
    }
  }
#pragma unroll
  for (int ni = 0; ni < 2; ni++) {
    const int n = w * 32 + ni * 16 + mrow;
#pragma unroll
    for (int r = 0; r < 4; r++) {
      const int row = kgrp * 4 + r;
      const int count = (t0 + row) >> 4;
      S_s[row][n] = (n < count) ? acc[ni][r] * 0.125f : NEGC;
    }
  }
  __syncthreads();

#pragma unroll
  for (int qq = 0; qq < 4; qq++) {
    const int row = w * 4 + qq, t = t0 + row, count = t >> 4;
    const float2 sv = *(const float2*)&S_s[row][2 * lane];
    const float s0 = sv.x, s1 = sv.y;
    const float M = wred_max(fmaxf(s0, s1));
    const float e0 = __expf(s0 - M), e1 = __expf(s1 - M);
    const float inv = 1.f / wred_sum(e0 + e1);
    S_s[row][2 * lane]     = (count == 0) ? 0.f : e0 * inv;
    S_s[row][2 * lane + 1] = (count == 0) ? 0.f : e1 * inv;

    float c0 = s0, c1 = s1;
    float curM = M;
    int se0 = 0, se1 = 0, se2 = 0, se3 = 0;
#pragma unroll
    for (int j = 0; j < 4; j++) {
      if (j) curM = wred_max(fmaxf(c0, c1));
      const unsigned long long b = __ballot((c0 == curM) || (c1 == curM));
      const int lidx = (int)__builtin_ctzll(b);
      const float c0l = __shfl(c0, lidx, 64);
      const int isc0 = (c0l == curM);
      const int idx = 2 * lidx + (isc0 ? 0 : 1);
      if (j == 0) se0 = idx; else if (j == 1) se1 = idx;
      else if (j == 2) se2 = idx; else se3 = idx;
      if (lane == lidx) { if (isc0) c0 = -FLT_MAX; else c1 = -FLT_MAX; }
    }
    if (lane == 0) sel[((size_t)h << 11) + t] = make_int4(se0, se1, se2, se3);
  }
  __syncthreads();

  const int d = w * 16 + mrow;
  floatx4 accp = zero;
#pragma unroll
  for (int ks = 0; ks < 4; ks++) {
    const float4 p0 = *(const float4*)&S_s[mrow][ks * 32 + kgrp * 8];
    const float4 p1 = *(const float4*)&S_s[mrow][ks * 32 + kgrp * 8 + 4];
    short8 a;
    a[0] = (short)f32_to_bf16(p0.x); a[1] = (short)f32_to_bf16(p0.y);
    a[2] = (short)f32_to_bf16(p0.z); a[3] = (short)f32_to_bf16(p0.w);
    a[4] = (short)f32_to_bf16(p1.x); a[5] = (short)f32_to_bf16(p1.y);
    a[6] = (short)f32_to_bf16(p1.z); a[7] = (short)f32_to_bf16(p1.w);
    const short8 b = *(const short8*)&vcT[((size_t)h * 64 + d) * 128 + ks * 32 + kgrp * 8];
    accp = __builtin_amdgcn_mfma_f32_16x16x32_bf16(a, b, accp, 0, 0, 0);
  }
#pragma unroll
  for (int r = 0; r < 4; r++)
    oc[(size_t)(t0 + kgrp * 4 + r) * 1024 + h * 64 + d] = accp[r];
}

// ------------- selected branch only: per-wave per-(h,t), writes osel -------------
__global__ __launch_bounds__(256) void nsa_sel(
    const unsigned short* __restrict__ qhf, const unsigned short* __restrict__ khfT,
    const unsigned short* __restrict__ vhf, const int4* __restrict__ sel,
    float* __restrict__ osel) {
  __shared__ float ps[4][64];
  __shared__ int tks[4][64];
  const int bid = blockIdx.x;
  const int h = ((bid & 7) << 1) | ((bid >> 3) & 1);
  const int w = threadIdx.x >> 6, lane = threadIdx.x & 63;
  const int t = (bid >> 4) * 4 + w;

  const unsigned short* kT = khfT + (size_t)h * 131072;
  const unsigned short* vhh = vhf + (size_t)h * 131072;

  uint4 qr[8];
  {
    const uint4* qp = (const uint4*)(qhf + (size_t)t * 1024 + h * 64);
#pragma unroll
    for (int j = 0; j < 8; j++) qr[j] = qp[j];
  }
  const int4 s4 = sel[((size_t)h << 11) + t];

  const int g16 = lane >> 4;
  const int blk = (g16 == 0) ? s4.x : (g16 == 1) ? s4.y : (g16 == 2) ? s4.z : s4.w;
  const int tok = blk * 16 + (lane & 15);
  tks[w][lane] = tok;
  {
    float a0 = 0.f, a1 = 0.f, a2 = 0.f, a3 = 0.f;
#pragma unroll
    for (int dc = 0; dc < 8; dc++) {
      const uint4 kk = *(const uint4*)(kT + ((size_t)dc * 2048 + tok) * 8);
      a0 = fdot2u(kk.x, qr[dc].x, a0);
      a1 = fdot2u(kk.y, qr[dc].y, a1);
      a2 = fdot2u(kk.z, qr[dc].z, a2);
      a3 = fdot2u(kk.w, qr[dc].w, a3);
    }
    const float sv_ = (tok <= t) ? ((a0 + a1) + (a2 + a3)) * 0.125f : NEGC;
    const float Ms = wred_max(sv_);
    const float es = __expf(sv_ - Ms);
    ps[w][lane] = es * (1.f / wred_sum(es));
  }

  const int dd = lane & 31, s = lane >> 5;
  const float4* ps4 = (const float4*)ps[w];
  const int4* tk4p = (const int4*)tks[w];

  float osx = 0.f, osy = 0.f;
#pragma unroll
  for (int jc = 0; jc < 8; jc++) {
    const float4 p4 = ps4[s * 8 + jc];
    const int4 t4 = tk4p[s * 8 + jc];
    const float pa[4] = {p4.x, p4.y, p4.z, p4.w};
    const int ta[4] = {t4.x, t4.y, t4.z, t4.w};
#pragma unroll
    for (int u = 0; u < 4; u++) {
      const unsigned int vv = *(const unsigned int*)(vhh + (size_t)ta[u] * 64 + 2 * dd);
      const h2 v2 = __builtin_bit_cast(h2, vv);
      osx += pa[u] * (float)v2[0];
      osy += pa[u] * (float)v2[1];
    }
  }
  osx += __shfl_xor(osx, 32, 64);
  osy += __shfl_xor(osy, 32, 64);

  if (lane < 32)
    *(float2*)&osel[(size_t)t * 1024 + h * 64 + 2 * dd] = make_float2(osx, osy);
}

// ------------- window branch via MFMA + gated combine -> outf -------------
__global__ __launch_bounds__(256) void nsa_win(
    const unsigned short* __restrict__ qhf, const unsigned short* __restrict__ khfT,
    const unsigned short* __restrict__ vhfT, const float* __restrict__ oc,
    const float* __restrict__ osel, const float* __restrict__ gates,
    unsigned short* __restrict__ outf) {
  __shared__ unsigned short P_lds[4][16][72];
  const int bid = blockIdx.x;
  const int h = bid & 15, tq0 = (bid >> 4) * 64;
  const int w = threadIdx.x >> 6, lane = threadIdx.x & 63;
  const int cc = lane & 15, kgrp = lane >> 4;
  const int qt0 = tq0 + w * 16;
  const int kb = qt0 - 32;

  const unsigned short* kT = khfT + (size_t)h * 131072;
  const unsigned short* vT = vhfT + (size_t)h * 131072;

  short8 aq[2];
#pragma unroll
  for (int ks = 0; ks < 2; ks++)
    aq[ks] = *(const short8*)&qhf[(size_t)(qt0 + cc) * 1024 + h * 64 + ks * 32 + kgrp * 8];

  floatx4 zero = {0.f, 0.f, 0.f, 0.f};
  floatx4 accs[3] = {zero, zero, zero};
#pragma unroll
  for (int ni = 0; ni < 3; ni++) {
    const int tokc = min(max(kb + ni * 16 + cc, 0), T_LEN - 1);
#pragma unroll
    for (int ks = 0; ks < 2; ks++) {
      const short8 bk = *(const short8*)&kT[((size_t)(ks * 4 + kgrp) * 2048 + tokc) * 8];
      accs[ni] = __builtin_amdgcn_mfma_f32_16x16x32_f16(
          __builtin_bit_cast(h8, aq[ks]), __builtin_bit_cast(h8, bk), accs[ni], 0, 0, 0);
    }
  }

#pragma unroll
  for (int r = 0; r < 4; r++) {
    const int t = qt0 + kgrp * 4 + r;
    float sc[3];
#pragma unroll
    for (int ni = 0; ni < 3; ni++) {
      const int s = kb + ni * 16 + cc;
      const int ds = t - s;
      sc[ni] = (s >= 0 && ds >= 0 && ds <= 32) ? accs[ni][r] * 0.125f : NEGC;
    }
    float m3 = fmaxf(fmaxf(sc[0], sc[1]), sc[2]);
#pragma unroll
    for (int o = 1; o <= 8; o <<= 1) m3 = fmaxf(m3, __shfl_xor(m3, o, 64));
    float e0 = __expf(sc[0] - m3), e1 = __expf(sc[1] - m3), e2 = __expf(sc[2] - m3);
    float sum = e0 + e1 + e2;
#pragma unroll
    for (int o = 1; o <= 8; o <<= 1) sum += __shfl_xor(sum, o, 64);
    const float inv = 1.f / sum;
    const int row = kgrp * 4 + r;
    P_lds[w][row][cc]      = f32_to_f16u(e0 * inv);
    P_lds[w][row][16 + cc] = f32_to_f16u(e1 * inv);
    P_lds[w][row][32 + cc] = f32_to_f16u(e2 * inv);
  }
  {
    const int rr = lane >> 2, c0 = 48 + (lane & 3) * 4;
    *(ushort4*)&P_lds[w][rr][c0] = make_ushort4(0, 0, 0, 0);
  }
  __syncthreads();

  floatx4 accp[4] = {zero, zero, zero, zero};
#pragma unroll
  for (int ks2 = 0; ks2 < 2; ks2++) {
    const short8 ap = *(const short8*)&P_lds[w][cc][ks2 * 32 + kgrp * 8];
    const int tok0 = min(max(kb + ks2 * 32 + kgrp * 8, 0), T_LEN - 8);
#pragma unroll
    for (int ni = 0; ni < 4; ni++) {
      const short8 bv = *(const short8*)&vT[(size_t)(ni * 16 + cc) * 2048 + tok0];
      accp[ni] = __builtin_amdgcn_mfma_f32_16x16x32_f16(
          __builtin_bit_cast(h8, ap), __builtin_bit_cast(h8, bv), accp[ni], 0, 0, 0);
    }
  }

#pragma unroll
  for (int r = 0; r < 4; r++) {
    const int t = qt0 + kgrp * 4 + r;
    const float g0 = gates[t * 3 + 0], g1 = gates[t * 3 + 1], g2 = gates[t * 3 + 2];
#pragma unroll
    for (int ni = 0; ni < 4; ni++) {
      const int d = ni * 16 + cc;
      const float ocv = oc[(size_t)t * 1024 + h * 64 + d];
      const float osv = osel[(size_t)t * 1024 + h * 64 + d];
      outf[(size_t)t * 1024 + h * 64 + d] =
          f32_to_bf16(g0 * ocv + g1 * osv + g2 * accp[ni][r]);
    }
  }
}

// ---------------- launch ----------------
extern "C" void kernel_launch(void* const* d_in, const int* in_sizes, int n_in,
                              void* d_out, int out_size, void* d_ws, size_t ws_size,
                              hipStream_t stream) {
  const float* x   = (const float*)d_in[0];
  const float* Wq  = (const float*)d_in[1];
  const float* Wk  = (const float*)d_in[2];
  const float* Wv  = (const float*)d_in[3];
  const float* Wo  = (const float*)d_in[4];
  const float* Wck = (const float*)d_in[5];
  const float* Wcv = (const float*)d_in[6];
  const float* Wg  = (const float*)d_in[7];
  const float* bg  = (const float*)d_in[8];
  float* out = (float*)d_out;

  float* ws = (float*)d_ws;
  // region A [0,24 MB): C alive through cscore; then osel [0,8), outf [16,20)
  float*          C    = ws;
  float*          osel = ws;                                // [0,8 MB)  (after cscore)
  unsigned short* outf = (unsigned short*)(ws + 4194304);   // [16,20 MB)
  // region B [24,36 MB): Axf (4 MB) until qkv GEMM; then oc [24,32) + smalls
  unsigned short* Axf   = (unsigned short*)(ws + 6291456);
  float*          oc    = ws + 6291456;                     // [24,32 MB) (was qh)
  unsigned short* Wot   = (unsigned short*)(ws + 8388608);  // [32,34 MB)
  unsigned short* kc_hi = (unsigned short*)(ws + 8912896);
  unsigned short* kc_lo = (unsigned short*)(ws + 8978432);
  unsigned short* vcT   = (unsigned short*)(ws + 9043968);
  int4*           sel   = (int4*)(ws + 9109504);
  unsigned short* WckT_hi = (unsigned short*)(ws + 9240576);
  unsigned short* WckT_lo = (unsigned short*)(ws + 9273344);
  unsigned short* WcvT_hi = (unsigned short*)(ws + 9306112);
  unsigned short* WcvT_lo = (unsigned short*)(ws + 9338880);
  float*          gates   = ws + 9371648;
  // region C [36,48 MB): Bqkv f16 (6 MB) until qkv GEMM; then qhf/khfT/vhf f16
  unsigned short* Bqkv = (unsigned short*)(ws + 9437184);   // 3072x1024 f16, 6 MB
  unsigned short* qhf  = (unsigned short*)(ws + 9437184);   // [36,40 MB)
  unsigned short* khfT = (unsigned short*)(ws + 10485760);  // [40,44 MB)
  unsigned short* vhf  = (unsigned short*)(ws + 11534336);  // [44,48 MB)
  // vhfT scratch lives in d_out (read by nsa_win, then gemm_bt64 overwrites out)
  unsigned short* vhfT = (unsigned short*)d_out;            // 16x64x2048 f16, 4 MB

  // 1. operand prep: single kernel (weights z0-5, x z6-7)
  cast_weights<<<dim3(32, 32, 8), dim3(32, 8), 0, stream>>>(
      x, Wq, Wk, Wv, Wo, Wck, Wcv, Axf, Bqkv, Wot, WckT_hi, WckT_lo, WcvT_hi, WcvT_lo);

  // 2. merged q|k|v GEMM: 64x128 BK=32, 3-buffer counted-vmcnt (structural floor)
  qkv_gemm<<<dim3(24, 32), 256, 0, stream>>>(Axf, Bqkv, C);

  // 3. reorg + gates (merged); V transpose for window MFMA
  reorg_qkv<<<6656, 256, 0, stream>>>(C, qhf, khfT, vhf, Wg, bg, gates);
  transp_v<<<dim3(64, 2, 16), dim3(32, 8), 0, stream>>>(vhf, vhfT);

  // 4. compression (reads C) + compressed branch (cscore reads C q-cols; oc
  //    now at [24,32) so C stays alive — qh copy deleted)
  compress_mfma<<<dim3(128, 2), 512, 0, stream>>>(C, WckT_hi, WckT_lo, WcvT_hi, WcvT_lo,
                                                  kc_hi, kc_lo, vcT);
  cscore_k<<<2048, 256, 0, stream>>>(C, kc_hi, kc_lo, vcT, oc, sel);

  // 5. selected branch (scalar, per-query) -> osel; window branch (MFMA) + combine
  nsa_sel<<<8192, 256, 0, stream>>>(qhf, khfT, vhf, sel, osel);
  nsa_win<<<512, 256, 0, stream>>>(qhf, khfT, vhfT, oc, osel, gates, outf);

  // 6. output projection: 64x64 tile, 512 blocks (2/CU)
  gemm_bt64<<<dim3(16, 32), 256, 0, stream>>>(outf, Wot, out, 1024, 1024, 1024);
}

// Round 14
// 227.612 us; speedup vs baseline: 1.0868x; 1.0134x over previous
//
#include <hip/hip_runtime.h>
#include <hip/hip_bf16.h>
#include <float.h>

#define T_LEN 2048
#define DM    1024
#define NB    128
#define NEGC  (-1e9f)

typedef __attribute__((ext_vector_type(8))) short short8;
typedef __attribute__((ext_vector_type(4))) float floatx4;
typedef _Float16 h2 __attribute__((ext_vector_type(2)));
typedef _Float16 h8 __attribute__((ext_vector_type(8)));

// ---------------- helpers ----------------
__device__ __forceinline__ float wred_max(float v) {
#pragma unroll
  for (int o = 32; o > 0; o >>= 1) v = fmaxf(v, __shfl_xor(v, o, 64));
  return v;
}
__device__ __forceinline__ float wred_sum(float v) {
#pragma unroll
  for (int o = 32; o > 0; o >>= 1) v += __shfl_xor(v, o, 64);
  return v;
}
__device__ __forceinline__ unsigned short f32_to_bf16(float f) {
  unsigned int b = __float_as_uint(f);
  return (unsigned short)((b + 0x7fffu + ((b >> 16) & 1u)) >> 16);
}
__device__ __forceinline__ float bf16_to_f32(unsigned short u) {
  return __uint_as_float(((unsigned int)u) << 16);
}
__device__ __forceinline__ unsigned int pack_h2(float a, float b) {
  h2 r; r[0] = (_Float16)a; r[1] = (_Float16)b;
  return __builtin_bit_cast(unsigned int, r);
}
__device__ __forceinline__ unsigned short f32_to_f16u(float f) {
  h2 r; r[0] = (_Float16)f; r[1] = (_Float16)0.f;
  return (unsigned short)(__builtin_bit_cast(unsigned int, r) & 0xffffu);
}
__device__ __forceinline__ float fdot2u(unsigned int a, unsigned int b, float c) {
#if __has_builtin(__builtin_amdgcn_fdot2)
  return __builtin_amdgcn_fdot2(__builtin_bit_cast(h2, a), __builtin_bit_cast(h2, b), c, false);
#else
  const h2 av = __builtin_bit_cast(h2, a), bv = __builtin_bit_cast(h2, b);
  return c + (float)av[0] * (float)bv[0] + (float)av[1] * (float)bv[1];
#endif
}
__device__ __forceinline__ void lds_async16(unsigned short* l, const unsigned short* g) {
  __builtin_amdgcn_global_load_lds(
      (const __attribute__((address_space(1))) unsigned int*)g,
      (__attribute__((address_space(3))) unsigned int*)l, 16, 0, 0);
}

// ====== 64x128-tile MFMA GEMM core — BK=32, 3-buffer counted-vmcnt (r10) ======
// qkv DONE at this structure (r10 null: 2-ahead == 1-ahead == 43 us, 297 TF
// ~= the known plain-HIP 2-barrier value at this shape).
template <bool F16>
__device__ __forceinline__ void gemm64_core(
    const unsigned short* __restrict__ A, const unsigned short* __restrict__ Bt,
    float* __restrict__ C, int K, int lda, int row0, int bcol0, int ccol0, int ldc,
    unsigned short* As, unsigned short* Bs) {
  const int tid = threadIdx.x;
  const int w = tid >> 6, lane = tid & 63;
  const int wr = w >> 1, wc = w & 1;
  const int mrow = lane & 15, kgrp = lane >> 4;

  const int sr = (w << 4) + mrow;          // staged row 0..63
  const int sc = kgrp;                     // staged chunk 0..3

  floatx4 zero = {0.f, 0.f, 0.f, 0.f};
  floatx4 acc[2][4];
#pragma unroll
  for (int i = 0; i < 2; i++)
#pragma unroll
    for (int j = 0; j < 4; j++) acc[i][j] = zero;

  const int nt = K >> 5;
  const unsigned short* Ap  = A  + (size_t)(row0 + sr) * lda + sc * 8;
  const unsigned short* Bp0 = Bt + (size_t)(bcol0 + sr) * K + sc * 8;
  const unsigned short* Bp1 = Bt + (size_t)(bcol0 + 64 + sr) * K + sc * 8;

  auto stage = [&](int t, int b) {
    lds_async16(&As[b * 2048 + w * 512], Ap + t * 32);
    lds_async16(&Bs[b * 4096 + w * 512], Bp0 + t * 32);
    lds_async16(&Bs[b * 4096 + 2048 + w * 512], Bp1 + t * 32);
  };

  stage(0, 0);
  if (nt > 1) stage(1, 1);
  int cur = 0;
  for (int t = 0; t < nt; t++) {
    if (t + 2 < nt) {
      const int nx = (cur + 2 >= 3) ? cur - 1 : cur + 2;
      stage(t + 2, nx);                                   // outstanding: 9
      asm volatile("s_waitcnt vmcnt(6)" ::: "memory");    // tile t landed
    } else if (t + 1 < nt) {
      asm volatile("s_waitcnt vmcnt(3)" ::: "memory");
    } else {
      asm volatile("s_waitcnt vmcnt(0)" ::: "memory");
    }
    __builtin_amdgcn_s_barrier();
    const unsigned short* as = As + cur * 2048;
    const unsigned short* bs = Bs + cur * 4096;
    short8 af[2], bf4[4];
#pragma unroll
    for (int mi = 0; mi < 2; mi++)
      af[mi] = *(const short8*)&as[(wr * 2 + mi) * 512 + kgrp * 128 + mrow * 8];
#pragma unroll
    for (int ni = 0; ni < 4; ni++)
      bf4[ni] = *(const short8*)&bs[(wc * 4 + ni) * 512 + kgrp * 128 + mrow * 8];
#pragma unroll
    for (int mi = 0; mi < 2; mi++)
#pragma unroll
      for (int ni = 0; ni < 4; ni++) {
        if constexpr (F16)
          acc[mi][ni] = __builtin_amdgcn_mfma_f32_16x16x32_f16(
              __builtin_bit_cast(h8, af[mi]), __builtin_bit_cast(h8, bf4[ni]),
              acc[mi][ni], 0, 0, 0);
        else
          acc[mi][ni] = __builtin_amdgcn_mfma_f32_16x16x32_bf16(af[mi], bf4[ni],
                                                                acc[mi][ni], 0, 0, 0);
      }
    asm volatile("" ::: "memory");
    __builtin_amdgcn_s_barrier();
    cur = (cur + 1 == 3) ? 0 : cur + 1;
  }
#pragma unroll
  for (int mi = 0; mi < 2; mi++)
#pragma unroll
    for (int ni = 0; ni < 4; ni++) {
      float* Cp = C + (size_t)(row0 + wr * 32 + mi * 16 + kgrp * 4) * ldc
                    + ccol0 + wc * 64 + ni * 16 + mrow;
      Cp[0] = acc[mi][ni][0];
      Cp[(size_t)ldc] = acc[mi][ni][1];
      Cp[(size_t)2 * ldc] = acc[mi][ni][2];
      Cp[(size_t)3 * ldc] = acc[mi][ni][3];
    }
}

// merged q|k|v GEMM: grid (24, 32) = 768 blocks (3/CU), f16 K=1024 single pass.
__global__ __launch_bounds__(256) void qkv_gemm(const unsigned short* __restrict__ Axf,
                                                const unsigned short* __restrict__ Bqkv,
                                                float* __restrict__ C) {
  __shared__ __align__(16) unsigned short As[3 * 64 * 32];
  __shared__ __align__(16) unsigned short Bs[3 * 128 * 32];
  gemm64_core<true>(Axf, Bqkv, C, 1024, 1024, blockIdx.y * 64,
                    blockIdx.x * 128, blockIdx.x * 128, 3072, As, Bs);
}

// ====== output projection — 64x64 tile, grid (16,32) = 512 blocks (2/CU) ======
// (r11 occupancy fix: 2 waves/SIMD so TLP hides the stage wait.)
__global__ __launch_bounds__(256) void gemm_bt64(const unsigned short* __restrict__ A,
                                                 const unsigned short* __restrict__ Bt,
                                                 float* __restrict__ C,
                                                 int K, int lda, int ldc) {
  __shared__ __align__(16) unsigned short As[3 * 2048];
  __shared__ __align__(16) unsigned short Bs[3 * 2048];
  const int tid = threadIdx.x;
  const int w = tid >> 6, lane = tid & 63;
  const int wr = w >> 1, wc = w & 1;
  const int mrow = lane & 15, kgrp = lane >> 4;
  const int row0 = blockIdx.y * 64, col0 = blockIdx.x * 64;

  const int sr = (w << 4) + mrow;

  floatx4 zero = {0.f, 0.f, 0.f, 0.f};
  floatx4 acc[2][2];
#pragma unroll
  for (int i = 0; i < 2; i++)
#pragma unroll
    for (int j = 0; j < 2; j++) acc[i][j] = zero;

  const int nt = K >> 5;
  const unsigned short* Ap = A + (size_t)(row0 + sr) * lda + kgrp * 8;
  const unsigned short* Bp = Bt + (size_t)(col0 + sr) * K + kgrp * 8;

  auto stage = [&](int t, int b) {
    lds_async16(&As[b * 2048 + w * 512], Ap + t * 32);
    lds_async16(&Bs[b * 2048 + w * 512], Bp + t * 32);
  };

  stage(0, 0);
  if (nt > 1) stage(1, 1);
  int cur = 0;
  for (int t = 0; t < nt; t++) {
    if (t + 2 < nt) {
      const int nx = (cur + 2 >= 3) ? cur - 1 : cur + 2;
      stage(t + 2, nx);                                   // outstanding: 6
      asm volatile("s_waitcnt vmcnt(4)" ::: "memory");    // tile t landed
    } else if (t + 1 < nt) {
      asm volatile("s_waitcnt vmcnt(2)" ::: "memory");
    } else {
      asm volatile("s_waitcnt vmcnt(0)" ::: "memory");
    }
    __builtin_amdgcn_s_barrier();
    const unsigned short* as = As + cur * 2048;
    const unsigned short* bs = Bs + cur * 2048;
    short8 af[2], bf2[2];
#pragma unroll
    for (int mi = 0; mi < 2; mi++)
      af[mi] = *(const short8*)&as[(wr * 2 + mi) * 512 + kgrp * 128 + mrow * 8];
#pragma unroll
    for (int ni = 0; ni < 2; ni++)
      bf2[ni] = *(const short8*)&bs[(wc * 2 + ni) * 512 + kgrp * 128 + mrow * 8];
#pragma unroll
    for (int mi = 0; mi < 2; mi++)
#pragma unroll
      for (int ni = 0; ni < 2; ni++)
        acc[mi][ni] = __builtin_amdgcn_mfma_f32_16x16x32_bf16(af[mi], bf2[ni],
                                                              acc[mi][ni], 0, 0, 0);
    asm volatile("" ::: "memory");
    __builtin_amdgcn_s_barrier();
    cur = (cur + 1 == 3) ? 0 : cur + 1;
  }
#pragma unroll
  for (int mi = 0; mi < 2; mi++)
#pragma unroll
    for (int ni = 0; ni < 2; ni++) {
      float* Cp = C + (size_t)(row0 + wr * 32 + mi * 16 + kgrp * 4) * ldc
                    + col0 + wc * 32 + ni * 16 + mrow;
      Cp[0] = acc[mi][ni][0];
      Cp[(size_t)ldc] = acc[mi][ni][1];
      Cp[(size_t)2 * ldc] = acc[mi][ni][2];
      Cp[(size_t)3 * ldc] = acc[mi][ni][3];
    }
}

// ---- merged operand prep (r12)
// z 0-2: Wq/Wk/Wv -> Bqkv f16 (3072n x 1024k); z=3: Wo -> Wot bf16;
// z 4-5: Wck/Wcv (1024x64) -> (64,1024) hi/lo bf16 (x>=2 blocks no-op);
// z 6-7: x -> Axf f16 flat copy-cast (1024 blocks/slice, 1 float4/thread).
__global__ void cast_weights(const float* __restrict__ x,
                             const float* __restrict__ Wq, const float* __restrict__ Wk,
                             const float* __restrict__ Wv, const float* __restrict__ Wo,
                             const float* __restrict__ Wck, const float* __restrict__ Wcv,
                             unsigned short* __restrict__ Axf,
                             unsigned short* __restrict__ Bqkv, unsigned short* __restrict__ Wot,
                             unsigned short* __restrict__ KT_hi, unsigned short* __restrict__ KT_lo,
                             unsigned short* __restrict__ VT_hi, unsigned short* __restrict__ VT_lo) {
  __shared__ float tile[32][33];
  const int z = blockIdx.z;
  const int tx = threadIdx.x, ty = threadIdx.y;
  const int kt0 = blockIdx.y * 32, nt0 = blockIdx.x * 32;
  if (z < 3) {
    const float* W = (z == 0) ? Wq : (z == 1) ? Wk : Wv;
#pragma unroll
    for (int i = 0; i < 32; i += 8)
      tile[ty + i][tx] = W[(size_t)(kt0 + ty + i) * 1024 + nt0 + tx];
    __syncthreads();
#pragma unroll
    for (int i = 0; i < 32; i += 8) {
      const int n = nt0 + ty + i, kk = kt0 + tx;
      Bqkv[(size_t)(z * 1024 + n) * 1024 + kk] = f32_to_f16u(tile[tx][ty + i]);
    }
  } else if (z == 3) {
#pragma unroll
    for (int i = 0; i < 32; i += 8)
      tile[ty + i][tx] = Wo[(size_t)(kt0 + ty + i) * 1024 + nt0 + tx];
    __syncthreads();
#pragma unroll
    for (int i = 0; i < 32; i += 8) {
      const int n = nt0 + ty + i, kk = kt0 + tx;
      Wot[(size_t)n * 1024 + kk] = f32_to_bf16(tile[tx][ty + i]);
    }
  } else if (z < 6) {
    if (nt0 >= 64) return;
    const float* W = (z == 5) ? Wcv : Wck;
    unsigned short* Bh = (z == 5) ? VT_hi : KT_hi;
    unsigned short* Bl = (z == 5) ? VT_lo : KT_lo;
#pragma unroll
    for (int i = 0; i < 32; i += 8)
      tile[ty + i][tx] = W[(size_t)(kt0 + ty + i) * 64 + nt0 + tx];
    __syncthreads();
#pragma unroll
    for (int i = 0; i < 32; i += 8) {
      const int n = nt0 + ty + i, kk = kt0 + tx;
      const float f = tile[tx][ty + i];
      const unsigned short hb = f32_to_bf16(f);
      Bh[(size_t)n * 1024 + kk] = hb;
      Bl[(size_t)n * 1024 + kk] = f32_to_bf16(f - bf16_to_f32(hb));
    }
  } else {
    // x -> f16: flat; slice z-6 covers 1024 blocks x 256 thr x 1 float4
    const size_t q4 = ((size_t)(z - 6) * 1024 + blockIdx.y * 32 + blockIdx.x) * 256
                      + ty * 32 + tx;
    const float4 xv = ((const float4*)x)[q4];
    const unsigned int p0 = pack_h2(xv.x, xv.y);
    const unsigned int p1 = pack_h2(xv.z, xv.w);
    *(uint2*)&Axf[q4 * 4] = make_uint2(p0, p1);
  }
}

// ---------------- reorg + gates merged (r12) ----------------
__global__ __launch_bounds__(256) void reorg_qkv(const float* __restrict__ C,
                                                 unsigned short* __restrict__ qhf,
                                                 unsigned short* __restrict__ khfT,
                                                 unsigned short* __restrict__ vhf,
                                                 const float* __restrict__ Wg,
                                                 const float* __restrict__ bg,
                                                 float* __restrict__ gates) {
  const int bid = blockIdx.x;
  if (bid < 6144) {
    const int gid = bid * 256 + threadIdx.x;
    const int t = gid / 768;
    const int c = (gid - t * 768) * 4;
    float4 val = *(const float4*)&C[(size_t)t * 3072 + c];
    const unsigned int p0 = pack_h2(val.x, val.y);
    const unsigned int p1 = pack_h2(val.z, val.w);
    if (c < 1024) {
      *(uint2*)&qhf[(size_t)t * 1024 + c] = make_uint2(p0, p1);
    } else if (c < 2048) {
      const int h = (c >> 6) & 15, d = c & 63;
      const int dc = d >> 3, j = d & 7;
      *(uint2*)&khfT[((size_t)(h * 8 + dc) * 2048 + t) * 8 + j] = make_uint2(p0, p1);
    } else {
      const int h = (c >> 6) & 15, d = c & 63;
      *(uint2*)&vhf[((size_t)h * 2048 + t) * 64 + d] = make_uint2(p0, p1);
    }
  } else {
    const int w = threadIdx.x >> 6, lane = threadIdx.x & 63;
    const int t = (bid - 6144) * 4 + w;
    float m = 0.f;
#pragma unroll
    for (int h = 0; h < 16; h++) m += C[(size_t)t * 3072 + h * 64 + lane];
    m *= (1.f / 16.f);
    float g0 = wred_sum(m * Wg[lane * 3 + 0]);
    float g1 = wred_sum(m * Wg[lane * 3 + 1]);
    float g2 = wred_sum(m * Wg[lane * 3 + 2]);
    if (lane == 0) {
      g0 += bg[0]; g1 += bg[1]; g2 += bg[2];
      float mx = fmaxf(g0, fmaxf(g1, g2));
      float e0 = __expf(g0 - mx), e1 = __expf(g1 - mx), e2 = __expf(g2 - mx);
      float inv = 1.f / (e0 + e1 + e2);
      gates[t * 3 + 0] = e0 * inv;
      gates[t * 3 + 1] = e1 * inv;
      gates[t * 3 + 2] = e2 * inv;
    }
  }
}

// ---- transpose vhf [h][t][64] -> vhfT [h][d][2048] f16 (for window PV MFMA) ----
__global__ void transp_v(const unsigned short* __restrict__ vhf,
                         unsigned short* __restrict__ vhfT) {
  __shared__ unsigned short tile[32][34];
  const int h = blockIdx.z;
  const int t0 = blockIdx.x * 32, d0 = blockIdx.y * 32;
  const int tx = threadIdx.x, ty = threadIdx.y;
#pragma unroll
  for (int i = 0; i < 32; i += 8)
    tile[ty + i][tx] = vhf[((size_t)h * 2048 + t0 + ty + i) * 64 + d0 + tx];
  __syncthreads();
#pragma unroll
  for (int i = 0; i < 32; i += 8)
    vhfT[((size_t)h * 64 + d0 + ty + i) * 2048 + t0 + tx] = tile[tx][ty + i];
}

// ---------------- compress via MFMA (reads k/v straight from C) ----------------
__global__ __launch_bounds__(512) void compress_mfma(
    const float* __restrict__ C,
    const unsigned short* __restrict__ KT_hi, const unsigned short* __restrict__ KT_lo,
    const unsigned short* __restrict__ VT_hi, const unsigned short* __restrict__ VT_lo,
    unsigned short* __restrict__ kc_hi, unsigned short* __restrict__ kc_lo,
    unsigned short* __restrict__ vcT) {
  __shared__ float red[8][64][17];
  const int isv = blockIdx.y;
  const unsigned short* Bh = isv ? VT_hi : KT_hi;
  const unsigned short* Bl = isv ? VT_lo : KT_lo;
  const int tid = threadIdx.x, w = tid >> 6, lane = tid & 63;
  const int mrow = lane & 15, kgrp = lane >> 4;
  const int m0 = blockIdx.x * 16;
  const int m = m0 + mrow;
  const int hh = m >> 7, nb = m & 127;
  const int cbase = 1024 + isv * 1024 + hh * 64;

  floatx4 zero = {0.f, 0.f, 0.f, 0.f};
  floatx4 acc[4] = {zero, zero, zero, zero};

  const int kbeg = w << 7;
  for (int k0 = kbeg; k0 < kbeg + 128; k0 += 32) {
    const int c = k0 + kgrp * 8;
    const float* ap = &C[(size_t)(nb * 16 + (c >> 6)) * 3072 + cbase + (c & 63)];
    float4 q0 = *(const float4*)ap;
    float4 q1 = *(const float4*)(ap + 4);
    float qq[8] = {q0.x, q0.y, q0.z, q0.w, q1.x, q1.y, q1.z, q1.w};
    short8 a_hi, a_lo;
#pragma unroll
    for (int j = 0; j < 8; j++) {
      unsigned short hb = f32_to_bf16(qq[j]);
      a_hi[j] = (short)hb;
      a_lo[j] = (short)f32_to_bf16(qq[j] - bf16_to_f32(hb));
    }
#pragma unroll
    for (int ni = 0; ni < 4; ni++) {
      const size_t boff = (size_t)(ni * 16 + mrow) * 1024 + k0 + kgrp * 8;
      short8 b_hi = *(const short8*)&Bh[boff];
      short8 b_lo = *(const short8*)&Bl[boff];
      acc[ni] = __builtin_amdgcn_mfma_f32_16x16x32_bf16(a_hi, b_hi, acc[ni], 0, 0, 0);
      acc[ni] = __builtin_amdgcn_mfma_f32_16x16x32_bf16(a_lo, b_hi, acc[ni], 0, 0, 0);
      acc[ni] = __builtin_amdgcn_mfma_f32_16x16x32_bf16(a_hi, b_lo, acc[ni], 0, 0, 0);
    }
  }

#pragma unroll
  for (int ni = 0; ni < 4; ni++)
#pragma unroll
    for (int r = 0; r < 4; r++) red[w][lane][ni * 4 + r] = acc[ni][r];
  __syncthreads();

  if (w < 4) {
#pragma unroll
    for (int r = 0; r < 4; r++) {
      const int j = w * 4 + r;
      float val = 0.f;
#pragma unroll
      for (int ww = 0; ww < 8; ww++) val += red[ww][lane][j];
      const int mo = m0 + kgrp * 4 + r;
      const int d = w * 16 + mrow;
      if (!isv) {
        const unsigned short hb = f32_to_bf16(val);
        kc_hi[(size_t)mo * 64 + d] = hb;
        kc_lo[(size_t)mo * 64 + d] = f32_to_bf16(val - bf16_to_f32(hb));
      } else {
        vcT[(size_t)(mo >> 7) * 8192 + (size_t)d * 128 + (mo & 127)] = f32_to_bf16(val);
      }
    }
  }
}

// ------- cscore: MFMA scores + softmax + top-4 + fused PV -------
// r14: t-tile 16 -> 32 queries/block (grid 2048 -> 1024, 4/CU). Halves the
// per-head kc_hi/kc_lo + vcT re-read traffic (each block's 32KB kc load now
// scores 32 rows); b-fragments hoisted across the 2 row-sets (2 MFMA per kc
// load); softmax/argmax runs 8 independent rows per wave (2x chain ILP).
// Per-row math UNCHANGED -> absmax bit-canary must hold.
__global__ __launch_bounds__(256) void cscore_k(
    const float* __restrict__ C, const unsigned short* __restrict__ kc_hi,
    const unsigned short* __restrict__ kc_lo, const unsigned short* __restrict__ vcT,
    float* __restrict__ oc, int4* __restrict__ sel) {
  __shared__ float S_s[32][132];
  const int h = blockIdx.x >> 6, t0 = (blockIdx.x & 63) * 32;
  const int tid = threadIdx.x, w = tid >> 6, lane = tid & 63;
  const int mrow = lane & 15, kgrp = lane >> 4;

  short8 a_hi[2][2], a_lo[2][2];           // [rowset][ks]
#pragma unroll
  for (int rs = 0; rs < 2; rs++)
#pragma unroll
    for (int ks = 0; ks < 2; ks++) {
      const float* qp = &C[(size_t)(t0 + rs * 16 + mrow) * 3072 + h * 64 + ks * 32 + kgrp * 8];
      float4 q0 = *(const float4*)qp;
      float4 q1 = *(const float4*)(qp + 4);
      float qq[8] = {q0.x, q0.y, q0.z, q0.w, q1.x, q1.y, q1.z, q1.w};
#pragma unroll
      for (int j = 0; j < 8; j++) {
        unsigned short hb = f32_to_bf16(qq[j]);
        a_hi[rs][ks][j] = (short)hb;
        a_lo[rs][ks][j] = (short)f32_to_bf16(qq[j] - bf16_to_f32(hb));
      }
    }
  floatx4 zero = {0.f, 0.f, 0.f, 0.f};
  floatx4 acc[2][2];                       // [rowset][ni]
#pragma unroll
  for (int rs = 0; rs < 2; rs++)
#pragma unroll
    for (int ni = 0; ni < 2; ni++) acc[rs][ni] = zero;
#pragma unroll
  for (int ni = 0; ni < 2; ni++) {
    const int nb = w * 32 + ni * 16 + mrow;
#pragma unroll
    for (int ks = 0; ks < 2; ks++) {
      const size_t off = ((size_t)h * 128 + nb) * 64 + ks * 32 + kgrp * 8;
      short8 b_hi = *(const short8*)&kc_hi[off];
      short8 b_lo = *(const short8*)&kc_lo[off];
#pragma unroll
      for (int rs = 0; rs < 2; rs++) {
        acc[rs][ni] = __builtin_amdgcn_mfma_f32_16x16x32_bf16(a_hi[rs][ks], b_hi, acc[rs][ni], 0, 0, 0);
        acc[rs][ni] = __builtin_amdgcn_mfma_f32_16x16x32_bf16(a_lo[rs][ks], b_hi, acc[rs][ni], 0, 0, 0);
        acc[rs][ni] = __builtin_amdgcn_mfma_f32_16x16x32_bf16(a_hi[rs][ks], b_lo, acc[rs][ni], 0, 0, 0);
      }
    }
  }
#pragma unroll
  for (int rs = 0; rs < 2; rs++)
#pragma unroll
    for (int ni = 0; ni < 2; ni++) {
      const int n = w * 32 + ni * 16 + mrow;
#pragma unroll
      for (int r = 0; r < 4; r++) {
        const int row = rs * 16 + kgrp * 4 + r;
        const int count = (t0 + row) >> 4;
        S_s[row][n] = (n < count) ? acc[rs][ni][r] * 0.125f : NEGC;
      }
    }
  __syncthreads();

#pragma unroll
  for (int qq = 0; qq < 8; qq++) {
    const int row = w * 8 + qq, t = t0 + row, count = t >> 4;
    const float2 sv = *(const float2*)&S_s[row][2 * lane];
    const float s0 = sv.x, s1 = sv.y;
    const float M = wred_max(fmaxf(s0, s1));
    const float e0 = __expf(s0 - M), e1 = __expf(s1 - M);
    const float inv = 1.f / wred_sum(e0 + e1);
    S_s[row][2 * lane]     = (count == 0) ? 0.f : e0 * inv;
    S_s[row][2 * lane + 1] = (count == 0) ? 0.f : e1 * inv;

    float c0 = s0, c1 = s1;
    float curM = M;
    int se0 = 0, se1 = 0, se2 = 0, se3 = 0;
#pragma unroll
    for (int j = 0; j < 4; j++) {
      if (j) curM = wred_max(fmaxf(c0, c1));
      const unsigned long long b = __ballot((c0 == curM) || (c1 == curM));
      const int lidx = (int)__builtin_ctzll(b);
      const float c0l = __shfl(c0, lidx, 64);
      const int isc0 = (c0l == curM);
      const int idx = 2 * lidx + (isc0 ? 0 : 1);
      if (j == 0) se0 = idx; else if (j == 1) se1 = idx;
      else if (j == 2) se2 = idx; else se3 = idx;
      if (lane == lidx) { if (isc0) c0 = -FLT_MAX; else c1 = -FLT_MAX; }
    }
    if (lane == 0) sel[((size_t)h << 11) + t] = make_int4(se0, se1, se2, se3);
  }
  __syncthreads();

  const int d = w * 16 + mrow;
#pragma unroll
  for (int rs = 0; rs < 2; rs++) {
    floatx4 accp = zero;
#pragma unroll
    for (int ks = 0; ks < 4; ks++) {
      const float4 p0 = *(const float4*)&S_s[rs * 16 + mrow][ks * 32 + kgrp * 8];
      const float4 p1 = *(const float4*)&S_s[rs * 16 + mrow][ks * 32 + kgrp * 8 + 4];
      short8 a;
      a[0] = (short)f32_to_bf16(p0.x); a[1] = (short)f32_to_bf16(p0.y);
      a[2] = (short)f32_to_bf16(p0.z); a[3] = (short)f32_to_bf16(p0.w);
      a[4] = (short)f32_to_bf16(p1.x); a[5] = (short)f32_to_bf16(p1.y);
      a[6] = (short)f32_to_bf16(p1.z); a[7] = (short)f32_to_bf16(p1.w);
      const short8 b = *(const short8*)&vcT[((size_t)h * 64 + d) * 128 + ks * 32 + kgrp * 8];
      accp = __builtin_amdgcn_mfma_f32_16x16x32_bf16(a, b, accp, 0, 0, 0);
    }
#pragma unroll
    for (int r = 0; r < 4; r++)
      oc[(size_t)(t0 + rs * 16 + kgrp * 4 + r) * 1024 + h * 64 + d] = accp[r];
  }
}

// ------------- selected branch only: per-wave per-(h,t), writes osel -------------
__global__ __launch_bounds__(256) void nsa_sel(
    const unsigned short* __restrict__ qhf, const unsigned short* __restrict__ khfT,
    const unsigned short* __restrict__ vhf, const int4* __restrict__ sel,
    float* __restrict__ osel) {
  __shared__ float ps[4][64];
  __shared__ int tks[4][64];
  const int bid = blockIdx.x;
  const int h = ((bid & 7) << 1) | ((bid >> 3) & 1);
  const int w = threadIdx.x >> 6, lane = threadIdx.x & 63;
  const int t = (bid >> 4) * 4 + w;

  const unsigned short* kT = khfT + (size_t)h * 131072;
  const unsigned short* vhh = vhf + (size_t)h * 131072;

  uint4 qr[8];
  {
    const uint4* qp = (const uint4*)(qhf + (size_t)t * 1024 + h * 64);
#pragma unroll
    for (int j = 0; j < 8; j++) qr[j] = qp[j];
  }
  const int4 s4 = sel[((size_t)h << 11) + t];

  const int g16 = lane >> 4;
  const int blk = (g16 == 0) ? s4.x : (g16 == 1) ? s4.y : (g16 == 2) ? s4.z : s4.w;
  const int tok = blk * 16 + (lane & 15);
  tks[w][lane] = tok;
  {
    float a0 = 0.f, a1 = 0.f, a2 = 0.f, a3 = 0.f;
#pragma unroll
    for (int dc = 0; dc < 8; dc++) {
      const uint4 kk = *(const uint4*)(kT + ((size_t)dc * 2048 + tok) * 8);
      a0 = fdot2u(kk.x, qr[dc].x, a0);
      a1 = fdot2u(kk.y, qr[dc].y, a1);
      a2 = fdot2u(kk.z, qr[dc].z, a2);
      a3 = fdot2u(kk.w, qr[dc].w, a3);
    }
    const float sv_ = (tok <= t) ? ((a0 + a1) + (a2 + a3)) * 0.125f : NEGC;
    const float Ms = wred_max(sv_);
    const float es = __expf(sv_ - Ms);
    ps[w][lane] = es * (1.f / wred_sum(es));
  }

  const int dd = lane & 31, s = lane >> 5;
  const float4* ps4 = (const float4*)ps[w];
  const int4* tk4p = (const int4*)tks[w];

  float osx = 0.f, osy = 0.f;
#pragma unroll
  for (int jc = 0; jc < 8; jc++) {
    const float4 p4 = ps4[s * 8 + jc];
    const int4 t4 = tk4p[s * 8 + jc];
    const float pa[4] = {p4.x, p4.y, p4.z, p4.w};
    const int ta[4] = {t4.x, t4.y, t4.z, t4.w};
#pragma unroll
    for (int u = 0; u < 4; u++) {
      const unsigned int vv = *(const unsigned int*)(vhh + (size_t)ta[u] * 64 + 2 * dd);
      const h2 v2 = __builtin_bit_cast(h2, vv);
      osx += pa[u] * (float)v2[0];
      osy += pa[u] * (float)v2[1];
    }
  }
  osx += __shfl_xor(osx, 32, 64);
  osy += __shfl_xor(osy, 32, 64);

  if (lane < 32)
    *(float2*)&osel[(size_t)t * 1024 + h * 64 + 2 * dd] = make_float2(osx, osy);
}

// ------------- window branch via MFMA + gated combine -> outf -------------
__global__ __launch_bounds__(256) void nsa_win(
    const unsigned short* __restrict__ qhf, const unsigned short* __restrict__ khfT,
    const unsigned short* __restrict__ vhfT, const float* __restrict__ oc,
    const float* __restrict__ osel, const float* __restrict__ gates,
    unsigned short* __restrict__ outf) {
  __shared__ unsigned short P_lds[4][16][72];
  const int bid = blockIdx.x;
  const int h = bid & 15, tq0 = (bid >> 4) * 64;
  const int w = threadIdx.x >> 6, lane = threadIdx.x & 63;
  const int cc = lane & 15, kgrp = lane >> 4;
  const int qt0 = tq0 + w * 16;
  const int kb = qt0 - 32;

  const unsigned short* kT = khfT + (size_t)h * 131072;
  const unsigned short* vT = vhfT + (size_t)h * 131072;

  short8 aq[2];
#pragma unroll
  for (int ks = 0; ks < 2; ks++)
    aq[ks] = *(const short8*)&qhf[(size_t)(qt0 + cc) * 1024 + h * 64 + ks * 32 + kgrp * 8];

  floatx4 zero = {0.f, 0.f, 0.f, 0.f};
  floatx4 accs[3] = {zero, zero, zero};
#pragma unroll
  for (int ni = 0; ni < 3; ni++) {
    const int tokc = min(max(kb + ni * 16 + cc, 0), T_LEN - 1);
#pragma unroll
    for (int ks = 0; ks < 2; ks++) {
      const short8 bk = *(const short8*)&kT[((size_t)(ks * 4 + kgrp) * 2048 + tokc) * 8];
      accs[ni] = __builtin_amdgcn_mfma_f32_16x16x32_f16(
          __builtin_bit_cast(h8, aq[ks]), __builtin_bit_cast(h8, bk), accs[ni], 0, 0, 0);
    }
  }

#pragma unroll
  for (int r = 0; r < 4; r++) {
    const int t = qt0 + kgrp * 4 + r;
    float sc[3];
#pragma unroll
    for (int ni = 0; ni < 3; ni++) {
      const int s = kb + ni * 16 + cc;
      const int ds = t - s;
      sc[ni] = (s >= 0 && ds >= 0 && ds <= 32) ? accs[ni][r] * 0.125f : NEGC;
    }
    float m3 = fmaxf(fmaxf(sc[0], sc[1]), sc[2]);
#pragma unroll
    for (int o = 1; o <= 8; o <<= 1) m3 = fmaxf(m3, __shfl_xor(m3, o, 64));
    float e0 = __expf(sc[0] - m3), e1 = __expf(sc[1] - m3), e2 = __expf(sc[2] - m3);
    float sum = e0 + e1 + e2;
#pragma unroll
    for (int o = 1; o <= 8; o <<= 1) sum += __shfl_xor(sum, o, 64);
    const float inv = 1.f / sum;
    const int row = kgrp * 4 + r;
    P_lds[w][row][cc]      = f32_to_f16u(e0 * inv);
    P_lds[w][row][16 + cc] = f32_to_f16u(e1 * inv);
    P_lds[w][row][32 + cc] = f32_to_f16u(e2 * inv);
  }
  {
    const int rr = lane >> 2, c0 = 48 + (lane & 3) * 4;
    *(ushort4*)&P_lds[w][rr][c0] = make_ushort4(0, 0, 0, 0);
  }
  __syncthreads();

  floatx4 accp[4] = {zero, zero, zero, zero};
#pragma unroll
  for (int ks2 = 0; ks2 < 2; ks2++) {
    const short8 ap = *(const short8*)&P_lds[w][cc][ks2 * 32 + kgrp * 8];
    const int tok0 = min(max(kb + ks2 * 32 + kgrp * 8, 0), T_LEN - 8);
#pragma unroll
    for (int ni = 0; ni < 4; ni++) {
      const short8 bv = *(const short8*)&vT[(size_t)(ni * 16 + cc) * 2048 + tok0];
      accp[ni] = __builtin_amdgcn_mfma_f32_16x16x32_f16(
          __builtin_bit_cast(h8, ap), __builtin_bit_cast(h8, bv), accp[ni], 0, 0, 0);
    }
  }

#pragma unroll
  for (int r = 0; r < 4; r++) {
    const int t = qt0 + kgrp * 4 + r;
    const float g0 = gates[t * 3 + 0], g1 = gates[t * 3 + 1], g2 = gates[t * 3 + 2];
#pragma unroll
    for (int ni = 0; ni < 4; ni++) {
      const int d = ni * 16 + cc;
      const float ocv = oc[(size_t)t * 1024 + h * 64 + d];
      const float osv = osel[(size_t)t * 1024 + h * 64 + d];
      outf[(size_t)t * 1024 + h * 64 + d] =
          f32_to_bf16(g0 * ocv + g1 * osv + g2 * accp[ni][r]);
    }
  }
}

// ---------------- launch ----------------
extern "C" void kernel_launch(void* const* d_in, const int* in_sizes, int n_in,
                              void* d_out, int out_size, void* d_ws, size_t ws_size,
                              hipStream_t stream) {
  const float* x   = (const float*)d_in[0];
  const float* Wq  = (const float*)d_in[1];
  const float* Wk  = (const float*)d_in[2];
  const float* Wv  = (const float*)d_in[3];
  const float* Wo  = (const float*)d_in[4];
  const float* Wck = (const float*)d_in[5];
  const float* Wcv = (const float*)d_in[6];
  const float* Wg  = (const float*)d_in[7];
  const float* bg  = (const float*)d_in[8];
  float* out = (float*)d_out;

  float* ws = (float*)d_ws;
  // region A [0,24 MB): C alive through cscore; then osel [0,8), outf [16,20)
  float*          C    = ws;
  float*          osel = ws;                                // [0,8 MB)  (after cscore)
  unsigned short* outf = (unsigned short*)(ws + 4194304);   // [16,20 MB)
  // region B [24,36 MB): Axf (4 MB) until qkv GEMM; then oc [24,32) + smalls
  unsigned short* Axf   = (unsigned short*)(ws + 6291456);
  float*          oc    = ws + 6291456;                     // [24,32 MB)
  unsigned short* Wot   = (unsigned short*)(ws + 8388608);  // [32,34 MB)
  unsigned short* kc_hi = (unsigned short*)(ws + 8912896);
  unsigned short* kc_lo = (unsigned short*)(ws + 8978432);
  unsigned short* vcT   = (unsigned short*)(ws + 9043968);
  int4*           sel   = (int4*)(ws + 9109504);
  unsigned short* WckT_hi = (unsigned short*)(ws + 9240576);
  unsigned short* WckT_lo = (unsigned short*)(ws + 9273344);
  unsigned short* WcvT_hi = (unsigned short*)(ws + 9306112);
  unsigned short* WcvT_lo = (unsigned short*)(ws + 9338880);
  float*          gates   = ws + 9371648;
  // region C [36,48 MB): Bqkv f16 (6 MB) until qkv GEMM; then qhf/khfT/vhf f16
  unsigned short* Bqkv = (unsigned short*)(ws + 9437184);   // 3072x1024 f16, 6 MB
  unsigned short* qhf  = (unsigned short*)(ws + 9437184);   // [36,40 MB)
  unsigned short* khfT = (unsigned short*)(ws + 10485760);  // [40,44 MB)
  unsigned short* vhf  = (unsigned short*)(ws + 11534336);  // [44,48 MB)
  // vhfT scratch lives in d_out (read by nsa_win, then gemm_bt64 overwrites out)
  unsigned short* vhfT = (unsigned short*)d_out;            // 16x64x2048 f16, 4 MB

  // 1. operand prep: single kernel (weights z0-5, x z6-7)
  cast_weights<<<dim3(32, 32, 8), dim3(32, 8), 0, stream>>>(
      x, Wq, Wk, Wv, Wo, Wck, Wcv, Axf, Bqkv, Wot, WckT_hi, WckT_lo, WcvT_hi, WcvT_lo);

  // 2. merged q|k|v GEMM: 64x128 BK=32, 3-buffer counted-vmcnt (structural floor)
  qkv_gemm<<<dim3(24, 32), 256, 0, stream>>>(Axf, Bqkv, C);

  // 3. reorg + gates (merged); V transpose for window MFMA
  reorg_qkv<<<6656, 256, 0, stream>>>(C, qhf, khfT, vhf, Wg, bg, gates);
  transp_v<<<dim3(64, 2, 16), dim3(32, 8), 0, stream>>>(vhf, vhfT);

  // 4. compression (reads C) + compressed branch (t-tiled cscore: 1024 blocks)
  compress_mfma<<<dim3(128, 2), 512, 0, stream>>>(C, WckT_hi, WckT_lo, WcvT_hi, WcvT_lo,
                                                  kc_hi, kc_lo, vcT);
  cscore_k<<<1024, 256, 0, stream>>>(C, kc_hi, kc_lo, vcT, oc, sel);

  // 5. selected branch (scalar, per-query) -> osel; window branch (MFMA) + combine
  nsa_sel<<<8192, 256, 0, stream>>>(qhf, khfT, vhf, sel, osel);
  nsa_win<<<512, 256, 0, stream>>>(qhf, khfT, vhfT, oc, osel, gates, outf);

  // 6. output projection: 64x64 tile, 512 blocks (2/CU)
  gemm_bt64<<<dim3(16, 32), 256, 0, stream>>>(outf, Wot, out, 1024, 1024, 1024);
}